// Round 5
// baseline (541.680 us; speedup 1.0000x reference)
//
#include <hip/hip_runtime.h>
#include <hip/hip_bf16.h>
#include <math.h>

#define B_      16
#define NPUS    1024
#define MEMS    4096
#define INS     512
#define RS      256
#define MD      128
#define GRUIN   640
#define MMUO    644
#define NROWS   (B_*NPUS)   // 16384

// d_out flat offsets (reference return order)
#define O_OUT   0u
#define O_REGS  8388608u
#define O_WKEY  12582912u
#define O_WVAL  14680064u
#define O_WGATE 16777216u
#define O_SSDK  16793600u
#define O_SSDV  18890752u
#define O_SSDG  20987904u

typedef __attribute__((ext_vector_type(8))) short bf16x8;
typedef __attribute__((ext_vector_type(4))) float f32x4;
typedef __attribute__((ext_vector_type(4))) unsigned short u16x4;

__device__ __forceinline__ float sigf(float x){ return 1.f/(1.f+__expf(-x)); }
__device__ __forceinline__ unsigned short bfu(float x){
    __hip_bfloat16 h = __float2bfloat16(x);
    return __builtin_bit_cast(unsigned short, h);
}

// ---------------- K_cvt: fp32 -> bf16, vectorized x4 ----------------
__global__ __launch_bounds__(256) void k_cvt(const float* __restrict__ src,
                                             unsigned short* __restrict__ dst, int n4)
{
    int i = blockIdx.x*256 + threadIdx.x;
    if (i >= n4) return;
    float4 v = ((const float4*)src)[i];
    u16x4 o = { bfu(v.x), bfu(v.y), bfu(v.z), bfu(v.w) };
    ((u16x4*)dst)[i] = o;
}

// ---------------- K0: memory_context -> bf16 row-major + transposed ----------------
__global__ __launch_bounds__(256) void k_conv(const float* __restrict__ mem,
                                              __hip_bfloat16* __restrict__ memB,
                                              __hip_bfloat16* __restrict__ memT)
{
    __shared__ float Ms[32][129];
    const int t = threadIdx.x;
    const int b = blockIdx.x >> 7;
    const int m0 = (blockIdx.x & 127) << 5;
    const float* src = mem + ((size_t)b*MEMS + m0)*MD;
    for (int idx = t; idx < 32*128; idx += 256) {
        int m = idx >> 7, d = idx & 127;
        float v = src[(size_t)m*MD + d];
        Ms[m][d] = v;
        memB[((size_t)b*MEMS + m0 + m)*MD + d] = __float2bfloat16(v);
    }
    __syncthreads();
    for (int idx = t; idx < 128*32; idx += 256) {
        int d = idx >> 5, m = idx & 31;
        memT[((size_t)b*MD + d)*MEMS + m0 + m] = __float2bfloat16(Ms[m][d]);
    }
}

// ---------------- K1: MMU GEMM (MFMA)  C[16384,644] = regs * Wmmu^T + b ----------------
__global__ __launch_bounds__(256) void k_mmu(const __hip_bfloat16* __restrict__ Ab,
                                             const __hip_bfloat16* __restrict__ Wb,
                                             const float* __restrict__ bias,
                                             float* __restrict__ out,
                                             __hip_bfloat16* __restrict__ qbf)
{
    const int t = threadIdx.x, w = t >> 6, l = t & 63;
    const int lg = l >> 4, ll = l & 15;
    const int m0 = blockIdx.x*64 + w*16;
    const int n0 = blockIdx.y*256;
    const short* A = (const short*)Ab;
    const short* W = (const short*)Wb;
    f32x4 acc[16];
    #pragma unroll
    for (int c = 0; c < 16; c++) acc[c] = (f32x4){0,0,0,0};
    for (int k0 = 0; k0 < RS; k0 += 32) {
        bf16x8 af = *(const bf16x8*)(A + (size_t)(m0+ll)*RS + k0 + lg*8);
        #pragma unroll
        for (int c = 0; c < 16; c++) {
            int n = n0 + c*16 + ll;
            bf16x8 bf = {};
            if (n < MMUO) bf = *(const bf16x8*)(W + (size_t)n*RS + k0 + lg*8);
            acc[c] = __builtin_amdgcn_mfma_f32_16x16x32_bf16(af, bf, acc[c], 0, 0, 0);
        }
    }
    #pragma unroll
    for (int c = 0; c < 16; c++) {
        int o = n0 + c*16 + ll;
        if (o >= MMUO) continue;
        float bv = bias[o];
        #pragma unroll
        for (int r = 0; r < 4; r++) {
            int row = m0 + lg*4 + r;
            float v = acc[c][r] + bv;
            if      (o < MD)        qbf[(size_t)row*MD + o] = __float2bfloat16(v * 0.08838834764831845f);
            else if (o < 2*MD)      out[O_WKEY + (size_t)row*MD + (o -   MD)] = v;
            else if (o < 3*MD)      out[O_WVAL + (size_t)row*MD + (o - 2*MD)] = v;
            else if (o == 3*MD)     out[O_WGATE + row] = sigf(v);
            else if (o < 4*MD + 1)  out[O_SSDK + (size_t)row*MD + (o - (3*MD+1))] = v;
            else if (o < 5*MD + 1)  out[O_SSDV + (size_t)row*MD + (o - (4*MD+1))] = v;
            else                    out[O_SSDG + (size_t)row*3  + (o - (5*MD+1))] = v;
        }
    }
}

// ---------------- K1b: softmax over the 3 ssd_gate logits ----------------
__global__ void k_softmax3(float* __restrict__ out)
{
    int r = blockIdx.x*256 + threadIdx.x;
    if (r >= NROWS) return;
    float* p = out + O_SSDG + (size_t)r*3;
    float a = p[0], b = p[1], c = p[2];
    float m = fmaxf(a, fmaxf(b, c));
    float ea = __expf(a-m), eb = __expf(b-m), ec = __expf(c-m);
    float inv = 1.f/(ea+eb+ec);
    p[0] = ea*inv; p[1] = eb*inv; p[2] = ec*inv;
}

// ---------------- K2: split-K flash attention, 8 waves, defer-max ----------------
// 1024 blocks x 8 waves (512 thr). Block owns 16 q-rows; wave w handles keys
// [w*512,(w+1)*512) with deferred-max online softmax (THR=4): fast path has zero
// cross-lane ops; per-lane l partials reduced once at the end. Block combine
// accumulates the 8 partial O's into one LDS buffer in serialized rounds.
__global__ __launch_bounds__(512) void k_attn(const __hip_bfloat16* __restrict__ qb,
                                              const __hip_bfloat16* __restrict__ memB,
                                              const __hip_bfloat16* __restrict__ memT,
                                              __hip_bfloat16* __restrict__ rdb)
{
    __shared__ float Oacc[16][132];
    __shared__ float Ml[8][16], Ll[8][16];
    __shared__ __hip_bfloat16 Pl[8][16][40];
    const int t  = threadIdx.x;
    const int w  = t >> 6, l = t & 63;
    const int lg = l >> 4, ll = l & 15;
    // XCD swizzle: batch pinned to XCD (id & 7) -> each XCD L2 holds 2 batches
    const int bid  = blockIdx.x;
    const int xcd  = bid & 7, rest = bid >> 3;
    const int b    = xcd + ((rest >> 6) << 3);
    const int qblk = rest & 63;
    const int qrow0 = (b << 10) + (qblk << 4);
    const float THR = 4.0f;

    bf16x8 qf[4];
    {
        const short* qp = (const short*)qb + (size_t)(qrow0 + ll)*MD;
        #pragma unroll
        for (int ks = 0; ks < 4; ks++)
            qf[ks] = *(const bf16x8*)(qp + ks*32 + lg*8);
    }
    f32x4 O[8];
    #pragma unroll
    for (int dt = 0; dt < 8; dt++) O[dt] = (f32x4){0.f,0.f,0.f,0.f};
    float m_run[4], lsum[4];
    #pragma unroll
    for (int r = 0; r < 4; r++) { m_run[r] = -INFINITY; lsum[r] = 0.f; }

    const short* Mb = (const short*)memB + (size_t)b*MEMS*MD;
    const short* Mt = (const short*)memT + (size_t)b*MD*MEMS;
    const int k_beg = w << 9, k_end = k_beg + 512;

    for (int k0 = k_beg; k0 < k_end; k0 += 32) {
        // V fragments first (independent of QK/softmax -> overlaps latency)
        bf16x8 vb[8];
        #pragma unroll
        for (int dt = 0; dt < 8; dt++)
            vb[dt] = *(const bf16x8*)(Mt + (size_t)(dt*16 + ll)*MEMS + k0 + lg*8);
        // QK^T
        f32x4 s0 = (f32x4){0,0,0,0}, s1 = (f32x4){0,0,0,0};
        #pragma unroll
        for (int ks = 0; ks < 4; ks++) {
            bf16x8 b0 = *(const bf16x8*)(Mb + (size_t)(k0      + ll)*MD + ks*32 + lg*8);
            bf16x8 b1 = *(const bf16x8*)(Mb + (size_t)(k0 + 16 + ll)*MD + ks*32 + lg*8);
            s0 = __builtin_amdgcn_mfma_f32_16x16x32_bf16(qf[ks], b0, s0, 0, 0, 0);
            s1 = __builtin_amdgcn_mfma_f32_16x16x32_bf16(qf[ks], b1, s1, 0, 0, 0);
        }
        // defer-max check (fast path: no cross-lane ops at all)
        bool need = false;
        #pragma unroll
        for (int r = 0; r < 4; r++) {
            need |= (s0[r] > m_run[r] + THR);
            need |= (s1[r] > m_run[r] + THR);
        }
        if (__any(need)) {
            // slow path: true row max, rescale O and l partials
            #pragma unroll
            for (int r = 0; r < 4; r++) {
                float v = fmaxf(s0[r], s1[r]);
                v = fmaxf(v, __shfl_xor(v, 1));
                v = fmaxf(v, __shfl_xor(v, 2));
                v = fmaxf(v, __shfl_xor(v, 4));
                v = fmaxf(v, __shfl_xor(v, 8));
                float mnew = fmaxf(m_run[r], v);
                float alpha = __expf(m_run[r] - mnew);
                m_run[r] = mnew;
                lsum[r] *= alpha;
                #pragma unroll
                for (int dt = 0; dt < 8; dt++) O[dt][r] *= alpha;
            }
        }
        // P = exp(s - m_run), accumulate per-lane l partials
        #pragma unroll
        for (int r = 0; r < 4; r++) {
            float p0 = __expf(s0[r] - m_run[r]);
            float p1 = __expf(s1[r] - m_run[r]);
            Pl[w][lg*4 + r][ll]      = __float2bfloat16(p0);
            Pl[w][lg*4 + r][16 + ll] = __float2bfloat16(p1);
            lsum[r] += p0 + p1;
        }
        __builtin_amdgcn_wave_barrier();
        bf16x8 pa = *(const bf16x8*)(&Pl[w][ll][lg*8]);
        __builtin_amdgcn_wave_barrier();
        #pragma unroll
        for (int dt = 0; dt < 8; dt++)
            O[dt] = __builtin_amdgcn_mfma_f32_16x16x32_bf16(pa, vb[dt], O[dt], 0, 0, 0);
    }
    // reduce l partials across the 16 lanes sharing each row
    #pragma unroll
    for (int r = 0; r < 4; r++) {
        float s = lsum[r];
        s += __shfl_xor(s, 1);
        s += __shfl_xor(s, 2);
        s += __shfl_xor(s, 4);
        s += __shfl_xor(s, 8);
        lsum[r] = s;
    }
    if (ll == 0) {
        #pragma unroll
        for (int r = 0; r < 4; r++) { Ml[w][lg*4 + r] = m_run[r]; Ll[w][lg*4 + r] = lsum[r]; }
    }
    __syncthreads();
    // per-thread combine weight for its own rows
    float wgt[4];
    #pragma unroll
    for (int r = 0; r < 4; r++) {
        int row = lg*4 + r;
        float M = -INFINITY;
        #pragma unroll
        for (int i = 0; i < 8; i++) M = fmaxf(M, Ml[i][row]);
        wgt[r] = __expf(m_run[r] - M);
    }
    // serialized accumulation of 8 wave-partials into Oacc
    for (int i = 0; i < 8; i++) {
        if (w == i) {
            #pragma unroll
            for (int dt = 0; dt < 8; dt++)
                #pragma unroll
                for (int r = 0; r < 4; r++) {
                    float val = O[dt][r] * wgt[r];
                    if (i == 0) Oacc[lg*4 + r][dt*16 + ll]  = val;
                    else        Oacc[lg*4 + r][dt*16 + ll] += val;
                }
        }
        __syncthreads();
    }
    // final normalize + write: thread -> (row t>>5, 4 cols at (t&31)*4)
    const int tr = t >> 5, tc0 = (t & 31) * 4;
    float M = -INFINITY;
    #pragma unroll
    for (int i = 0; i < 8; i++) M = fmaxf(M, Ml[i][tr]);
    float L = 0.f;
    #pragma unroll
    for (int i = 0; i < 8; i++) L += __expf(Ml[i][tr] - M) * Ll[i][tr];
    float invL = 1.f / L;
    u16x4 ov;
    #pragma unroll
    for (int j = 0; j < 4; j++) ov[j] = bfu(Oacc[tr][tc0 + j] * invL);
    *(u16x4*)((unsigned short*)rdb + (size_t)(qrow0 + tr)*MD + tc0) = ov;
}

// ---------------- K3: fused GRU (MFMA) ----------------
__global__ __launch_bounds__(256) void k_gru(const __hip_bfloat16* __restrict__ inpb,
                                             const __hip_bfloat16* __restrict__ rdb,
                                             const __hip_bfloat16* __restrict__ regsb,
                                             const float* __restrict__ regs,
                                             const __hip_bfloat16* __restrict__ Wihb,
                                             const float* __restrict__ bih,
                                             const __hip_bfloat16* __restrict__ Whhb,
                                             const float* __restrict__ bhh,
                                             float* __restrict__ newregs,
                                             __hip_bfloat16* __restrict__ nregsb)
{
    const int t = threadIdx.x, w = t >> 6, l = t & 63;
    const int lg = l >> 4, ll = l & 15;
    const int m0 = blockIdx.x*64 + w*16;
    const int n0 = blockIdx.y*64;
    const int batch = blockIdx.x >> 4;
    const short* Xi = (const short*)inpb + (size_t)batch*INS;
    const short* Rd = (const short*)rdb;
    const short* Hb = (const short*)regsb;
    const short* Wi = (const short*)Wihb;
    const short* Wh = (const short*)Whhb;

    f32x4 aR[4], aZ[4], aNi[4], aNh[4];
    #pragma unroll
    for (int c = 0; c < 4; c++) {
        aR[c] = (f32x4){0,0,0,0}; aZ[c] = (f32x4){0,0,0,0};
        aNi[c] = (f32x4){0,0,0,0}; aNh[c] = (f32x4){0,0,0,0};
    }
    for (int k0 = 0; k0 < GRUIN; k0 += 32) {
        bf16x8 af;
        if (k0 < INS) af = *(const bf16x8*)(Xi + k0 + lg*8);
        else          af = *(const bf16x8*)(Rd + (size_t)(m0+ll)*MD + (k0 - INS) + lg*8);
        #pragma unroll
        for (int c = 0; c < 4; c++) {
            int n = n0 + c*16 + ll;
            bf16x8 bR = *(const bf16x8*)(Wi + (size_t)(n         )*GRUIN + k0 + lg*8);
            bf16x8 bZ = *(const bf16x8*)(Wi + (size_t)(n +   RS  )*GRUIN + k0 + lg*8);
            bf16x8 bN = *(const bf16x8*)(Wi + (size_t)(n + 2*RS  )*GRUIN + k0 + lg*8);
            aR[c]  = __builtin_amdgcn_mfma_f32_16x16x32_bf16(af, bR, aR[c],  0, 0, 0);
            aZ[c]  = __builtin_amdgcn_mfma_f32_16x16x32_bf16(af, bZ, aZ[c],  0, 0, 0);
            aNi[c] = __builtin_amdgcn_mfma_f32_16x16x32_bf16(af, bN, aNi[c], 0, 0, 0);
        }
    }
    for (int k0 = 0; k0 < RS; k0 += 32) {
        bf16x8 af = *(const bf16x8*)(Hb + (size_t)(m0+ll)*RS + k0 + lg*8);
        #pragma unroll
        for (int c = 0; c < 4; c++) {
            int n = n0 + c*16 + ll;
            bf16x8 bR = *(const bf16x8*)(Wh + (size_t)(n        )*RS + k0 + lg*8);
            bf16x8 bZ = *(const bf16x8*)(Wh + (size_t)(n +   RS )*RS + k0 + lg*8);
            bf16x8 bN = *(const bf16x8*)(Wh + (size_t)(n + 2*RS )*RS + k0 + lg*8);
            aR[c]  = __builtin_amdgcn_mfma_f32_16x16x32_bf16(af, bR, aR[c],  0, 0, 0);
            aZ[c]  = __builtin_amdgcn_mfma_f32_16x16x32_bf16(af, bZ, aZ[c],  0, 0, 0);
            aNh[c] = __builtin_amdgcn_mfma_f32_16x16x32_bf16(af, bN, aNh[c], 0, 0, 0);
        }
    }
    #pragma unroll
    for (int c = 0; c < 4; c++) {
        int o = n0 + c*16 + ll;
        float bR = bih[o]        + bhh[o];
        float bZ = bih[o +   RS] + bhh[o +   RS];
        float bNi = bih[o + 2*RS];
        float bNh = bhh[o + 2*RS];
        #pragma unroll
        for (int r = 0; r < 4; r++) {
            int row = m0 + lg*4 + r;
            float rr = sigf(aR[c][r] + bR);
            float zz = sigf(aZ[c][r] + bZ);
            float nn = tanhf(aNi[c][r] + bNi + rr*(aNh[c][r] + bNh));
            float cv = regs[(size_t)row*RS + o];
            float nv = (1.f - zz)*nn + zz*cv;
            newregs[(size_t)row*RS + o] = nv;
            nregsb[(size_t)row*RS + o] = __float2bfloat16(nv);
        }
    }
}

// ---------------- K4: output GEMM (MFMA) ----------------
__global__ __launch_bounds__(256) void k_out(const __hip_bfloat16* __restrict__ Ab,
                                             const __hip_bfloat16* __restrict__ Wb,
                                             const float* __restrict__ bias,
                                             float* __restrict__ out0)
{
    const int t = threadIdx.x, w = t >> 6, l = t & 63;
    const int lg = l >> 4, ll = l & 15;
    const int m0 = blockIdx.x*64 + w*16;
    const int n0 = blockIdx.y*256;
    const short* A = (const short*)Ab;
    const short* W = (const short*)Wb;
    f32x4 acc[16];
    #pragma unroll
    for (int c = 0; c < 16; c++) acc[c] = (f32x4){0,0,0,0};
    for (int k0 = 0; k0 < RS; k0 += 32) {
        bf16x8 af = *(const bf16x8*)(A + (size_t)(m0+ll)*RS + k0 + lg*8);
        #pragma unroll
        for (int c = 0; c < 16; c++) {
            int n = n0 + c*16 + ll;
            bf16x8 bf = *(const bf16x8*)(W + (size_t)n*RS + k0 + lg*8);
            acc[c] = __builtin_amdgcn_mfma_f32_16x16x32_bf16(af, bf, acc[c], 0, 0, 0);
        }
    }
    #pragma unroll
    for (int c = 0; c < 16; c++) {
        int o = n0 + c*16 + ll;
        float bv = bias[o];
        #pragma unroll
        for (int r = 0; r < 4; r++) {
            int row = m0 + lg*4 + r;
            out0[(size_t)row*INS + o] = acc[c][r] + bv;
        }
    }
}

extern "C" void kernel_launch(void* const* d_in, const int* in_sizes, int n_in,
                              void* d_out, int out_size, void* d_ws, size_t ws_size,
                              hipStream_t stream)
{
    const float* inp  = (const float*)d_in[0];
    const float* regs = (const float*)d_in[1];
    const float* mem  = (const float*)d_in[2];
    const float* Wih  = (const float*)d_in[3];
    const float* bih  = (const float*)d_in[4];
    const float* Whh  = (const float*)d_in[5];
    const float* bhh  = (const float*)d_in[6];
    const float* Wmmu = (const float*)d_in[7];
    const float* bmmu = (const float*)d_in[8];
    const float* Wout = (const float*)d_in[9];
    const float* bout = (const float*)d_in[10];
    float* out = (float*)d_out;

    char* ws = (char*)d_ws;
    __hip_bfloat16* qbf    = (__hip_bfloat16*)(ws);
    __hip_bfloat16* rdb    = (__hip_bfloat16*)(ws + ((size_t)4<<20));
    __hip_bfloat16* memB   = (__hip_bfloat16*)(ws + ((size_t)8<<20));
    __hip_bfloat16* memT   = (__hip_bfloat16*)(ws + ((size_t)24<<20));
    __hip_bfloat16* regsb  = (__hip_bfloat16*)(ws + ((size_t)40<<20));
    __hip_bfloat16* nregsb = (__hip_bfloat16*)(ws + ((size_t)48<<20));
    __hip_bfloat16* Wmmub  = (__hip_bfloat16*)(ws + ((size_t)56<<20));
    __hip_bfloat16* Wihb   = (__hip_bfloat16*)(ws + ((size_t)56<<20) + ( 1<<20));
    __hip_bfloat16* Whhb   = (__hip_bfloat16*)(ws + ((size_t)56<<20) + ( 2<<20));
    __hip_bfloat16* Woutb  = (__hip_bfloat16*)(ws + ((size_t)56<<20) + ( 3<<20));
    __hip_bfloat16* inpb   = (__hip_bfloat16*)(ws + ((size_t)56<<20) + ( 4<<20));

    k_cvt<<<(164864/4 + 255)/256, 256, 0, stream>>>(Wmmu, (unsigned short*)Wmmub, 164864/4);
    k_cvt<<<(491520/4 + 255)/256, 256, 0, stream>>>(Wih,  (unsigned short*)Wihb,  491520/4);
    k_cvt<<<(196608/4 + 255)/256, 256, 0, stream>>>(Whh,  (unsigned short*)Whhb,  196608/4);
    k_cvt<<<(131072/4 + 255)/256, 256, 0, stream>>>(Wout, (unsigned short*)Woutb, 131072/4);
    k_cvt<<<(8192/4   + 255)/256, 256, 0, stream>>>(inp,  (unsigned short*)inpb,  8192/4);
    k_cvt<<<(4194304/4+ 255)/256, 256, 0, stream>>>(regs, (unsigned short*)regsb, 4194304/4);
    k_conv<<<B_*128, 256, 0, stream>>>(mem, memB, memT);

    dim3 g1(NROWS/64, 3);
    k_mmu<<<g1, 256, 0, stream>>>(regsb, Wmmub, bmmu, out, qbf);
    k_softmax3<<<NROWS/256, 256, 0, stream>>>(out);
    k_attn<<<NROWS/16, 512, 0, stream>>>(qbf, memB, memT, rdb);
    dim3 g3(NROWS/64, 4);
    k_gru<<<g3, 256, 0, stream>>>(inpb, rdb, regsb, regs, Wihb, bih, Whhb, bhh,
                                  out + O_REGS, nregsb);
    dim3 g4(NROWS/64, 2);
    k_out<<<g4, 256, 0, stream>>>(nregsb, Woutb, bout, out);
}

// Round 6
// 538.139 us; speedup vs baseline: 1.0066x; 1.0066x over previous
//
#include <hip/hip_runtime.h>
#include <hip/hip_bf16.h>
#include <math.h>

#define B_      16
#define NPUS    1024
#define MEMS    4096
#define INS     512
#define RS      256
#define MD      128
#define GRUIN   640
#define MMUO    644
#define NROWS   (B_*NPUS)   // 16384

// d_out flat offsets (reference return order)
#define O_OUT   0u
#define O_REGS  8388608u
#define O_WKEY  12582912u
#define O_WVAL  14680064u
#define O_WGATE 16777216u
#define O_SSDK  16793600u
#define O_SSDV  18890752u
#define O_SSDG  20987904u

typedef __attribute__((ext_vector_type(8))) short bf16x8;
typedef __attribute__((ext_vector_type(4))) float f32x4;
typedef __attribute__((ext_vector_type(4))) unsigned short u16x4;

__device__ __forceinline__ float sigf(float x){ return 1.f/(1.f+__expf(-x)); }
__device__ __forceinline__ unsigned short bfu(float x){
    __hip_bfloat16 h = __float2bfloat16(x);
    return __builtin_bit_cast(unsigned short, h);
}

// ---------------- K_cvt: fp32 -> bf16, vectorized x4 ----------------
__global__ __launch_bounds__(256) void k_cvt(const float* __restrict__ src,
                                             unsigned short* __restrict__ dst, int n4)
{
    int i = blockIdx.x*256 + threadIdx.x;
    if (i >= n4) return;
    float4 v = ((const float4*)src)[i];
    u16x4 o = { bfu(v.x), bfu(v.y), bfu(v.z), bfu(v.w) };
    ((u16x4*)dst)[i] = o;
}

// ---------------- K0: memory_context -> bf16 row-major + transposed ----------------
__global__ __launch_bounds__(256) void k_conv(const float* __restrict__ mem,
                                              __hip_bfloat16* __restrict__ memB,
                                              __hip_bfloat16* __restrict__ memT)
{
    __shared__ float Ms[32][129];
    const int t = threadIdx.x;
    const int b = blockIdx.x >> 7;
    const int m0 = (blockIdx.x & 127) << 5;
    const float* src = mem + ((size_t)b*MEMS + m0)*MD;
    for (int idx = t; idx < 32*128; idx += 256) {
        int m = idx >> 7, d = idx & 127;
        float v = src[(size_t)m*MD + d];
        Ms[m][d] = v;
        memB[((size_t)b*MEMS + m0 + m)*MD + d] = __float2bfloat16(v);
    }
    __syncthreads();
    for (int idx = t; idx < 128*32; idx += 256) {
        int d = idx >> 5, m = idx & 31;
        memT[((size_t)b*MD + d)*MEMS + m0 + m] = __float2bfloat16(Ms[m][d]);
    }
}

// ---------------- K1: MMU GEMM (MFMA)  C[16384,644] = regs * Wmmu^T + b ----------------
__global__ __launch_bounds__(256) void k_mmu(const __hip_bfloat16* __restrict__ Ab,
                                             const __hip_bfloat16* __restrict__ Wb,
                                             const float* __restrict__ bias,
                                             float* __restrict__ out,
                                             __hip_bfloat16* __restrict__ qbf)
{
    const int t = threadIdx.x, w = t >> 6, l = t & 63;
    const int lg = l >> 4, ll = l & 15;
    const int m0 = blockIdx.x*64 + w*16;
    const int n0 = blockIdx.y*256;
    const short* A = (const short*)Ab;
    const short* W = (const short*)Wb;
    f32x4 acc[16];
    #pragma unroll
    for (int c = 0; c < 16; c++) acc[c] = (f32x4){0,0,0,0};
    for (int k0 = 0; k0 < RS; k0 += 32) {
        bf16x8 af = *(const bf16x8*)(A + (size_t)(m0+ll)*RS + k0 + lg*8);
        #pragma unroll
        for (int c = 0; c < 16; c++) {
            int n = n0 + c*16 + ll;
            bf16x8 bf = {};
            if (n < MMUO) bf = *(const bf16x8*)(W + (size_t)n*RS + k0 + lg*8);
            acc[c] = __builtin_amdgcn_mfma_f32_16x16x32_bf16(af, bf, acc[c], 0, 0, 0);
        }
    }
    #pragma unroll
    for (int c = 0; c < 16; c++) {
        int o = n0 + c*16 + ll;
        if (o >= MMUO) continue;
        float bv = bias[o];
        #pragma unroll
        for (int r = 0; r < 4; r++) {
            int row = m0 + lg*4 + r;
            float v = acc[c][r] + bv;
            if      (o < MD)        qbf[(size_t)row*MD + o] = __float2bfloat16(v * 0.08838834764831845f);
            else if (o < 2*MD)      out[O_WKEY + (size_t)row*MD + (o -   MD)] = v;
            else if (o < 3*MD)      out[O_WVAL + (size_t)row*MD + (o - 2*MD)] = v;
            else if (o == 3*MD)     out[O_WGATE + row] = sigf(v);
            else if (o < 4*MD + 1)  out[O_SSDK + (size_t)row*MD + (o - (3*MD+1))] = v;
            else if (o < 5*MD + 1)  out[O_SSDV + (size_t)row*MD + (o - (4*MD+1))] = v;
            else                    out[O_SSDG + (size_t)row*3  + (o - (5*MD+1))] = v;
        }
    }
}

// ---------------- K1b: softmax over the 3 ssd_gate logits ----------------
__global__ void k_softmax3(float* __restrict__ out)
{
    int r = blockIdx.x*256 + threadIdx.x;
    if (r >= NROWS) return;
    float* p = out + O_SSDG + (size_t)r*3;
    float a = p[0], b = p[1], c = p[2];
    float m = fmaxf(a, fmaxf(b, c));
    float ea = __expf(a-m), eb = __expf(b-m), ec = __expf(c-m);
    float inv = 1.f/(ea+eb+ec);
    p[0] = ea*inv; p[1] = eb*inv; p[2] = ec*inv;
}

// ---------------- K2: shared-stream flash attention ----------------
// 256 blocks (1/CU) x 4 waves. Block owns 64 q-rows (wave w: 16 rows); ALL waves
// stream the SAME full key range -> K/V fragment loads are identical addresses
// across waves (L1-shared; per-CU fresh traffic 2MB instead of 8MB). Defer-max
// softmax (THR=4): fast path has no cross-lane ops; l reduced once at the end.
// Batch pinned to XCD (bid&7): each XCD's L2 holds exactly its 2 batches (4MB).
__global__ __launch_bounds__(256) void k_attn(const __hip_bfloat16* __restrict__ qb,
                                              const __hip_bfloat16* __restrict__ memB,
                                              const __hip_bfloat16* __restrict__ memT,
                                              __hip_bfloat16* __restrict__ rdb)
{
    __shared__ __hip_bfloat16 Pl[4][16][40];
    const int t  = threadIdx.x;
    const int w  = t >> 6, l = t & 63;
    const int lg = l >> 4, ll = l & 15;
    const int bid  = blockIdx.x;
    const int xcd  = bid & 7, rest = bid >> 3;        // rest in [0,32)
    const int b    = xcd + ((rest >> 4) << 3);        // 2 batches per XCD
    const int qblk = rest & 15;                       // 16 q-blocks per batch
    const int qrow0 = (b << 10) + (qblk << 6) + (w << 4);
    const float THR = 4.0f;

    bf16x8 qf[4];
    {
        const short* qp = (const short*)qb + (size_t)(qrow0 + ll)*MD;
        #pragma unroll
        for (int ks = 0; ks < 4; ks++)
            qf[ks] = *(const bf16x8*)(qp + ks*32 + lg*8);
    }
    f32x4 O[8];
    #pragma unroll
    for (int dt = 0; dt < 8; dt++) O[dt] = (f32x4){0.f,0.f,0.f,0.f};
    float m_run[4], lsum[4];
    #pragma unroll
    for (int r = 0; r < 4; r++) { m_run[r] = -INFINITY; lsum[r] = 0.f; }

    const short* Mb = (const short*)memB + (size_t)b*MEMS*MD;
    const short* Mt = (const short*)memT + (size_t)b*MD*MEMS;

    for (int k0 = 0; k0 < MEMS; k0 += 32) {
        // V fragments first (independent of QK/softmax -> overlaps latency)
        bf16x8 vb[8];
        #pragma unroll
        for (int dt = 0; dt < 8; dt++)
            vb[dt] = *(const bf16x8*)(Mt + (size_t)(dt*16 + ll)*MEMS + k0 + lg*8);
        // QK^T
        f32x4 s0 = (f32x4){0,0,0,0}, s1 = (f32x4){0,0,0,0};
        #pragma unroll
        for (int ks = 0; ks < 4; ks++) {
            bf16x8 b0 = *(const bf16x8*)(Mb + (size_t)(k0      + ll)*MD + ks*32 + lg*8);
            bf16x8 b1 = *(const bf16x8*)(Mb + (size_t)(k0 + 16 + ll)*MD + ks*32 + lg*8);
            s0 = __builtin_amdgcn_mfma_f32_16x16x32_bf16(qf[ks], b0, s0, 0, 0, 0);
            s1 = __builtin_amdgcn_mfma_f32_16x16x32_bf16(qf[ks], b1, s1, 0, 0, 0);
        }
        // defer-max check (fast path: no cross-lane ops)
        bool need = false;
        #pragma unroll
        for (int r = 0; r < 4; r++) {
            need |= (s0[r] > m_run[r] + THR);
            need |= (s1[r] > m_run[r] + THR);
        }
        if (__any(need)) {
            #pragma unroll
            for (int r = 0; r < 4; r++) {
                float v = fmaxf(s0[r], s1[r]);
                v = fmaxf(v, __shfl_xor(v, 1));
                v = fmaxf(v, __shfl_xor(v, 2));
                v = fmaxf(v, __shfl_xor(v, 4));
                v = fmaxf(v, __shfl_xor(v, 8));
                float mnew = fmaxf(m_run[r], v);
                float alpha = __expf(m_run[r] - mnew);
                m_run[r] = mnew;
                lsum[r] *= alpha;
                #pragma unroll
                for (int dt = 0; dt < 8; dt++) O[dt][r] *= alpha;
            }
        }
        // P = exp(s - m_run), per-lane l partials
        #pragma unroll
        for (int r = 0; r < 4; r++) {
            float p0 = __expf(s0[r] - m_run[r]);
            float p1 = __expf(s1[r] - m_run[r]);
            Pl[w][lg*4 + r][ll]      = __float2bfloat16(p0);
            Pl[w][lg*4 + r][16 + ll] = __float2bfloat16(p1);
            lsum[r] += p0 + p1;
        }
        __builtin_amdgcn_wave_barrier();
        bf16x8 pa = *(const bf16x8*)(&Pl[w][ll][lg*8]);
        __builtin_amdgcn_wave_barrier();
        #pragma unroll
        for (int dt = 0; dt < 8; dt++)
            O[dt] = __builtin_amdgcn_mfma_f32_16x16x32_bf16(pa, vb[dt], O[dt], 0, 0, 0);
    }
    // final: reduce l across the 16 lanes sharing each row, normalize, write
    #pragma unroll
    for (int r = 0; r < 4; r++) {
        float s = lsum[r];
        s += __shfl_xor(s, 1);
        s += __shfl_xor(s, 2);
        s += __shfl_xor(s, 4);
        s += __shfl_xor(s, 8);
        lsum[r] = 1.f / s;
    }
    #pragma unroll
    for (int dt = 0; dt < 8; dt++) {
        #pragma unroll
        for (int r = 0; r < 4; r++)
            rdb[(size_t)(qrow0 + lg*4 + r)*MD + dt*16 + ll] = __float2bfloat16(O[dt][r] * lsum[r]);
    }
}

// ---------------- K3: fused GRU (MFMA) ----------------
__global__ __launch_bounds__(256) void k_gru(const __hip_bfloat16* __restrict__ inpb,
                                             const __hip_bfloat16* __restrict__ rdb,
                                             const __hip_bfloat16* __restrict__ regsb,
                                             const float* __restrict__ regs,
                                             const __hip_bfloat16* __restrict__ Wihb,
                                             const float* __restrict__ bih,
                                             const __hip_bfloat16* __restrict__ Whhb,
                                             const float* __restrict__ bhh,
                                             float* __restrict__ newregs,
                                             __hip_bfloat16* __restrict__ nregsb)
{
    const int t = threadIdx.x, w = t >> 6, l = t & 63;
    const int lg = l >> 4, ll = l & 15;
    const int m0 = blockIdx.x*64 + w*16;
    const int n0 = blockIdx.y*64;
    const int batch = blockIdx.x >> 4;
    const short* Xi = (const short*)inpb + (size_t)batch*INS;
    const short* Rd = (const short*)rdb;
    const short* Hb = (const short*)regsb;
    const short* Wi = (const short*)Wihb;
    const short* Wh = (const short*)Whhb;

    f32x4 aR[4], aZ[4], aNi[4], aNh[4];
    #pragma unroll
    for (int c = 0; c < 4; c++) {
        aR[c] = (f32x4){0,0,0,0}; aZ[c] = (f32x4){0,0,0,0};
        aNi[c] = (f32x4){0,0,0,0}; aNh[c] = (f32x4){0,0,0,0};
    }
    for (int k0 = 0; k0 < GRUIN; k0 += 32) {
        bf16x8 af;
        if (k0 < INS) af = *(const bf16x8*)(Xi + k0 + lg*8);
        else          af = *(const bf16x8*)(Rd + (size_t)(m0+ll)*MD + (k0 - INS) + lg*8);
        #pragma unroll
        for (int c = 0; c < 4; c++) {
            int n = n0 + c*16 + ll;
            bf16x8 bR = *(const bf16x8*)(Wi + (size_t)(n         )*GRUIN + k0 + lg*8);
            bf16x8 bZ = *(const bf16x8*)(Wi + (size_t)(n +   RS  )*GRUIN + k0 + lg*8);
            bf16x8 bN = *(const bf16x8*)(Wi + (size_t)(n + 2*RS  )*GRUIN + k0 + lg*8);
            aR[c]  = __builtin_amdgcn_mfma_f32_16x16x32_bf16(af, bR, aR[c],  0, 0, 0);
            aZ[c]  = __builtin_amdgcn_mfma_f32_16x16x32_bf16(af, bZ, aZ[c],  0, 0, 0);
            aNi[c] = __builtin_amdgcn_mfma_f32_16x16x32_bf16(af, bN, aNi[c], 0, 0, 0);
        }
    }
    for (int k0 = 0; k0 < RS; k0 += 32) {
        bf16x8 af = *(const bf16x8*)(Hb + (size_t)(m0+ll)*RS + k0 + lg*8);
        #pragma unroll
        for (int c = 0; c < 4; c++) {
            int n = n0 + c*16 + ll;
            bf16x8 bR = *(const bf16x8*)(Wh + (size_t)(n        )*RS + k0 + lg*8);
            bf16x8 bZ = *(const bf16x8*)(Wh + (size_t)(n +   RS )*RS + k0 + lg*8);
            bf16x8 bN = *(const bf16x8*)(Wh + (size_t)(n + 2*RS )*RS + k0 + lg*8);
            aR[c]  = __builtin_amdgcn_mfma_f32_16x16x32_bf16(af, bR, aR[c],  0, 0, 0);
            aZ[c]  = __builtin_amdgcn_mfma_f32_16x16x32_bf16(af, bZ, aZ[c],  0, 0, 0);
            aNh[c] = __builtin_amdgcn_mfma_f32_16x16x32_bf16(af, bN, aNh[c], 0, 0, 0);
        }
    }
    #pragma unroll
    for (int c = 0; c < 4; c++) {
        int o = n0 + c*16 + ll;
        float bR = bih[o]        + bhh[o];
        float bZ = bih[o +   RS] + bhh[o +   RS];
        float bNi = bih[o + 2*RS];
        float bNh = bhh[o + 2*RS];
        #pragma unroll
        for (int r = 0; r < 4; r++) {
            int row = m0 + lg*4 + r;
            float rr = sigf(aR[c][r] + bR);
            float zz = sigf(aZ[c][r] + bZ);
            float nn = tanhf(aNi[c][r] + bNi + rr*(aNh[c][r] + bNh));
            float cv = regs[(size_t)row*RS + o];
            float nv = (1.f - zz)*nn + zz*cv;
            newregs[(size_t)row*RS + o] = nv;
            nregsb[(size_t)row*RS + o] = __float2bfloat16(nv);
        }
    }
}

// ---------------- K4: output GEMM (MFMA) ----------------
__global__ __launch_bounds__(256) void k_out(const __hip_bfloat16* __restrict__ Ab,
                                             const __hip_bfloat16* __restrict__ Wb,
                                             const float* __restrict__ bias,
                                             float* __restrict__ out0)
{
    const int t = threadIdx.x, w = t >> 6, l = t & 63;
    const int lg = l >> 4, ll = l & 15;
    const int m0 = blockIdx.x*64 + w*16;
    const int n0 = blockIdx.y*256;
    const short* A = (const short*)Ab;
    const short* W = (const short*)Wb;
    f32x4 acc[16];
    #pragma unroll
    for (int c = 0; c < 16; c++) acc[c] = (f32x4){0,0,0,0};
    for (int k0 = 0; k0 < RS; k0 += 32) {
        bf16x8 af = *(const bf16x8*)(A + (size_t)(m0+ll)*RS + k0 + lg*8);
        #pragma unroll
        for (int c = 0; c < 16; c++) {
            int n = n0 + c*16 + ll;
            bf16x8 bf = *(const bf16x8*)(W + (size_t)n*RS + k0 + lg*8);
            acc[c] = __builtin_amdgcn_mfma_f32_16x16x32_bf16(af, bf, acc[c], 0, 0, 0);
        }
    }
    #pragma unroll
    for (int c = 0; c < 16; c++) {
        int o = n0 + c*16 + ll;
        float bv = bias[o];
        #pragma unroll
        for (int r = 0; r < 4; r++) {
            int row = m0 + lg*4 + r;
            out0[(size_t)row*INS + o] = acc[c][r] + bv;
        }
    }
}

extern "C" void kernel_launch(void* const* d_in, const int* in_sizes, int n_in,
                              void* d_out, int out_size, void* d_ws, size_t ws_size,
                              hipStream_t stream)
{
    const float* inp  = (const float*)d_in[0];
    const float* regs = (const float*)d_in[1];
    const float* mem  = (const float*)d_in[2];
    const float* Wih  = (const float*)d_in[3];
    const float* bih  = (const float*)d_in[4];
    const float* Whh  = (const float*)d_in[5];
    const float* bhh  = (const float*)d_in[6];
    const float* Wmmu = (const float*)d_in[7];
    const float* bmmu = (const float*)d_in[8];
    const float* Wout = (const float*)d_in[9];
    const float* bout = (const float*)d_in[10];
    float* out = (float*)d_out;

    char* ws = (char*)d_ws;
    __hip_bfloat16* qbf    = (__hip_bfloat16*)(ws);
    __hip_bfloat16* rdb    = (__hip_bfloat16*)(ws + ((size_t)4<<20));
    __hip_bfloat16* memB   = (__hip_bfloat16*)(ws + ((size_t)8<<20));
    __hip_bfloat16* memT   = (__hip_bfloat16*)(ws + ((size_t)24<<20));
    __hip_bfloat16* regsb  = (__hip_bfloat16*)(ws + ((size_t)40<<20));
    __hip_bfloat16* nregsb = (__hip_bfloat16*)(ws + ((size_t)48<<20));
    __hip_bfloat16* Wmmub  = (__hip_bfloat16*)(ws + ((size_t)56<<20));
    __hip_bfloat16* Wihb   = (__hip_bfloat16*)(ws + ((size_t)56<<20) + ( 1<<20));
    __hip_bfloat16* Whhb   = (__hip_bfloat16*)(ws + ((size_t)56<<20) + ( 2<<20));
    __hip_bfloat16* Woutb  = (__hip_bfloat16*)(ws + ((size_t)56<<20) + ( 3<<20));
    __hip_bfloat16* inpb   = (__hip_bfloat16*)(ws + ((size_t)56<<20) + ( 4<<20));

    k_cvt<<<(164864/4 + 255)/256, 256, 0, stream>>>(Wmmu, (unsigned short*)Wmmub, 164864/4);
    k_cvt<<<(491520/4 + 255)/256, 256, 0, stream>>>(Wih,  (unsigned short*)Wihb,  491520/4);
    k_cvt<<<(196608/4 + 255)/256, 256, 0, stream>>>(Whh,  (unsigned short*)Whhb,  196608/4);
    k_cvt<<<(131072/4 + 255)/256, 256, 0, stream>>>(Wout, (unsigned short*)Woutb, 131072/4);
    k_cvt<<<(8192/4   + 255)/256, 256, 0, stream>>>(inp,  (unsigned short*)inpb,  8192/4);
    k_cvt<<<(4194304/4+ 255)/256, 256, 0, stream>>>(regs, (unsigned short*)regsb, 4194304/4);
    k_conv<<<B_*128, 256, 0, stream>>>(mem, memB, memT);

    dim3 g1(NROWS/64, 3);
    k_mmu<<<g1, 256, 0, stream>>>(regsb, Wmmub, bmmu, out, qbf);
    k_softmax3<<<NROWS/256, 256, 0, stream>>>(out);
    k_attn<<<NROWS/64, 256, 0, stream>>>(qbf, memB, memT, rdb);
    dim3 g3(NROWS/64, 4);
    k_gru<<<g3, 256, 0, stream>>>(inpb, rdb, regsb, regs, Wihb, bih, Whhb, bhh,
                                  out + O_REGS, nregsb);
    dim3 g4(NROWS/64, 2);
    k_out<<<g4, 256, 0, stream>>>(nregsb, Woutb, bout, out);
}

// Round 7
// 399.073 us; speedup vs baseline: 1.3573x; 1.3485x over previous
//
#include <hip/hip_runtime.h>
#include <hip/hip_bf16.h>
#include <math.h>

#define B_      16
#define NPUS    1024
#define MEMS    4096
#define INS     512
#define RS      256
#define MD      128
#define GRUIN   640
#define MMUO    644
#define NROWS   (B_*NPUS)   // 16384

// d_out flat offsets (reference return order)
#define O_OUT   0u
#define O_REGS  8388608u
#define O_WKEY  12582912u
#define O_WVAL  14680064u
#define O_WGATE 16777216u
#define O_SSDK  16793600u
#define O_SSDV  18890752u
#define O_SSDG  20987904u

typedef __attribute__((ext_vector_type(8))) short bf16x8;
typedef __attribute__((ext_vector_type(4))) float f32x4;
typedef __attribute__((ext_vector_type(4))) unsigned short u16x4;

__device__ __forceinline__ float sigf(float x){ return 1.f/(1.f+__expf(-x)); }
__device__ __forceinline__ unsigned short bfu(float x){
    __hip_bfloat16 h = __float2bfloat16(x);
    return __builtin_bit_cast(unsigned short, h);
}
// async global->LDS, 16B per lane; LDS dest is wave-uniform base + lane*16 (m104)
__device__ __forceinline__ void gload16(const void* g, void* s)
{
    __builtin_amdgcn_global_load_lds(
        (const __attribute__((address_space(1))) void*)g,
        (__attribute__((address_space(3))) void*)s, 16, 0, 0);
}

// ---------------- K_cvt: fp32 -> bf16, vectorized x4 ----------------
__global__ __launch_bounds__(256) void k_cvt(const float* __restrict__ src,
                                             unsigned short* __restrict__ dst, int n4)
{
    int i = blockIdx.x*256 + threadIdx.x;
    if (i >= n4) return;
    float4 v = ((const float4*)src)[i];
    u16x4 o = { bfu(v.x), bfu(v.y), bfu(v.z), bfu(v.w) };
    ((u16x4*)dst)[i] = o;
}

// ---------------- K0: memory_context -> bf16 row-major + transposed ----------------
__global__ __launch_bounds__(256) void k_conv(const float* __restrict__ mem,
                                              __hip_bfloat16* __restrict__ memB,
                                              __hip_bfloat16* __restrict__ memT)
{
    __shared__ float Ms[32][129];
    const int t = threadIdx.x;
    const int b = blockIdx.x >> 7;
    const int m0 = (blockIdx.x & 127) << 5;
    const float* src = mem + ((size_t)b*MEMS + m0)*MD;
    for (int idx = t; idx < 32*128; idx += 256) {
        int m = idx >> 7, d = idx & 127;
        float v = src[(size_t)m*MD + d];
        Ms[m][d] = v;
        memB[((size_t)b*MEMS + m0 + m)*MD + d] = __float2bfloat16(v);
    }
    __syncthreads();
    for (int idx = t; idx < 128*32; idx += 256) {
        int d = idx >> 5, m = idx & 31;
        memT[((size_t)b*MD + d)*MEMS + m0 + m] = __float2bfloat16(Ms[m][d]);
    }
}

// ---------------- K1: MMU GEMM (MFMA)  C[16384,644] = regs * Wmmu^T + b ----------------
__global__ __launch_bounds__(256) void k_mmu(const __hip_bfloat16* __restrict__ Ab,
                                             const __hip_bfloat16* __restrict__ Wb,
                                             const float* __restrict__ bias,
                                             float* __restrict__ out,
                                             __hip_bfloat16* __restrict__ qbf)
{
    const int t = threadIdx.x, w = t >> 6, l = t & 63;
    const int lg = l >> 4, ll = l & 15;
    const int m0 = blockIdx.x*64 + w*16;
    const int n0 = blockIdx.y*256;
    const short* A = (const short*)Ab;
    const short* W = (const short*)Wb;
    f32x4 acc[16];
    #pragma unroll
    for (int c = 0; c < 16; c++) acc[c] = (f32x4){0,0,0,0};
    for (int k0 = 0; k0 < RS; k0 += 32) {
        bf16x8 af = *(const bf16x8*)(A + (size_t)(m0+ll)*RS + k0 + lg*8);
        #pragma unroll
        for (int c = 0; c < 16; c++) {
            int n = n0 + c*16 + ll;
            bf16x8 bf = {};
            if (n < MMUO) bf = *(const bf16x8*)(W + (size_t)n*RS + k0 + lg*8);
            acc[c] = __builtin_amdgcn_mfma_f32_16x16x32_bf16(af, bf, acc[c], 0, 0, 0);
        }
    }
    #pragma unroll
    for (int c = 0; c < 16; c++) {
        int o = n0 + c*16 + ll;
        if (o >= MMUO) continue;
        float bv = bias[o];
        #pragma unroll
        for (int r = 0; r < 4; r++) {
            int row = m0 + lg*4 + r;
            float v = acc[c][r] + bv;
            if      (o < MD)        qbf[(size_t)row*MD + o] = __float2bfloat16(v * 0.08838834764831845f);
            else if (o < 2*MD)      out[O_WKEY + (size_t)row*MD + (o -   MD)] = v;
            else if (o < 3*MD)      out[O_WVAL + (size_t)row*MD + (o - 2*MD)] = v;
            else if (o == 3*MD)     out[O_WGATE + row] = sigf(v);
            else if (o < 4*MD + 1)  out[O_SSDK + (size_t)row*MD + (o - (3*MD+1))] = v;
            else if (o < 5*MD + 1)  out[O_SSDV + (size_t)row*MD + (o - (4*MD+1))] = v;
            else                    out[O_SSDG + (size_t)row*3  + (o - (5*MD+1))] = v;
        }
    }
}

// ---------------- K1b: softmax over the 3 ssd_gate logits ----------------
__global__ void k_softmax3(float* __restrict__ out)
{
    int r = blockIdx.x*256 + threadIdx.x;
    if (r >= NROWS) return;
    float* p = out + O_SSDG + (size_t)r*3;
    float a = p[0], b = p[1], c = p[2];
    float m = fmaxf(a, fmaxf(b, c));
    float ea = __expf(a-m), eb = __expf(b-m), ec = __expf(c-m);
    float inv = 1.f/(ea+eb+ec);
    p[0] = ea*inv; p[1] = eb*inv; p[2] = ec*inv;
}

// ---------------- K2: LDS-staged split-K flash attention ----------------
// 256 blocks (1/CU) x 4 waves. Block: 128 q-rows (wave w: 32), keys [kh*2048,+2048).
// K+V tile (32 keys, 16KB) staged ONCE per block into double-buffered LDS via
// global_load_lds (K XOR-swizzled via pre-swizzled global src, V linear), barrier-
// synced so all 4 waves share it. Per-CU fresh traffic: 64 iters x 16KB = 1MB.
// Partials (O fp32, m, l) -> Opart/MLpart; k_comb merges the 2 key-halves.
__global__ __launch_bounds__(256) void k_attn(const __hip_bfloat16* __restrict__ qb,
                                              const __hip_bfloat16* __restrict__ memB,
                                              const __hip_bfloat16* __restrict__ memT,
                                              float* __restrict__ Opart,
                                              float* __restrict__ MLpart)
{
    __shared__ __hip_bfloat16 Kt[2][32][128];   // swizzled: row chunk c' = c ^ (row&7)
    __shared__ __hip_bfloat16 Vt[2][128][32];   // linear [d][key]
    __shared__ __hip_bfloat16 Pl[4][16][40];
    const int t = threadIdx.x, w = t >> 6, l = t & 63;
    const int lg = l >> 4, ll = l & 15;
    const int bid = blockIdx.x;
    const int xcd = bid & 7, rest = bid >> 3;      // rest 0..31
    const int b = xcd + ((rest >> 4) << 3);        // 2 batches per XCD
    const int sub = rest & 15;
    const int qblk = sub >> 1, kh = sub & 1;
    const int qrow0 = (b << 10) + (qblk << 7) + (w << 5);   // wave's 32 q-rows
    const int k_beg = kh << 11;                             // 2048 keys per half
    const float THR = 4.0f;

    const short* Q = (const short*)qb;
    bf16x8 qf[2][4];
    #pragma unroll
    for (int qs = 0; qs < 2; qs++)
        #pragma unroll
        for (int ks = 0; ks < 4; ks++)
            qf[qs][ks] = *(const bf16x8*)(Q + (size_t)(qrow0 + qs*16 + ll)*MD + ks*32 + lg*8);

    f32x4 O[2][8];
    #pragma unroll
    for (int qs = 0; qs < 2; qs++)
        #pragma unroll
        for (int dt = 0; dt < 8; dt++) O[qs][dt] = (f32x4){0.f,0.f,0.f,0.f};
    float m_run[2][4], lsum[2][4];
    #pragma unroll
    for (int qs = 0; qs < 2; qs++)
        #pragma unroll
        for (int r = 0; r < 4; r++) { m_run[qs][r] = -INFINITY; lsum[qs][r] = 0.f; }

    const char* MbB = (const char*)memB + (size_t)b*MEMS*MD*2;
    const char* MtB = (const char*)memT + (size_t)b*MD*MEMS*2;

    auto stage = [&](int buf, int it) {
        const int k0 = k_beg + it*32;
        char* kbase = (char*)(&Kt[buf][0][0]);
        char* vbase = (char*)(&Vt[buf][0][0]);
        #pragma unroll
        for (int j = 0; j < 2; j++) {
            int ci = (w << 7) + (j << 6) + l;        // chunk 0..511 (16B each)
            int krow = ci >> 4, cc = ci & 15;
            int gc = cc ^ (krow & 7);                // pre-swizzled global source
            gload16(MbB + (size_t)(k0 + krow)*256 + gc*16,
                    kbase + (size_t)((w << 7) + (j << 6))*16);
        }
        #pragma unroll
        for (int j = 0; j < 2; j++) {
            int ci = (w << 7) + (j << 6) + l;
            int drow = ci >> 2, cc = ci & 3;
            gload16(MtB + (size_t)drow*(MEMS*2) + (size_t)k0*2 + cc*16,
                    vbase + (size_t)((w << 7) + (j << 6))*16);
        }
    };

    stage(0, 0);
    asm volatile("s_waitcnt vmcnt(0)" ::: "memory");
    __syncthreads();
    int cur = 0;
    const int NIT = 2048/32;
    for (int it = 0; it < NIT; ++it) {
        if (it + 1 < NIT) stage(cur ^ 1, it + 1);
        const char* kbase = (const char*)(&Kt[cur][0][0]);
        const char* vbase = (const char*)(&Vt[cur][0][0]);
        // V frags early (independent of QK/softmax)
        bf16x8 vf[8];
        #pragma unroll
        for (int dt = 0; dt < 8; dt++)
            vf[dt] = *(const bf16x8*)(vbase + (size_t)(dt*16 + ll)*64 + lg*16);
        // QK^T: 2 qs x 2 key-halves
        f32x4 s[2][2];
        s[0][0]=(f32x4){0,0,0,0}; s[0][1]=(f32x4){0,0,0,0};
        s[1][0]=(f32x4){0,0,0,0}; s[1][1]=(f32x4){0,0,0,0};
        #pragma unroll
        for (int ks = 0; ks < 4; ks++) {
            int c0 = ks*4 + lg;
            int sw = (c0 ^ (ll & 7)) << 4;           // (16+ll)&7 == ll&7
            bf16x8 kf0 = *(const bf16x8*)(kbase + (size_t)ll*256 + sw);
            bf16x8 kf1 = *(const bf16x8*)(kbase + (size_t)(16 + ll)*256 + sw);
            s[0][0] = __builtin_amdgcn_mfma_f32_16x16x32_bf16(qf[0][ks], kf0, s[0][0], 0, 0, 0);
            s[1][0] = __builtin_amdgcn_mfma_f32_16x16x32_bf16(qf[1][ks], kf0, s[1][0], 0, 0, 0);
            s[0][1] = __builtin_amdgcn_mfma_f32_16x16x32_bf16(qf[0][ks], kf1, s[0][1], 0, 0, 0);
            s[1][1] = __builtin_amdgcn_mfma_f32_16x16x32_bf16(qf[1][ks], kf1, s[1][1], 0, 0, 0);
        }
        // defer-max (fast path: no cross-lane ops)
        bool need = false;
        #pragma unroll
        for (int qs = 0; qs < 2; qs++)
            #pragma unroll
            for (int r = 0; r < 4; r++) {
                need |= (s[qs][0][r] > m_run[qs][r] + THR);
                need |= (s[qs][1][r] > m_run[qs][r] + THR);
            }
        if (__any(need)) {
            #pragma unroll
            for (int qs = 0; qs < 2; qs++)
                #pragma unroll
                for (int r = 0; r < 4; r++) {
                    float v = fmaxf(s[qs][0][r], s[qs][1][r]);
                    v = fmaxf(v, __shfl_xor(v, 1));
                    v = fmaxf(v, __shfl_xor(v, 2));
                    v = fmaxf(v, __shfl_xor(v, 4));
                    v = fmaxf(v, __shfl_xor(v, 8));
                    float mnew = fmaxf(m_run[qs][r], v);
                    float alpha = __expf(m_run[qs][r] - mnew);
                    m_run[qs][r] = mnew;
                    lsum[qs][r] *= alpha;
                    #pragma unroll
                    for (int dt = 0; dt < 8; dt++) O[qs][dt][r] *= alpha;
                }
        }
        // P + PV per qs (Pl reused qs=0 then qs=1; wave-internal ordering)
        #pragma unroll
        for (int qs = 0; qs < 2; qs++) {
            #pragma unroll
            for (int r = 0; r < 4; r++) {
                float p0 = __expf(s[qs][0][r] - m_run[qs][r]);
                float p1 = __expf(s[qs][1][r] - m_run[qs][r]);
                Pl[w][lg*4 + r][ll]      = __float2bfloat16(p0);
                Pl[w][lg*4 + r][16 + ll] = __float2bfloat16(p1);
                lsum[qs][r] += p0 + p1;
            }
            __builtin_amdgcn_wave_barrier();
            bf16x8 pa = *(const bf16x8*)(&Pl[w][ll][lg*8]);
            __builtin_amdgcn_wave_barrier();
            #pragma unroll
            for (int dt = 0; dt < 8; dt++)
                O[qs][dt] = __builtin_amdgcn_mfma_f32_16x16x32_bf16(pa, vf[dt], O[qs][dt], 0, 0, 0);
        }
        asm volatile("s_waitcnt vmcnt(0)" ::: "memory");
        __syncthreads();
        cur ^= 1;
    }
    // reduce l partials across the 16 lanes per row
    #pragma unroll
    for (int qs = 0; qs < 2; qs++)
        #pragma unroll
        for (int r = 0; r < 4; r++) {
            float s = lsum[qs][r];
            s += __shfl_xor(s, 1);
            s += __shfl_xor(s, 2);
            s += __shfl_xor(s, 4);
            s += __shfl_xor(s, 8);
            lsum[qs][r] = s;
        }
    // write raw partials
    #pragma unroll
    for (int qs = 0; qs < 2; qs++)
        #pragma unroll
        for (int dt = 0; dt < 8; dt++)
            #pragma unroll
            for (int r = 0; r < 4; r++) {
                int row = qrow0 + qs*16 + lg*4 + r;
                Opart[((size_t)row*2 + kh)*128 + dt*16 + ll] = O[qs][dt][r];
            }
    if (ll == 0) {
        #pragma unroll
        for (int qs = 0; qs < 2; qs++)
            #pragma unroll
            for (int r = 0; r < 4; r++) {
                int row = qrow0 + qs*16 + lg*4 + r;
                MLpart[((size_t)row*2 + kh)*2 + 0] = m_run[qs][r];
                MLpart[((size_t)row*2 + kh)*2 + 1] = lsum[qs][r];
            }
    }
}

// ---------------- K2b: combine the 2 split-K partials -> rd bf16 ----------------
__global__ __launch_bounds__(256) void k_comb(const float* __restrict__ Opart,
                                              const float* __restrict__ MLpart,
                                              __hip_bfloat16* __restrict__ rdb)
{
    const int t = threadIdx.x;
    const int row = blockIdx.x*64 + (t >> 2);
    const int c0 = (t & 3) * 32;
    float m0 = MLpart[((size_t)row*2 + 0)*2 + 0];
    float l0 = MLpart[((size_t)row*2 + 0)*2 + 1];
    float m1 = MLpart[((size_t)row*2 + 1)*2 + 0];
    float l1 = MLpart[((size_t)row*2 + 1)*2 + 1];
    float M = fmaxf(m0, m1);
    float a0 = __expf(m0 - M), a1 = __expf(m1 - M);
    float invL = 1.f / (a0*l0 + a1*l1);
    a0 *= invL; a1 *= invL;
    const float4* p0 = (const float4*)(Opart + ((size_t)row*2 + 0)*128 + c0);
    const float4* p1 = (const float4*)(Opart + ((size_t)row*2 + 1)*128 + c0);
    unsigned short* dst = (unsigned short*)rdb + (size_t)row*128 + c0;
    #pragma unroll
    for (int j = 0; j < 8; j++) {
        float4 x = p0[j], y = p1[j];
        u16x4 o = { bfu(a0*x.x + a1*y.x), bfu(a0*x.y + a1*y.y),
                    bfu(a0*x.z + a1*y.z), bfu(a0*x.w + a1*y.w) };
        ((u16x4*)dst)[j] = o;
    }
}

// ---------------- K3: fused GRU (MFMA) ----------------
__global__ __launch_bounds__(256) void k_gru(const __hip_bfloat16* __restrict__ inpb,
                                             const __hip_bfloat16* __restrict__ rdb,
                                             const __hip_bfloat16* __restrict__ regsb,
                                             const float* __restrict__ regs,
                                             const __hip_bfloat16* __restrict__ Wihb,
                                             const float* __restrict__ bih,
                                             const __hip_bfloat16* __restrict__ Whhb,
                                             const float* __restrict__ bhh,
                                             float* __restrict__ newregs,
                                             __hip_bfloat16* __restrict__ nregsb)
{
    const int t = threadIdx.x, w = t >> 6, l = t & 63;
    const int lg = l >> 4, ll = l & 15;
    const int m0 = blockIdx.x*64 + w*16;
    const int n0 = blockIdx.y*64;
    const int batch = blockIdx.x >> 4;
    const short* Xi = (const short*)inpb + (size_t)batch*INS;
    const short* Rd = (const short*)rdb;
    const short* Hb = (const short*)regsb;
    const short* Wi = (const short*)Wihb;
    const short* Wh = (const short*)Whhb;

    f32x4 aR[4], aZ[4], aNi[4], aNh[4];
    #pragma unroll
    for (int c = 0; c < 4; c++) {
        aR[c] = (f32x4){0,0,0,0}; aZ[c] = (f32x4){0,0,0,0};
        aNi[c] = (f32x4){0,0,0,0}; aNh[c] = (f32x4){0,0,0,0};
    }
    for (int k0 = 0; k0 < GRUIN; k0 += 32) {
        bf16x8 af;
        if (k0 < INS) af = *(const bf16x8*)(Xi + k0 + lg*8);
        else          af = *(const bf16x8*)(Rd + (size_t)(m0+ll)*MD + (k0 - INS) + lg*8);
        #pragma unroll
        for (int c = 0; c < 4; c++) {
            int n = n0 + c*16 + ll;
            bf16x8 bR = *(const bf16x8*)(Wi + (size_t)(n         )*GRUIN + k0 + lg*8);
            bf16x8 bZ = *(const bf16x8*)(Wi + (size_t)(n +   RS  )*GRUIN + k0 + lg*8);
            bf16x8 bN = *(const bf16x8*)(Wi + (size_t)(n + 2*RS  )*GRUIN + k0 + lg*8);
            aR[c]  = __builtin_amdgcn_mfma_f32_16x16x32_bf16(af, bR, aR[c],  0, 0, 0);
            aZ[c]  = __builtin_amdgcn_mfma_f32_16x16x32_bf16(af, bZ, aZ[c],  0, 0, 0);
            aNi[c] = __builtin_amdgcn_mfma_f32_16x16x32_bf16(af, bN, aNi[c], 0, 0, 0);
        }
    }
    for (int k0 = 0; k0 < RS; k0 += 32) {
        bf16x8 af = *(const bf16x8*)(Hb + (size_t)(m0+ll)*RS + k0 + lg*8);
        #pragma unroll
        for (int c = 0; c < 4; c++) {
            int n = n0 + c*16 + ll;
            bf16x8 bR = *(const bf16x8*)(Wh + (size_t)(n        )*RS + k0 + lg*8);
            bf16x8 bZ = *(const bf16x8*)(Wh + (size_t)(n +   RS )*RS + k0 + lg*8);
            bf16x8 bN = *(const bf16x8*)(Wh + (size_t)(n + 2*RS )*RS + k0 + lg*8);
            aR[c]  = __builtin_amdgcn_mfma_f32_16x16x32_bf16(af, bR, aR[c],  0, 0, 0);
            aZ[c]  = __builtin_amdgcn_mfma_f32_16x16x32_bf16(af, bZ, aZ[c],  0, 0, 0);
            aNh[c] = __builtin_amdgcn_mfma_f32_16x16x32_bf16(af, bN, aNh[c], 0, 0, 0);
        }
    }
    #pragma unroll
    for (int c = 0; c < 4; c++) {
        int o = n0 + c*16 + ll;
        float bR = bih[o]        + bhh[o];
        float bZ = bih[o +   RS] + bhh[o +   RS];
        float bNi = bih[o + 2*RS];
        float bNh = bhh[o + 2*RS];
        #pragma unroll
        for (int r = 0; r < 4; r++) {
            int row = m0 + lg*4 + r;
            float rr = sigf(aR[c][r] + bR);
            float zz = sigf(aZ[c][r] + bZ);
            float nn = tanhf(aNi[c][r] + bNi + rr*(aNh[c][r] + bNh));
            float cv = regs[(size_t)row*RS + o];
            float nv = (1.f - zz)*nn + zz*cv;
            newregs[(size_t)row*RS + o] = nv;
            nregsb[(size_t)row*RS + o] = __float2bfloat16(nv);
        }
    }
}

// ---------------- K4: output GEMM (MFMA) ----------------
__global__ __launch_bounds__(256) void k_out(const __hip_bfloat16* __restrict__ Ab,
                                             const __hip_bfloat16* __restrict__ Wb,
                                             const float* __restrict__ bias,
                                             float* __restrict__ out0)
{
    const int t = threadIdx.x, w = t >> 6, l = t & 63;
    const int lg = l >> 4, ll = l & 15;
    const int m0 = blockIdx.x*64 + w*16;
    const int n0 = blockIdx.y*256;
    const short* A = (const short*)Ab;
    const short* W = (const short*)Wb;
    f32x4 acc[16];
    #pragma unroll
    for (int c = 0; c < 16; c++) acc[c] = (f32x4){0,0,0,0};
    for (int k0 = 0; k0 < RS; k0 += 32) {
        bf16x8 af = *(const bf16x8*)(A + (size_t)(m0+ll)*RS + k0 + lg*8);
        #pragma unroll
        for (int c = 0; c < 16; c++) {
            int n = n0 + c*16 + ll;
            bf16x8 bf = *(const bf16x8*)(W + (size_t)n*RS + k0 + lg*8);
            acc[c] = __builtin_amdgcn_mfma_f32_16x16x32_bf16(af, bf, acc[c], 0, 0, 0);
        }
    }
    #pragma unroll
    for (int c = 0; c < 16; c++) {
        int o = n0 + c*16 + ll;
        float bv = bias[o];
        #pragma unroll
        for (int r = 0; r < 4; r++) {
            int row = m0 + lg*4 + r;
            out0[(size_t)row*INS + o] = acc[c][r] + bv;
        }
    }
}

extern "C" void kernel_launch(void* const* d_in, const int* in_sizes, int n_in,
                              void* d_out, int out_size, void* d_ws, size_t ws_size,
                              hipStream_t stream)
{
    const float* inp  = (const float*)d_in[0];
    const float* regs = (const float*)d_in[1];
    const float* mem  = (const float*)d_in[2];
    const float* Wih  = (const float*)d_in[3];
    const float* bih  = (const float*)d_in[4];
    const float* Whh  = (const float*)d_in[5];
    const float* bhh  = (const float*)d_in[6];
    const float* Wmmu = (const float*)d_in[7];
    const float* bmmu = (const float*)d_in[8];
    const float* Wout = (const float*)d_in[9];
    const float* bout = (const float*)d_in[10];
    float* out = (float*)d_out;

    char* ws = (char*)d_ws;
    __hip_bfloat16* qbf    = (__hip_bfloat16*)(ws);
    __hip_bfloat16* rdb    = (__hip_bfloat16*)(ws + ((size_t)4<<20));
    __hip_bfloat16* memB   = (__hip_bfloat16*)(ws + ((size_t)8<<20));
    __hip_bfloat16* memT   = (__hip_bfloat16*)(ws + ((size_t)24<<20));
    __hip_bfloat16* regsb  = (__hip_bfloat16*)(ws + ((size_t)40<<20));
    __hip_bfloat16* nregsb = (__hip_bfloat16*)(ws + ((size_t)48<<20));
    __hip_bfloat16* Wmmub  = (__hip_bfloat16*)(ws + ((size_t)56<<20));
    __hip_bfloat16* Wihb   = (__hip_bfloat16*)(ws + ((size_t)56<<20) + ( 1<<20));
    __hip_bfloat16* Whhb   = (__hip_bfloat16*)(ws + ((size_t)56<<20) + ( 2<<20));
    __hip_bfloat16* Woutb  = (__hip_bfloat16*)(ws + ((size_t)56<<20) + ( 3<<20));
    __hip_bfloat16* inpb   = (__hip_bfloat16*)(ws + ((size_t)56<<20) + ( 4<<20));
    float*          MLpart = (float*)(ws + ((size_t)61<<20));            // 256 KB
    // split-K O partials live in the out0 region (unused until k_out): 16 MB < 32 MB
    float*          Opart  = out + O_OUT;

    k_cvt<<<(164864/4 + 255)/256, 256, 0, stream>>>(Wmmu, (unsigned short*)Wmmub, 164864/4);
    k_cvt<<<(491520/4 + 255)/256, 256, 0, stream>>>(Wih,  (unsigned short*)Wihb,  491520/4);
    k_cvt<<<(196608/4 + 255)/256, 256, 0, stream>>>(Whh,  (unsigned short*)Whhb,  196608/4);
    k_cvt<<<(131072/4 + 255)/256, 256, 0, stream>>>(Wout, (unsigned short*)Woutb, 131072/4);
    k_cvt<<<(8192/4   + 255)/256, 256, 0, stream>>>(inp,  (unsigned short*)inpb,  8192/4);
    k_cvt<<<(4194304/4+ 255)/256, 256, 0, stream>>>(regs, (unsigned short*)regsb, 4194304/4);
    k_conv<<<B_*128, 256, 0, stream>>>(mem, memB, memT);

    dim3 g1(NROWS/64, 3);
    k_mmu<<<g1, 256, 0, stream>>>(regsb, Wmmub, bmmu, out, qbf);
    k_softmax3<<<NROWS/256, 256, 0, stream>>>(out);
    k_attn<<<256, 256, 0, stream>>>(qbf, memB, memT, Opart, MLpart);
    k_comb<<<NROWS/64, 256, 0, stream>>>(Opart, MLpart, rdb);
    dim3 g3(NROWS/64, 4);
    k_gru<<<g3, 256, 0, stream>>>(inpb, rdb, regsb, regs, Wihb, bih, Whhb, bhh,
                                  out + O_REGS, nregsb);
    dim3 g4(NROWS/64, 2);
    k_out<<<g4, 256, 0, stream>>>(nregsb, Woutb, bout, out);
}

// Round 8
// 307.808 us; speedup vs baseline: 1.7598x; 1.2965x over previous
//
#include <hip/hip_runtime.h>
#include <hip/hip_bf16.h>
#include <math.h>

#define B_      16
#define NPUS    1024
#define MEMS    4096
#define INS     512
#define RS      256
#define MD      128
#define GRUIN   640
#define MMUO    644
#define NROWS   (B_*NPUS)   // 16384

// d_out flat offsets (reference return order)
#define O_OUT   0u
#define O_REGS  8388608u
#define O_WKEY  12582912u
#define O_WVAL  14680064u
#define O_WGATE 16777216u
#define O_SSDK  16793600u
#define O_SSDV  18890752u
#define O_SSDG  20987904u

typedef __attribute__((ext_vector_type(8))) short bf16x8;
typedef __attribute__((ext_vector_type(4))) float f32x4;
typedef __attribute__((ext_vector_type(4))) unsigned short u16x4;

__device__ __forceinline__ float sigf(float x){ return 1.f/(1.f+__expf(-x)); }
__device__ __forceinline__ unsigned short bfu(float x){
    __hip_bfloat16 h = __float2bfloat16(x);
    return __builtin_bit_cast(unsigned short, h);
}
// async global->LDS, 16B per lane; LDS dest is wave-uniform base + lane*16 (m104)
__device__ __forceinline__ void gload16(const void* g, void* s)
{
    __builtin_amdgcn_global_load_lds(
        (const __attribute__((address_space(1))) void*)g,
        (__attribute__((address_space(3))) void*)s, 16, 0, 0);
}

// ---------------- K_cvt: fp32 -> bf16, vectorized x4 ----------------
__global__ __launch_bounds__(256) void k_cvt(const float* __restrict__ src,
                                             unsigned short* __restrict__ dst, int n4)
{
    int i = blockIdx.x*256 + threadIdx.x;
    if (i >= n4) return;
    float4 v = ((const float4*)src)[i];
    u16x4 o = { bfu(v.x), bfu(v.y), bfu(v.z), bfu(v.w) };
    ((u16x4*)dst)[i] = o;
}

// ---------------- K0: memory_context -> bf16 row-major + transposed ----------------
__global__ __launch_bounds__(256) void k_conv(const float* __restrict__ mem,
                                              __hip_bfloat16* __restrict__ memB,
                                              __hip_bfloat16* __restrict__ memT)
{
    __shared__ float Ms[32][129];
    const int t = threadIdx.x;
    const int b = blockIdx.x >> 7;
    const int m0 = (blockIdx.x & 127) << 5;
    const float* src = mem + ((size_t)b*MEMS + m0)*MD;
    for (int idx = t; idx < 32*128; idx += 256) {
        int m = idx >> 7, d = idx & 127;
        float v = src[(size_t)m*MD + d];
        Ms[m][d] = v;
        memB[((size_t)b*MEMS + m0 + m)*MD + d] = __float2bfloat16(v);
    }
    __syncthreads();
    for (int idx = t; idx < 128*32; idx += 256) {
        int d = idx >> 5, m = idx & 31;
        memT[((size_t)b*MD + d)*MEMS + m0 + m] = __float2bfloat16(Ms[m][d]);
    }
}

// ---------------- K1: MMU GEMM (MFMA)  C[16384,644] = regs * Wmmu^T + b ----------------
__global__ __launch_bounds__(256) void k_mmu(const __hip_bfloat16* __restrict__ Ab,
                                             const __hip_bfloat16* __restrict__ Wb,
                                             const float* __restrict__ bias,
                                             float* __restrict__ out,
                                             __hip_bfloat16* __restrict__ qbf)
{
    const int t = threadIdx.x, w = t >> 6, l = t & 63;
    const int lg = l >> 4, ll = l & 15;
    const int m0 = blockIdx.x*64 + w*16;
    const int n0 = blockIdx.y*256;
    const short* A = (const short*)Ab;
    const short* W = (const short*)Wb;
    f32x4 acc[16];
    #pragma unroll
    for (int c = 0; c < 16; c++) acc[c] = (f32x4){0,0,0,0};
    for (int k0 = 0; k0 < RS; k0 += 32) {
        bf16x8 af = *(const bf16x8*)(A + (size_t)(m0+ll)*RS + k0 + lg*8);
        #pragma unroll
        for (int c = 0; c < 16; c++) {
            int n = n0 + c*16 + ll;
            bf16x8 bf = {};
            if (n < MMUO) bf = *(const bf16x8*)(W + (size_t)n*RS + k0 + lg*8);
            acc[c] = __builtin_amdgcn_mfma_f32_16x16x32_bf16(af, bf, acc[c], 0, 0, 0);
        }
    }
    #pragma unroll
    for (int c = 0; c < 16; c++) {
        int o = n0 + c*16 + ll;
        if (o >= MMUO) continue;
        float bv = bias[o];
        #pragma unroll
        for (int r = 0; r < 4; r++) {
            int row = m0 + lg*4 + r;
            float v = acc[c][r] + bv;
            if      (o < MD)        qbf[(size_t)row*MD + o] = __float2bfloat16(v * 0.08838834764831845f);
            else if (o < 2*MD)      out[O_WKEY + (size_t)row*MD + (o -   MD)] = v;
            else if (o < 3*MD)      out[O_WVAL + (size_t)row*MD + (o - 2*MD)] = v;
            else if (o == 3*MD)     out[O_WGATE + row] = sigf(v);
            else if (o < 4*MD + 1)  out[O_SSDK + (size_t)row*MD + (o - (3*MD+1))] = v;
            else if (o < 5*MD + 1)  out[O_SSDV + (size_t)row*MD + (o - (4*MD+1))] = v;
            else                    out[O_SSDG + (size_t)row*3  + (o - (5*MD+1))] = v;
        }
    }
}

// ---------------- K1b: softmax over the 3 ssd_gate logits ----------------
__global__ void k_softmax3(float* __restrict__ out)
{
    int r = blockIdx.x*256 + threadIdx.x;
    if (r >= NROWS) return;
    float* p = out + O_SSDG + (size_t)r*3;
    float a = p[0], b = p[1], c = p[2];
    float m = fmaxf(a, fmaxf(b, c));
    float ea = __expf(a-m), eb = __expf(b-m), ec = __expf(c-m);
    float inv = 1.f/(ea+eb+ec);
    p[0] = ea*inv; p[1] = eb*inv; p[2] = ec*inv;
}

// ---------------- K2: LDS-staged split-K flash attention ----------------
__global__ __launch_bounds__(256) void k_attn(const __hip_bfloat16* __restrict__ qb,
                                              const __hip_bfloat16* __restrict__ memB,
                                              const __hip_bfloat16* __restrict__ memT,
                                              float* __restrict__ Opart,
                                              float* __restrict__ MLpart)
{
    __shared__ __hip_bfloat16 Kt[2][32][128];   // swizzled: row chunk c' = c ^ (row&7)
    __shared__ __hip_bfloat16 Vt[2][128][32];   // linear [d][key]
    __shared__ __hip_bfloat16 Pl[4][16][40];
    const int t = threadIdx.x, w = t >> 6, l = t & 63;
    const int lg = l >> 4, ll = l & 15;
    const int bid = blockIdx.x;
    const int xcd = bid & 7, rest = bid >> 3;      // rest 0..31
    const int b = xcd + ((rest >> 4) << 3);        // 2 batches per XCD
    const int sub = rest & 15;
    const int qblk = sub >> 1, kh = sub & 1;
    const int qrow0 = (b << 10) + (qblk << 7) + (w << 5);   // wave's 32 q-rows
    const int k_beg = kh << 11;                             // 2048 keys per half
    const float THR = 4.0f;

    const short* Q = (const short*)qb;
    bf16x8 qf[2][4];
    #pragma unroll
    for (int qs = 0; qs < 2; qs++)
        #pragma unroll
        for (int ks = 0; ks < 4; ks++)
            qf[qs][ks] = *(const bf16x8*)(Q + (size_t)(qrow0 + qs*16 + ll)*MD + ks*32 + lg*8);

    f32x4 O[2][8];
    #pragma unroll
    for (int qs = 0; qs < 2; qs++)
        #pragma unroll
        for (int dt = 0; dt < 8; dt++) O[qs][dt] = (f32x4){0.f,0.f,0.f,0.f};
    float m_run[2][4], lsum[2][4];
    #pragma unroll
    for (int qs = 0; qs < 2; qs++)
        #pragma unroll
        for (int r = 0; r < 4; r++) { m_run[qs][r] = -INFINITY; lsum[qs][r] = 0.f; }

    const char* MbB = (const char*)memB + (size_t)b*MEMS*MD*2;
    const char* MtB = (const char*)memT + (size_t)b*MD*MEMS*2;

    auto stage = [&](int buf, int it) {
        const int k0 = k_beg + it*32;
        char* kbase = (char*)(&Kt[buf][0][0]);
        char* vbase = (char*)(&Vt[buf][0][0]);
        #pragma unroll
        for (int j = 0; j < 2; j++) {
            int ci = (w << 7) + (j << 6) + l;        // chunk 0..511 (16B each)
            int krow = ci >> 4, cc = ci & 15;
            int gc = cc ^ (krow & 7);                // pre-swizzled global source
            gload16(MbB + (size_t)(k0 + krow)*256 + gc*16,
                    kbase + (size_t)((w << 7) + (j << 6))*16);
        }
        #pragma unroll
        for (int j = 0; j < 2; j++) {
            int ci = (w << 7) + (j << 6) + l;
            int drow = ci >> 2, cc = ci & 3;
            gload16(MtB + (size_t)drow*(MEMS*2) + (size_t)k0*2 + cc*16,
                    vbase + (size_t)((w << 7) + (j << 6))*16);
        }
    };

    stage(0, 0);
    asm volatile("s_waitcnt vmcnt(0)" ::: "memory");
    __syncthreads();
    int cur = 0;
    const int NIT = 2048/32;
    for (int it = 0; it < NIT; ++it) {
        if (it + 1 < NIT) stage(cur ^ 1, it + 1);
        const char* kbase = (const char*)(&Kt[cur][0][0]);
        const char* vbase = (const char*)(&Vt[cur][0][0]);
        bf16x8 vf[8];
        #pragma unroll
        for (int dt = 0; dt < 8; dt++)
            vf[dt] = *(const bf16x8*)(vbase + (size_t)(dt*16 + ll)*64 + lg*16);
        f32x4 s[2][2];
        s[0][0]=(f32x4){0,0,0,0}; s[0][1]=(f32x4){0,0,0,0};
        s[1][0]=(f32x4){0,0,0,0}; s[1][1]=(f32x4){0,0,0,0};
        #pragma unroll
        for (int ks = 0; ks < 4; ks++) {
            int c0 = ks*4 + lg;
            int sw = (c0 ^ (ll & 7)) << 4;
            bf16x8 kf0 = *(const bf16x8*)(kbase + (size_t)ll*256 + sw);
            bf16x8 kf1 = *(const bf16x8*)(kbase + (size_t)(16 + ll)*256 + sw);
            s[0][0] = __builtin_amdgcn_mfma_f32_16x16x32_bf16(qf[0][ks], kf0, s[0][0], 0, 0, 0);
            s[1][0] = __builtin_amdgcn_mfma_f32_16x16x32_bf16(qf[1][ks], kf0, s[1][0], 0, 0, 0);
            s[0][1] = __builtin_amdgcn_mfma_f32_16x16x32_bf16(qf[0][ks], kf1, s[0][1], 0, 0, 0);
            s[1][1] = __builtin_amdgcn_mfma_f32_16x16x32_bf16(qf[1][ks], kf1, s[1][1], 0, 0, 0);
        }
        bool need = false;
        #pragma unroll
        for (int qs = 0; qs < 2; qs++)
            #pragma unroll
            for (int r = 0; r < 4; r++) {
                need |= (s[qs][0][r] > m_run[qs][r] + THR);
                need |= (s[qs][1][r] > m_run[qs][r] + THR);
            }
        if (__any(need)) {
            #pragma unroll
            for (int qs = 0; qs < 2; qs++)
                #pragma unroll
                for (int r = 0; r < 4; r++) {
                    float v = fmaxf(s[qs][0][r], s[qs][1][r]);
                    v = fmaxf(v, __shfl_xor(v, 1));
                    v = fmaxf(v, __shfl_xor(v, 2));
                    v = fmaxf(v, __shfl_xor(v, 4));
                    v = fmaxf(v, __shfl_xor(v, 8));
                    float mnew = fmaxf(m_run[qs][r], v);
                    float alpha = __expf(m_run[qs][r] - mnew);
                    m_run[qs][r] = mnew;
                    lsum[qs][r] *= alpha;
                    #pragma unroll
                    for (int dt = 0; dt < 8; dt++) O[qs][dt][r] *= alpha;
                }
        }
        #pragma unroll
        for (int qs = 0; qs < 2; qs++) {
            #pragma unroll
            for (int r = 0; r < 4; r++) {
                float p0 = __expf(s[qs][0][r] - m_run[qs][r]);
                float p1 = __expf(s[qs][1][r] - m_run[qs][r]);
                Pl[w][lg*4 + r][ll]      = __float2bfloat16(p0);
                Pl[w][lg*4 + r][16 + ll] = __float2bfloat16(p1);
                lsum[qs][r] += p0 + p1;
            }
            __builtin_amdgcn_wave_barrier();
            bf16x8 pa = *(const bf16x8*)(&Pl[w][ll][lg*8]);
            __builtin_amdgcn_wave_barrier();
            #pragma unroll
            for (int dt = 0; dt < 8; dt++)
                O[qs][dt] = __builtin_amdgcn_mfma_f32_16x16x32_bf16(pa, vf[dt], O[qs][dt], 0, 0, 0);
        }
        asm volatile("s_waitcnt vmcnt(0)" ::: "memory");
        __syncthreads();
        cur ^= 1;
    }
    #pragma unroll
    for (int qs = 0; qs < 2; qs++)
        #pragma unroll
        for (int r = 0; r < 4; r++) {
            float s = lsum[qs][r];
            s += __shfl_xor(s, 1);
            s += __shfl_xor(s, 2);
            s += __shfl_xor(s, 4);
            s += __shfl_xor(s, 8);
            lsum[qs][r] = s;
        }
    #pragma unroll
    for (int qs = 0; qs < 2; qs++)
        #pragma unroll
        for (int dt = 0; dt < 8; dt++)
            #pragma unroll
            for (int r = 0; r < 4; r++) {
                int row = qrow0 + qs*16 + lg*4 + r;
                Opart[((size_t)row*2 + kh)*128 + dt*16 + ll] = O[qs][dt][r];
            }
    if (ll == 0) {
        #pragma unroll
        for (int qs = 0; qs < 2; qs++)
            #pragma unroll
            for (int r = 0; r < 4; r++) {
                int row = qrow0 + qs*16 + lg*4 + r;
                MLpart[((size_t)row*2 + kh)*2 + 0] = m_run[qs][r];
                MLpart[((size_t)row*2 + kh)*2 + 1] = lsum[qs][r];
            }
    }
}

// ---------------- K2b: combine the 2 split-K partials -> rd bf16 ----------------
__global__ __launch_bounds__(256) void k_comb(const float* __restrict__ Opart,
                                              const float* __restrict__ MLpart,
                                              __hip_bfloat16* __restrict__ rdb)
{
    const int t = threadIdx.x;
    const int row = blockIdx.x*64 + (t >> 2);
    const int c0 = (t & 3) * 32;
    float m0 = MLpart[((size_t)row*2 + 0)*2 + 0];
    float l0 = MLpart[((size_t)row*2 + 0)*2 + 1];
    float m1 = MLpart[((size_t)row*2 + 1)*2 + 0];
    float l1 = MLpart[((size_t)row*2 + 1)*2 + 1];
    float M = fmaxf(m0, m1);
    float a0 = __expf(m0 - M), a1 = __expf(m1 - M);
    float invL = 1.f / (a0*l0 + a1*l1);
    a0 *= invL; a1 *= invL;
    const float4* p0 = (const float4*)(Opart + ((size_t)row*2 + 0)*128 + c0);
    const float4* p1 = (const float4*)(Opart + ((size_t)row*2 + 1)*128 + c0);
    unsigned short* dst = (unsigned short*)rdb + (size_t)row*128 + c0;
    #pragma unroll
    for (int j = 0; j < 8; j++) {
        float4 x = p0[j], y = p1[j];
        u16x4 o = { bfu(a0*x.x + a1*y.x), bfu(a0*x.y + a1*y.y),
                    bfu(a0*x.z + a1*y.z), bfu(a0*x.w + a1*y.w) };
        ((u16x4*)dst)[j] = o;
    }
}

// ---------------- K3: fused GRU (MFMA, LDS-staged double-buffered GEMM) ----------------
// 1024 blocks (256x4) x 4 waves. Block: 64 rows x 64 output-cols (x3 gates).
// Per k-step: A-tile [64][32] (4KB) + B-tile [192][32] (12KB) staged via
// global_load_lds, double-buffered (32KB). XOR slot swizzle s=(row>>1)&3 on the
// 64B rows -> frag reads are 2-way (free). Phase1 K=640 (x=[inp|rd], Wih -> Ni),
// phase2 K=256 (h, Whh -> Nh). Epilogue computes gates and writes newregs.
__global__ __launch_bounds__(256) void k_gru(const __hip_bfloat16* __restrict__ inpb,
                                             const __hip_bfloat16* __restrict__ rdb,
                                             const __hip_bfloat16* __restrict__ regsb,
                                             const float* __restrict__ regs,
                                             const __hip_bfloat16* __restrict__ Wihb,
                                             const float* __restrict__ bih,
                                             const __hip_bfloat16* __restrict__ Whhb,
                                             const float* __restrict__ bhh,
                                             float* __restrict__ newregs,
                                             __hip_bfloat16* __restrict__ nregsb)
{
    __shared__ __hip_bfloat16 At[2][64][32];
    __shared__ __hip_bfloat16 Bt[2][192][32];
    const int t = threadIdx.x, w = t >> 6, l = t & 63;
    const int lg = l >> 4, ll = l & 15;
    const int m0 = blockIdx.x*64;
    const int n0 = blockIdx.y*64;
    const int batch = blockIdx.x >> 4;
    const short* Xi = (const short*)inpb + (size_t)batch*INS;
    const short* Rd = (const short*)rdb;
    const short* Hb = (const short*)regsb;
    const short* Wi = (const short*)Wihb;
    const short* Wh = (const short*)Whhb;

    f32x4 aR[4], aZ[4], aNi[4], aNh[4];
    #pragma unroll
    for (int c = 0; c < 4; c++) {
        aR[c] = (f32x4){0,0,0,0}; aZ[c] = (f32x4){0,0,0,0};
        aNi[c] = (f32x4){0,0,0,0}; aNh[c] = (f32x4){0,0,0,0};
    }

    const int NIT1 = GRUIN/32;              // 20
    const int NIT  = NIT1 + RS/32;          // 28

    auto stage = [&](int buf, int it) {
        char* abase = (char*)(&At[buf][0][0]);
        char* bbase = (char*)(&Bt[buf][0][0]);
        // A: 256 chunks of 16B, 1/thread
        {
            int ci = (w << 6) + l;
            int row = ci >> 2, cc = ci & 3;
            int gc = cc ^ ((row >> 1) & 3);
            const char* src;
            if (it < NIT1) {
                int k0 = it*32;
                if (k0 < INS) src = (const char*)(Xi + k0) + gc*16;
                else          src = (const char*)(Rd + (size_t)(m0+row)*MD + (k0 - INS)) + gc*16;
            } else {
                int k0 = (it - NIT1)*32;
                src = (const char*)(Hb + (size_t)(m0+row)*RS + k0) + gc*16;
            }
            gload16(src, abase + (size_t)((w << 6))*16);
        }
        // B: 768 chunks of 16B, 3/thread
        #pragma unroll
        for (int j = 0; j < 3; j++) {
            int ci = w*192 + (j << 6) + l;
            int row = ci >> 2, cc = ci & 3;
            int gc = cc ^ ((row >> 1) & 3);
            int g = row >> 6, col = row & 63;
            const char* src;
            if (it < NIT1) {
                int k0 = it*32;
                src = (const char*)(Wi + (size_t)(g*RS + n0 + col)*GRUIN + k0) + gc*16;
            } else {
                int k0 = (it - NIT1)*32;
                src = (const char*)(Wh + (size_t)(g*RS + n0 + col)*RS + k0) + gc*16;
            }
            gload16(src, bbase + (size_t)(w*192 + (j << 6))*16);
        }
    };

    stage(0, 0);
    asm volatile("s_waitcnt vmcnt(0)" ::: "memory");
    __syncthreads();
    int cur = 0;
    const int arow = (w << 4) + ll;
    const int aswz = ((lg ^ ((arow >> 1) & 3)) << 4);
    for (int it = 0; it < NIT; ++it) {
        if (it + 1 < NIT) stage(cur ^ 1, it + 1);
        const char* ab = (const char*)(&At[cur][0][0]);
        const char* bb = (const char*)(&Bt[cur][0][0]);
        bf16x8 af = *(const bf16x8*)(ab + arow*64 + aswz);
        if (it < NIT1) {
            #pragma unroll
            for (int c = 0; c < 4; c++) {
                int r0 = c*16 + ll;
                int sw = ((lg ^ ((r0 >> 1) & 3)) << 4);
                bf16x8 bR = *(const bf16x8*)(bb + (size_t)r0*64 + sw);
                bf16x8 bZ = *(const bf16x8*)(bb + (size_t)(r0 + 64)*64 + sw);
                bf16x8 bN = *(const bf16x8*)(bb + (size_t)(r0 + 128)*64 + sw);
                aR[c]  = __builtin_amdgcn_mfma_f32_16x16x32_bf16(af, bR, aR[c],  0, 0, 0);
                aZ[c]  = __builtin_amdgcn_mfma_f32_16x16x32_bf16(af, bZ, aZ[c],  0, 0, 0);
                aNi[c] = __builtin_amdgcn_mfma_f32_16x16x32_bf16(af, bN, aNi[c], 0, 0, 0);
            }
        } else {
            #pragma unroll
            for (int c = 0; c < 4; c++) {
                int r0 = c*16 + ll;
                int sw = ((lg ^ ((r0 >> 1) & 3)) << 4);
                bf16x8 bR = *(const bf16x8*)(bb + (size_t)r0*64 + sw);
                bf16x8 bZ = *(const bf16x8*)(bb + (size_t)(r0 + 64)*64 + sw);
                bf16x8 bN = *(const bf16x8*)(bb + (size_t)(r0 + 128)*64 + sw);
                aR[c]  = __builtin_amdgcn_mfma_f32_16x16x32_bf16(af, bR, aR[c],  0, 0, 0);
                aZ[c]  = __builtin_amdgcn_mfma_f32_16x16x32_bf16(af, bZ, aZ[c],  0, 0, 0);
                aNh[c] = __builtin_amdgcn_mfma_f32_16x16x32_bf16(af, bN, aNh[c], 0, 0, 0);
            }
        }
        asm volatile("s_waitcnt vmcnt(0)" ::: "memory");
        __syncthreads();
        cur ^= 1;
    }
    // epilogue: gates
    const int wm0 = m0 + (w << 4);
    #pragma unroll
    for (int c = 0; c < 4; c++) {
        int o = n0 + c*16 + ll;
        float bR = bih[o]        + bhh[o];
        float bZ = bih[o +   RS] + bhh[o +   RS];
        float bNi = bih[o + 2*RS];
        float bNh = bhh[o + 2*RS];
        #pragma unroll
        for (int r = 0; r < 4; r++) {
            int row = wm0 + lg*4 + r;
            float rr = sigf(aR[c][r] + bR);
            float zz = sigf(aZ[c][r] + bZ);
            float nn = tanhf(aNi[c][r] + bNi + rr*(aNh[c][r] + bNh));
            float cv = regs[(size_t)row*RS + o];
            float nv = (1.f - zz)*nn + zz*cv;
            newregs[(size_t)row*RS + o] = nv;
            nregsb[(size_t)row*RS + o] = __float2bfloat16(nv);
        }
    }
}

// ---------------- K4: output GEMM (MFMA) ----------------
__global__ __launch_bounds__(256) void k_out(const __hip_bfloat16* __restrict__ Ab,
                                             const __hip_bfloat16* __restrict__ Wb,
                                             const float* __restrict__ bias,
                                             float* __restrict__ out0)
{
    const int t = threadIdx.x, w = t >> 6, l = t & 63;
    const int lg = l >> 4, ll = l & 15;
    const int m0 = blockIdx.x*64 + w*16;
    const int n0 = blockIdx.y*256;
    const short* A = (const short*)Ab;
    const short* W = (const short*)Wb;
    f32x4 acc[16];
    #pragma unroll
    for (int c = 0; c < 16; c++) acc[c] = (f32x4){0,0,0,0};
    for (int k0 = 0; k0 < RS; k0 += 32) {
        bf16x8 af = *(const bf16x8*)(A + (size_t)(m0+ll)*RS + k0 + lg*8);
        #pragma unroll
        for (int c = 0; c < 16; c++) {
            int n = n0 + c*16 + ll;
            bf16x8 bf = *(const bf16x8*)(W + (size_t)n*RS + k0 + lg*8);
            acc[c] = __builtin_amdgcn_mfma_f32_16x16x32_bf16(af, bf, acc[c], 0, 0, 0);
        }
    }
    #pragma unroll
    for (int c = 0; c < 16; c++) {
        int o = n0 + c*16 + ll;
        float bv = bias[o];
        #pragma unroll
        for (int r = 0; r < 4; r++) {
            int row = m0 + lg*4 + r;
            out0[(size_t)row*INS + o] = acc[c][r] + bv;
        }
    }
}

extern "C" void kernel_launch(void* const* d_in, const int* in_sizes, int n_in,
                              void* d_out, int out_size, void* d_ws, size_t ws_size,
                              hipStream_t stream)
{
    const float* inp  = (const float*)d_in[0];
    const float* regs = (const float*)d_in[1];
    const float* mem  = (const float*)d_in[2];
    const float* Wih  = (const float*)d_in[3];
    const float* bih  = (const float*)d_in[4];
    const float* Whh  = (const float*)d_in[5];
    const float* bhh  = (const float*)d_in[6];
    const float* Wmmu = (const float*)d_in[7];
    const float* bmmu = (const float*)d_in[8];
    const float* Wout = (const float*)d_in[9];
    const float* bout = (const float*)d_in[10];
    float* out = (float*)d_out;

    char* ws = (char*)d_ws;
    __hip_bfloat16* qbf    = (__hip_bfloat16*)(ws);
    __hip_bfloat16* rdb    = (__hip_bfloat16*)(ws + ((size_t)4<<20));
    __hip_bfloat16* memB   = (__hip_bfloat16*)(ws + ((size_t)8<<20));
    __hip_bfloat16* memT   = (__hip_bfloat16*)(ws + ((size_t)24<<20));
    __hip_bfloat16* regsb  = (__hip_bfloat16*)(ws + ((size_t)40<<20));
    __hip_bfloat16* nregsb = (__hip_bfloat16*)(ws + ((size_t)48<<20));
    __hip_bfloat16* Wmmub  = (__hip_bfloat16*)(ws + ((size_t)56<<20));
    __hip_bfloat16* Wihb   = (__hip_bfloat16*)(ws + ((size_t)56<<20) + ( 1<<20));
    __hip_bfloat16* Whhb   = (__hip_bfloat16*)(ws + ((size_t)56<<20) + ( 2<<20));
    __hip_bfloat16* Woutb  = (__hip_bfloat16*)(ws + ((size_t)56<<20) + ( 3<<20));
    __hip_bfloat16* inpb   = (__hip_bfloat16*)(ws + ((size_t)56<<20) + ( 4<<20));
    float*          MLpart = (float*)(ws + ((size_t)61<<20));            // 256 KB
    float*          Opart  = out + O_OUT;   // lives in out0 region until k_out

    k_cvt<<<(164864/4 + 255)/256, 256, 0, stream>>>(Wmmu, (unsigned short*)Wmmub, 164864/4);
    k_cvt<<<(491520/4 + 255)/256, 256, 0, stream>>>(Wih,  (unsigned short*)Wihb,  491520/4);
    k_cvt<<<(196608/4 + 255)/256, 256, 0, stream>>>(Whh,  (unsigned short*)Whhb,  196608/4);
    k_cvt<<<(131072/4 + 255)/256, 256, 0, stream>>>(Wout, (unsigned short*)Woutb, 131072/4);
    k_cvt<<<(8192/4   + 255)/256, 256, 0, stream>>>(inp,  (unsigned short*)inpb,  8192/4);
    k_cvt<<<(4194304/4+ 255)/256, 256, 0, stream>>>(regs, (unsigned short*)regsb, 4194304/4);
    k_conv<<<B_*128, 256, 0, stream>>>(mem, memB, memT);

    dim3 g1(NROWS/64, 3);
    k_mmu<<<g1, 256, 0, stream>>>(regsb, Wmmub, bmmu, out, qbf);
    k_softmax3<<<NROWS/256, 256, 0, stream>>>(out);
    k_attn<<<256, 256, 0, stream>>>(qbf, memB, memT, Opart, MLpart);
    k_comb<<<NROWS/64, 256, 0, stream>>>(Opart, MLpart, rdb);
    dim3 g3(NROWS/64, 4);
    k_gru<<<g3, 256, 0, stream>>>(inpb, rdb, regsb, regs, Wihb, bih, Whhb, bhh,
                                  out + O_REGS, nregsb);
    dim3 g4(NROWS/64, 2);
    k_out<<<g4, 256, 0, stream>>>(nregsb, Woutb, bout, out);
}

// Round 9
// 307.730 us; speedup vs baseline: 1.7602x; 1.0003x over previous
//
#include <hip/hip_runtime.h>
#include <hip/hip_bf16.h>
#include <math.h>

#define B_      16
#define NPUS    1024
#define MEMS    4096
#define INS     512
#define RS      256
#define MD      128
#define GRUIN   640
#define MMUO    644
#define NROWS   (B_*NPUS)   // 16384

// d_out flat offsets (reference return order)
#define O_OUT   0u
#define O_REGS  8388608u
#define O_WKEY  12582912u
#define O_WVAL  14680064u
#define O_WGATE 16777216u
#define O_SSDK  16793600u
#define O_SSDV  18890752u
#define O_SSDG  20987904u

typedef __attribute__((ext_vector_type(8))) short bf16x8;
typedef __attribute__((ext_vector_type(4))) float f32x4;
typedef __attribute__((ext_vector_type(4))) unsigned short u16x4;

__device__ __forceinline__ float sigf(float x){ return 1.f/(1.f+__expf(-x)); }
__device__ __forceinline__ unsigned short bfu(float x){
    __hip_bfloat16 h = __float2bfloat16(x);
    return __builtin_bit_cast(unsigned short, h);
}
// async global->LDS, 16B per lane; LDS dest is wave-uniform base + lane*16 (m104)
__device__ __forceinline__ void gload16(const void* g, void* s)
{
    __builtin_amdgcn_global_load_lds(
        (const __attribute__((address_space(1))) void*)g,
        (__attribute__((address_space(3))) void*)s, 16, 0, 0);
}

// ---------------- K_cvt: fp32 -> bf16, vectorized x4 ----------------
__global__ __launch_bounds__(256) void k_cvt(const float* __restrict__ src,
                                             unsigned short* __restrict__ dst, int n4)
{
    int i = blockIdx.x*256 + threadIdx.x;
    if (i >= n4) return;
    float4 v = ((const float4*)src)[i];
    u16x4 o = { bfu(v.x), bfu(v.y), bfu(v.z), bfu(v.w) };
    ((u16x4*)dst)[i] = o;
}

// ---------------- K_cvt5: fused 5-tensor fp32->bf16 (block-aligned segments) ----------------
// quads: Wmmu 41216 | Wih 122880 | Whh 49152 | Wout 32768 | inp 2048 ; 969 blocks total
__global__ __launch_bounds__(256) void k_cvt5(const float* __restrict__ s0, unsigned short* __restrict__ d0,
                                              const float* __restrict__ s1, unsigned short* __restrict__ d1,
                                              const float* __restrict__ s2, unsigned short* __restrict__ d2,
                                              const float* __restrict__ s3, unsigned short* __restrict__ d3,
                                              const float* __restrict__ s4, unsigned short* __restrict__ d4)
{
    int gi = blockIdx.x*256 + threadIdx.x;
    const float* s; unsigned short* d; int idx;
    if      (gi < 41216)  { s = s0; d = d0; idx = gi; }
    else if (gi < 164096) { s = s1; d = d1; idx = gi - 41216; }
    else if (gi < 213248) { s = s2; d = d2; idx = gi - 164096; }
    else if (gi < 246016) { s = s3; d = d3; idx = gi - 213248; }
    else                  { s = s4; d = d4; idx = gi - 246016; }
    float4 v = ((const float4*)s)[idx];
    u16x4 o = { bfu(v.x), bfu(v.y), bfu(v.z), bfu(v.w) };
    ((u16x4*)d)[idx] = o;
}

// ---------------- K0: memory_context -> bf16 row-major + transposed ----------------
__global__ __launch_bounds__(256) void k_conv(const float* __restrict__ mem,
                                              __hip_bfloat16* __restrict__ memB,
                                              __hip_bfloat16* __restrict__ memT)
{
    __shared__ float Ms[32][129];
    const int t = threadIdx.x;
    const int b = blockIdx.x >> 7;
    const int m0 = (blockIdx.x & 127) << 5;
    const float* src = mem + ((size_t)b*MEMS + m0)*MD;
    for (int idx = t; idx < 32*128; idx += 256) {
        int m = idx >> 7, d = idx & 127;
        float v = src[(size_t)m*MD + d];
        Ms[m][d] = v;
        memB[((size_t)b*MEMS + m0 + m)*MD + d] = __float2bfloat16(v);
    }
    __syncthreads();
    for (int idx = t; idx < 128*32; idx += 256) {
        int d = idx >> 5, m = idx & 31;
        memT[((size_t)b*MD + d)*MEMS + m0 + m] = __float2bfloat16(Ms[m][d]);
    }
}

// ---------------- K1: MMU GEMM (MFMA)  C[16384,644] = regs * Wmmu^T + b ----------------
__global__ __launch_bounds__(256) void k_mmu(const __hip_bfloat16* __restrict__ Ab,
                                             const __hip_bfloat16* __restrict__ Wb,
                                             const float* __restrict__ bias,
                                             float* __restrict__ out,
                                             __hip_bfloat16* __restrict__ qbf)
{
    const int t = threadIdx.x, w = t >> 6, l = t & 63;
    const int lg = l >> 4, ll = l & 15;
    const int m0 = blockIdx.x*64 + w*16;
    const int n0 = blockIdx.y*256;
    const short* A = (const short*)Ab;
    const short* W = (const short*)Wb;
    f32x4 acc[16];
    #pragma unroll
    for (int c = 0; c < 16; c++) acc[c] = (f32x4){0,0,0,0};
    for (int k0 = 0; k0 < RS; k0 += 32) {
        bf16x8 af = *(const bf16x8*)(A + (size_t)(m0+ll)*RS + k0 + lg*8);
        #pragma unroll
        for (int c = 0; c < 16; c++) {
            int n = n0 + c*16 + ll;
            bf16x8 bf = {};
            if (n < MMUO) bf = *(const bf16x8*)(W + (size_t)n*RS + k0 + lg*8);
            acc[c] = __builtin_amdgcn_mfma_f32_16x16x32_bf16(af, bf, acc[c], 0, 0, 0);
        }
    }
    #pragma unroll
    for (int c = 0; c < 16; c++) {
        int o = n0 + c*16 + ll;
        if (o >= MMUO) continue;
        float bv = bias[o];
        #pragma unroll
        for (int r = 0; r < 4; r++) {
            int row = m0 + lg*4 + r;
            float v = acc[c][r] + bv;
            if      (o < MD)        qbf[(size_t)row*MD + o] = __float2bfloat16(v * 0.08838834764831845f);
            else if (o < 2*MD)      out[O_WKEY + (size_t)row*MD + (o -   MD)] = v;
            else if (o < 3*MD)      out[O_WVAL + (size_t)row*MD + (o - 2*MD)] = v;
            else if (o == 3*MD)     out[O_WGATE + row] = sigf(v);
            else if (o < 4*MD + 1)  out[O_SSDK + (size_t)row*MD + (o - (3*MD+1))] = v;
            else if (o < 5*MD + 1)  out[O_SSDV + (size_t)row*MD + (o - (4*MD+1))] = v;
            else                    out[O_SSDG + (size_t)row*3  + (o - (5*MD+1))] = v;
        }
    }
}

// ---------------- K1b: softmax over the 3 ssd_gate logits ----------------
__global__ void k_softmax3(float* __restrict__ out)
{
    int r = blockIdx.x*256 + threadIdx.x;
    if (r >= NROWS) return;
    float* p = out + O_SSDG + (size_t)r*3;
    float a = p[0], b = p[1], c = p[2];
    float m = fmaxf(a, fmaxf(b, c));
    float ea = __expf(a-m), eb = __expf(b-m), ec = __expf(c-m);
    float inv = 1.f/(ea+eb+ec);
    p[0] = ea*inv; p[1] = eb*inv; p[2] = ec*inv;
}

// ---------------- K2: LDS-staged 4-way split-K flash attention ----------------
// 512 blocks (2/CU) x 4 waves. Block: 128 q-rows, keys [kh*1024,+1024). K+V tile
// (32 keys, 16KB) double-buffered via global_load_lds; counted vmcnt(4) keeps
// next-tile loads in flight across both raw barriers (T4). K swizzle (row&7 on
// 16 chunks) and V swizzle ((row>>1)&3 on 4 chunks) kill read bank conflicts.
__global__ __launch_bounds__(256) void k_attn(const __hip_bfloat16* __restrict__ qb,
                                              const __hip_bfloat16* __restrict__ memB,
                                              const __hip_bfloat16* __restrict__ memT,
                                              float* __restrict__ Opart,
                                              float* __restrict__ MLpart)
{
    __shared__ __hip_bfloat16 Kt[2][32][128];
    __shared__ __hip_bfloat16 Vt[2][128][32];
    __shared__ __hip_bfloat16 Pl[4][16][40];
    const int t = threadIdx.x, w = t >> 6, l = t & 63;
    const int lg = l >> 4, ll = l & 15;
    const int bid = blockIdx.x;
    const int xcd = bid & 7, rest = bid >> 3;      // rest 0..63
    const int b = xcd + ((rest >> 5) << 3);        // 2 batches per XCD
    const int sub = rest & 31;
    const int qblk = sub >> 2, kh = sub & 3;
    const int qrow0 = (b << 10) + (qblk << 7) + (w << 5);   // wave's 32 q-rows
    const int k_beg = kh << 10;                             // 1024 keys per quarter
    const float THR = 4.0f;

    const short* Q = (const short*)qb;
    bf16x8 qf[2][4];
    #pragma unroll
    for (int qs = 0; qs < 2; qs++)
        #pragma unroll
        for (int ks = 0; ks < 4; ks++)
            qf[qs][ks] = *(const bf16x8*)(Q + (size_t)(qrow0 + qs*16 + ll)*MD + ks*32 + lg*8);

    f32x4 O[2][8];
    #pragma unroll
    for (int qs = 0; qs < 2; qs++)
        #pragma unroll
        for (int dt = 0; dt < 8; dt++) O[qs][dt] = (f32x4){0.f,0.f,0.f,0.f};
    float m_run[2][4], lsum[2][4];
    #pragma unroll
    for (int qs = 0; qs < 2; qs++)
        #pragma unroll
        for (int r = 0; r < 4; r++) { m_run[qs][r] = -INFINITY; lsum[qs][r] = 0.f; }

    const char* MbB = (const char*)memB + (size_t)b*MEMS*MD*2;
    const char* MtB = (const char*)memT + (size_t)b*MD*MEMS*2;

    auto stage = [&](int buf, int it) {
        const int k0 = k_beg + it*32;
        char* kbase = (char*)(&Kt[buf][0][0]);
        char* vbase = (char*)(&Vt[buf][0][0]);
        #pragma unroll
        for (int j = 0; j < 2; j++) {
            int ci = (w << 7) + (j << 6) + l;        // chunk 0..511 (16B each)
            int krow = ci >> 4, cc = ci & 15;
            int gc = cc ^ (krow & 7);                // pre-swizzled global source
            gload16(MbB + (size_t)(k0 + krow)*256 + gc*16,
                    kbase + (size_t)((w << 7) + (j << 6))*16);
        }
        #pragma unroll
        for (int j = 0; j < 2; j++) {
            int ci = (w << 7) + (j << 6) + l;
            int drow = ci >> 2, cc = ci & 3;
            int gc = cc ^ ((drow >> 1) & 3);         // V swizzle (both-sides involution)
            gload16(MtB + (size_t)drow*(MEMS*2) + (size_t)k0*2 + gc*16,
                    vbase + (size_t)((w << 7) + (j << 6))*16);
        }
    };

    stage(0, 0);
    asm volatile("s_waitcnt vmcnt(0)" ::: "memory");
    asm volatile("s_barrier" ::: "memory");
    int cur = 0;
    const int NIT = 1024/32;   // 32
    const int vsw = ((lg ^ ((ll >> 1) & 3)) << 4);
    for (int it = 0; it < NIT; ++it) {
        if (it + 1 < NIT) {
            stage(cur ^ 1, it + 1);
            asm volatile("s_waitcnt vmcnt(4)" ::: "memory");   // own stage(cur) done; next-tile stays in flight
        } else {
            asm volatile("s_waitcnt vmcnt(0)" ::: "memory");
        }
        asm volatile("s_barrier" ::: "memory");                // everyone's stage(cur) done
        const char* kbase = (const char*)(&Kt[cur][0][0]);
        const char* vbase = (const char*)(&Vt[cur][0][0]);
        bf16x8 vf[8];
        #pragma unroll
        for (int dt = 0; dt < 8; dt++)
            vf[dt] = *(const bf16x8*)(vbase + (size_t)(dt*16 + ll)*64 + vsw);
        f32x4 s[2][2];
        s[0][0]=(f32x4){0,0,0,0}; s[0][1]=(f32x4){0,0,0,0};
        s[1][0]=(f32x4){0,0,0,0}; s[1][1]=(f32x4){0,0,0,0};
        #pragma unroll
        for (int ks = 0; ks < 4; ks++) {
            int c0 = ks*4 + lg;
            int sw = (c0 ^ (ll & 7)) << 4;
            bf16x8 kf0 = *(const bf16x8*)(kbase + (size_t)ll*256 + sw);
            bf16x8 kf1 = *(const bf16x8*)(kbase + (size_t)(16 + ll)*256 + sw);
            s[0][0] = __builtin_amdgcn_mfma_f32_16x16x32_bf16(qf[0][ks], kf0, s[0][0], 0, 0, 0);
            s[1][0] = __builtin_amdgcn_mfma_f32_16x16x32_bf16(qf[1][ks], kf0, s[1][0], 0, 0, 0);
            s[0][1] = __builtin_amdgcn_mfma_f32_16x16x32_bf16(qf[0][ks], kf1, s[0][1], 0, 0, 0);
            s[1][1] = __builtin_amdgcn_mfma_f32_16x16x32_bf16(qf[1][ks], kf1, s[1][1], 0, 0, 0);
        }
        bool need = false;
        #pragma unroll
        for (int qs = 0; qs < 2; qs++)
            #pragma unroll
            for (int r = 0; r < 4; r++) {
                need |= (s[qs][0][r] > m_run[qs][r] + THR);
                need |= (s[qs][1][r] > m_run[qs][r] + THR);
            }
        if (__any(need)) {
            #pragma unroll
            for (int qs = 0; qs < 2; qs++)
                #pragma unroll
                for (int r = 0; r < 4; r++) {
                    float v = fmaxf(s[qs][0][r], s[qs][1][r]);
                    v = fmaxf(v, __shfl_xor(v, 1));
                    v = fmaxf(v, __shfl_xor(v, 2));
                    v = fmaxf(v, __shfl_xor(v, 4));
                    v = fmaxf(v, __shfl_xor(v, 8));
                    float mnew = fmaxf(m_run[qs][r], v);
                    float alpha = __expf(m_run[qs][r] - mnew);
                    m_run[qs][r] = mnew;
                    lsum[qs][r] *= alpha;
                    #pragma unroll
                    for (int dt = 0; dt < 8; dt++) O[qs][dt][r] *= alpha;
                }
        }
        #pragma unroll
        for (int qs = 0; qs < 2; qs++) {
            #pragma unroll
            for (int r = 0; r < 4; r++) {
                float p0 = __expf(s[qs][0][r] - m_run[qs][r]);
                float p1 = __expf(s[qs][1][r] - m_run[qs][r]);
                Pl[w][lg*4 + r][ll]      = __float2bfloat16(p0);
                Pl[w][lg*4 + r][16 + ll] = __float2bfloat16(p1);
                lsum[qs][r] += p0 + p1;
            }
            __builtin_amdgcn_wave_barrier();
            bf16x8 pa = *(const bf16x8*)(&Pl[w][ll][lg*8]);
            __builtin_amdgcn_wave_barrier();
            #pragma unroll
            for (int dt = 0; dt < 8; dt++)
                O[qs][dt] = __builtin_amdgcn_mfma_f32_16x16x32_bf16(pa, vf[dt], O[qs][dt], 0, 0, 0);
        }
        asm volatile("s_barrier" ::: "memory");                // all reads of buf cur done
        cur ^= 1;
    }
    #pragma unroll
    for (int qs = 0; qs < 2; qs++)
        #pragma unroll
        for (int r = 0; r < 4; r++) {
            float s = lsum[qs][r];
            s += __shfl_xor(s, 1);
            s += __shfl_xor(s, 2);
            s += __shfl_xor(s, 4);
            s += __shfl_xor(s, 8);
            lsum[qs][r] = s;
        }
    #pragma unroll
    for (int qs = 0; qs < 2; qs++)
        #pragma unroll
        for (int dt = 0; dt < 8; dt++)
            #pragma unroll
            for (int r = 0; r < 4; r++) {
                int row = qrow0 + qs*16 + lg*4 + r;
                Opart[((size_t)row*4 + kh)*128 + dt*16 + ll] = O[qs][dt][r];
            }
    if (ll == 0) {
        #pragma unroll
        for (int qs = 0; qs < 2; qs++)
            #pragma unroll
            for (int r = 0; r < 4; r++) {
                int row = qrow0 + qs*16 + lg*4 + r;
                MLpart[((size_t)row*4 + kh)*2 + 0] = m_run[qs][r];
                MLpart[((size_t)row*4 + kh)*2 + 1] = lsum[qs][r];
            }
    }
}

// ---------------- K2b: combine the 4 split-K partials -> rd bf16 ----------------
__global__ __launch_bounds__(256) void k_comb(const float* __restrict__ Opart,
                                              const float* __restrict__ MLpart,
                                              __hip_bfloat16* __restrict__ rdb)
{
    const int t = threadIdx.x;
    const int row = blockIdx.x*64 + (t >> 2);
    const int c0 = (t & 3) * 32;
    float m[4], lv[4], a[4];
    float M = -INFINITY;
    #pragma unroll
    for (int i = 0; i < 4; i++) {
        m[i]  = MLpart[((size_t)row*4 + i)*2 + 0];
        lv[i] = MLpart[((size_t)row*4 + i)*2 + 1];
        M = fmaxf(M, m[i]);
    }
    float L = 0.f;
    #pragma unroll
    for (int i = 0; i < 4; i++) { a[i] = __expf(m[i] - M); L += a[i]*lv[i]; }
    float invL = 1.f / L;
    #pragma unroll
    for (int i = 0; i < 4; i++) a[i] *= invL;
    unsigned short* dst = (unsigned short*)rdb + (size_t)row*128 + c0;
    #pragma unroll
    for (int j = 0; j < 8; j++) {
        float4 acc = {0.f,0.f,0.f,0.f};
        #pragma unroll
        for (int i = 0; i < 4; i++) {
            float4 x = ((const float4*)(Opart + ((size_t)row*4 + i)*128 + c0))[j];
            acc.x += a[i]*x.x; acc.y += a[i]*x.y; acc.z += a[i]*x.z; acc.w += a[i]*x.w;
        }
        u16x4 o = { bfu(acc.x), bfu(acc.y), bfu(acc.z), bfu(acc.w) };
        ((u16x4*)dst)[j] = o;
    }
}

// ---------------- K3: fused GRU (MFMA, LDS-staged double-buffered GEMM) ----------------
__global__ __launch_bounds__(256) void k_gru(const __hip_bfloat16* __restrict__ inpb,
                                             const __hip_bfloat16* __restrict__ rdb,
                                             const __hip_bfloat16* __restrict__ regsb,
                                             const float* __restrict__ regs,
                                             const __hip_bfloat16* __restrict__ Wihb,
                                             const float* __restrict__ bih,
                                             const __hip_bfloat16* __restrict__ Whhb,
                                             const float* __restrict__ bhh,
                                             float* __restrict__ newregs,
                                             __hip_bfloat16* __restrict__ nregsb)
{
    __shared__ __hip_bfloat16 At[2][64][32];
    __shared__ __hip_bfloat16 Bt[2][192][32];
    const int t = threadIdx.x, w = t >> 6, l = t & 63;
    const int lg = l >> 4, ll = l & 15;
    const int m0 = blockIdx.x*64;
    const int n0 = blockIdx.y*64;
    const int batch = blockIdx.x >> 4;
    const short* Xi = (const short*)inpb + (size_t)batch*INS;
    const short* Rd = (const short*)rdb;
    const short* Hb = (const short*)regsb;
    const short* Wi = (const short*)Wihb;
    const short* Wh = (const short*)Whhb;

    f32x4 aR[4], aZ[4], aNi[4], aNh[4];
    #pragma unroll
    for (int c = 0; c < 4; c++) {
        aR[c] = (f32x4){0,0,0,0}; aZ[c] = (f32x4){0,0,0,0};
        aNi[c] = (f32x4){0,0,0,0}; aNh[c] = (f32x4){0,0,0,0};
    }

    const int NIT1 = GRUIN/32;              // 20
    const int NIT  = NIT1 + RS/32;          // 28

    auto stage = [&](int buf, int it) {
        char* abase = (char*)(&At[buf][0][0]);
        char* bbase = (char*)(&Bt[buf][0][0]);
        {
            int ci = (w << 6) + l;
            int row = ci >> 2, cc = ci & 3;
            int gc = cc ^ ((row >> 1) & 3);
            const char* src;
            if (it < NIT1) {
                int k0 = it*32;
                if (k0 < INS) src = (const char*)(Xi + k0) + gc*16;
                else          src = (const char*)(Rd + (size_t)(m0+row)*MD + (k0 - INS)) + gc*16;
            } else {
                int k0 = (it - NIT1)*32;
                src = (const char*)(Hb + (size_t)(m0+row)*RS + k0) + gc*16;
            }
            gload16(src, abase + (size_t)((w << 6))*16);
        }
        #pragma unroll
        for (int j = 0; j < 3; j++) {
            int ci = w*192 + (j << 6) + l;
            int row = ci >> 2, cc = ci & 3;
            int gc = cc ^ ((row >> 1) & 3);
            int g = row >> 6, col = row & 63;
            const char* src;
            if (it < NIT1) {
                int k0 = it*32;
                src = (const char*)(Wi + (size_t)(g*RS + n0 + col)*GRUIN + k0) + gc*16;
            } else {
                int k0 = (it - NIT1)*32;
                src = (const char*)(Wh + (size_t)(g*RS + n0 + col)*RS + k0) + gc*16;
            }
            gload16(src, bbase + (size_t)(w*192 + (j << 6))*16);
        }
    };

    stage(0, 0);
    asm volatile("s_waitcnt vmcnt(0)" ::: "memory");
    __syncthreads();
    int cur = 0;
    const int arow = (w << 4) + ll;
    const int aswz = ((lg ^ ((arow >> 1) & 3)) << 4);
    for (int it = 0; it < NIT; ++it) {
        if (it + 1 < NIT) stage(cur ^ 1, it + 1);
        const char* ab = (const char*)(&At[cur][0][0]);
        const char* bb = (const char*)(&Bt[cur][0][0]);
        bf16x8 af = *(const bf16x8*)(ab + arow*64 + aswz);
        if (it < NIT1) {
            #pragma unroll
            for (int c = 0; c < 4; c++) {
                int r0 = c*16 + ll;
                int sw = ((lg ^ ((r0 >> 1) & 3)) << 4);
                bf16x8 bR = *(const bf16x8*)(bb + (size_t)r0*64 + sw);
                bf16x8 bZ = *(const bf16x8*)(bb + (size_t)(r0 + 64)*64 + sw);
                bf16x8 bN = *(const bf16x8*)(bb + (size_t)(r0 + 128)*64 + sw);
                aR[c]  = __builtin_amdgcn_mfma_f32_16x16x32_bf16(af, bR, aR[c],  0, 0, 0);
                aZ[c]  = __builtin_amdgcn_mfma_f32_16x16x32_bf16(af, bZ, aZ[c],  0, 0, 0);
                aNi[c] = __builtin_amdgcn_mfma_f32_16x16x32_bf16(af, bN, aNi[c], 0, 0, 0);
            }
        } else {
            #pragma unroll
            for (int c = 0; c < 4; c++) {
                int r0 = c*16 + ll;
                int sw = ((lg ^ ((r0 >> 1) & 3)) << 4);
                bf16x8 bR = *(const bf16x8*)(bb + (size_t)r0*64 + sw);
                bf16x8 bZ = *(const bf16x8*)(bb + (size_t)(r0 + 64)*64 + sw);
                bf16x8 bN = *(const bf16x8*)(bb + (size_t)(r0 + 128)*64 + sw);
                aR[c]  = __builtin_amdgcn_mfma_f32_16x16x32_bf16(af, bR, aR[c],  0, 0, 0);
                aZ[c]  = __builtin_amdgcn_mfma_f32_16x16x32_bf16(af, bZ, aZ[c],  0, 0, 0);
                aNh[c] = __builtin_amdgcn_mfma_f32_16x16x32_bf16(af, bN, aNh[c], 0, 0, 0);
            }
        }
        asm volatile("s_waitcnt vmcnt(0)" ::: "memory");
        __syncthreads();
        cur ^= 1;
    }
    const int wm0 = m0 + (w << 4);
    #pragma unroll
    for (int c = 0; c < 4; c++) {
        int o = n0 + c*16 + ll;
        float bR = bih[o]        + bhh[o];
        float bZ = bih[o +   RS] + bhh[o +   RS];
        float bNi = bih[o + 2*RS];
        float bNh = bhh[o + 2*RS];
        #pragma unroll
        for (int r = 0; r < 4; r++) {
            int row = wm0 + lg*4 + r;
            float rr = sigf(aR[c][r] + bR);
            float zz = sigf(aZ[c][r] + bZ);
            float nn = tanhf(aNi[c][r] + bNi + rr*(aNh[c][r] + bNh));
            float cv = regs[(size_t)row*RS + o];
            float nv = (1.f - zz)*nn + zz*cv;
            newregs[(size_t)row*RS + o] = nv;
            nregsb[(size_t)row*RS + o] = __float2bfloat16(nv);
        }
    }
}

// ---------------- K4: output GEMM (MFMA) ----------------
__global__ __launch_bounds__(256) void k_out(const __hip_bfloat16* __restrict__ Ab,
                                             const __hip_bfloat16* __restrict__ Wb,
                                             const float* __restrict__ bias,
                                             float* __restrict__ out0)
{
    const int t = threadIdx.x, w = t >> 6, l = t & 63;
    const int lg = l >> 4, ll = l & 15;
    const int m0 = blockIdx.x*64 + w*16;
    const int n0 = blockIdx.y*256;
    const short* A = (const short*)Ab;
    const short* W = (const short*)Wb;
    f32x4 acc[16];
    #pragma unroll
    for (int c = 0; c < 16; c++) acc[c] = (f32x4){0,0,0,0};
    for (int k0 = 0; k0 < RS; k0 += 32) {
        bf16x8 af = *(const bf16x8*)(A + (size_t)(m0+ll)*RS + k0 + lg*8);
        #pragma unroll
        for (int c = 0; c < 16; c++) {
            int n = n0 + c*16 + ll;
            bf16x8 bf = *(const bf16x8*)(W + (size_t)n*RS + k0 + lg*8);
            acc[c] = __builtin_amdgcn_mfma_f32_16x16x32_bf16(af, bf, acc[c], 0, 0, 0);
        }
    }
    #pragma unroll
    for (int c = 0; c < 16; c++) {
        int o = n0 + c*16 + ll;
        float bv = bias[o];
        #pragma unroll
        for (int r = 0; r < 4; r++) {
            int row = m0 + lg*4 + r;
            out0[(size_t)row*INS + o] = acc[c][r] + bv;
        }
    }
}

extern "C" void kernel_launch(void* const* d_in, const int* in_sizes, int n_in,
                              void* d_out, int out_size, void* d_ws, size_t ws_size,
                              hipStream_t stream)
{
    const float* inp  = (const float*)d_in[0];
    const float* regs = (const float*)d_in[1];
    const float* mem  = (const float*)d_in[2];
    const float* Wih  = (const float*)d_in[3];
    const float* bih  = (const float*)d_in[4];
    const float* Whh  = (const float*)d_in[5];
    const float* bhh  = (const float*)d_in[6];
    const float* Wmmu = (const float*)d_in[7];
    const float* bmmu = (const float*)d_in[8];
    const float* Wout = (const float*)d_in[9];
    const float* bout = (const float*)d_in[10];
    float* out = (float*)d_out;

    char* ws = (char*)d_ws;
    __hip_bfloat16* qbf    = (__hip_bfloat16*)(ws);
    __hip_bfloat16* rdb    = (__hip_bfloat16*)(ws + ((size_t)4<<20));
    __hip_bfloat16* memB   = (__hip_bfloat16*)(ws + ((size_t)8<<20));
    __hip_bfloat16* memT   = (__hip_bfloat16*)(ws + ((size_t)24<<20));
    __hip_bfloat16* regsb  = (__hip_bfloat16*)(ws + ((size_t)40<<20));
    __hip_bfloat16* nregsb = (__hip_bfloat16*)(ws + ((size_t)48<<20));
    __hip_bfloat16* Wmmub  = (__hip_bfloat16*)(ws + ((size_t)56<<20));
    __hip_bfloat16* Wihb   = (__hip_bfloat16*)(ws + ((size_t)56<<20) + ( 1<<20));
    __hip_bfloat16* Whhb   = (__hip_bfloat16*)(ws + ((size_t)56<<20) + ( 2<<20));
    __hip_bfloat16* Woutb  = (__hip_bfloat16*)(ws + ((size_t)56<<20) + ( 3<<20));
    __hip_bfloat16* inpb   = (__hip_bfloat16*)(ws + ((size_t)56<<20) + ( 4<<20));
    float*          MLpart = (float*)(ws + ((size_t)61<<20));            // 512 KB
    float*          Opart  = out + O_OUT;   // 33.5 MB, exactly the out0 region

    k_cvt5<<<969, 256, 0, stream>>>(Wmmu, (unsigned short*)Wmmub,
                                    Wih,  (unsigned short*)Wihb,
                                    Whh,  (unsigned short*)Whhb,
                                    Wout, (unsigned short*)Woutb,
                                    inp,  (unsigned short*)inpb);
    k_cvt<<<(4194304/4 + 255)/256, 256, 0, stream>>>(regs, (unsigned short*)regsb, 4194304/4);
    k_conv<<<B_*128, 256, 0, stream>>>(mem, memB, memT);

    dim3 g1(NROWS/64, 3);
    k_mmu<<<g1, 256, 0, stream>>>(regsb, Wmmub, bmmu, out, qbf);
    k_softmax3<<<NROWS/256, 256, 0, stream>>>(out);
    k_attn<<<512, 256, 0, stream>>>(qbf, memB, memT, Opart, MLpart);
    k_comb<<<NROWS/64, 256, 0, stream>>>(Opart, MLpart, rdb);
    dim3 g3(NROWS/64, 4);
    k_gru<<<g3, 256, 0, stream>>>(inpb, rdb, regsb, regs, Wihb, bih, Whhb, bhh,
                                  out + O_REGS, nregsb);
    dim3 g4(NROWS/64, 2);
    k_out<<<g4, 256, 0, stream>>>(nregsb, Woutb, bout, out);
}

// Round 10
// 272.202 us; speedup vs baseline: 1.9900x; 1.1305x over previous
//
#include <hip/hip_runtime.h>
#include <hip/hip_bf16.h>
#include <math.h>

#define B_      16
#define NPUS    1024
#define MEMS    4096
#define INS     512
#define RS      256
#define MD      128
#define GRUIN   640
#define MMUO    644
#define NROWS   (B_*NPUS)   // 16384

// d_out flat offsets (reference return order)
#define O_OUT   0u
#define O_REGS  8388608u
#define O_WKEY  12582912u
#define O_WVAL  14680064u
#define O_WGATE 16777216u
#define O_SSDK  16793600u
#define O_SSDV  18890752u
#define O_SSDG  20987904u

typedef __attribute__((ext_vector_type(8))) short bf16x8;
typedef __attribute__((ext_vector_type(4))) float f32x4;
typedef __attribute__((ext_vector_type(4))) unsigned short u16x4;

__device__ __forceinline__ float sigf(float x){ return 1.f/(1.f+__expf(-x)); }
__device__ __forceinline__ unsigned short bfu(float x){
    __hip_bfloat16 h = __float2bfloat16(x);
    return __builtin_bit_cast(unsigned short, h);
}
// async global->LDS, 16B per lane; LDS dest is wave-uniform base + lane*16 (m104)
__device__ __forceinline__ void gload16(const void* g, void* s)
{
    __builtin_amdgcn_global_load_lds(
        (const __attribute__((address_space(1))) void*)g,
        (__attribute__((address_space(3))) void*)s, 16, 0, 0);
}

// ---------------- K_cvt: fp32 -> bf16, vectorized x4 ----------------
__global__ __launch_bounds__(256) void k_cvt(const float* __restrict__ src,
                                             unsigned short* __restrict__ dst, int n4)
{
    int i = blockIdx.x*256 + threadIdx.x;
    if (i >= n4) return;
    float4 v = ((const float4*)src)[i];
    u16x4 o = { bfu(v.x), bfu(v.y), bfu(v.z), bfu(v.w) };
    ((u16x4*)dst)[i] = o;
}

// ---------------- K_cvt5: fused 5-tensor fp32->bf16 (block-aligned segments) ----------------
__global__ __launch_bounds__(256) void k_cvt5(const float* __restrict__ s0, unsigned short* __restrict__ d0,
                                              const float* __restrict__ s1, unsigned short* __restrict__ d1,
                                              const float* __restrict__ s2, unsigned short* __restrict__ d2,
                                              const float* __restrict__ s3, unsigned short* __restrict__ d3,
                                              const float* __restrict__ s4, unsigned short* __restrict__ d4)
{
    int gi = blockIdx.x*256 + threadIdx.x;
    const float* s; unsigned short* d; int idx;
    if      (gi < 41216)  { s = s0; d = d0; idx = gi; }
    else if (gi < 164096) { s = s1; d = d1; idx = gi - 41216; }
    else if (gi < 213248) { s = s2; d = d2; idx = gi - 164096; }
    else if (gi < 246016) { s = s3; d = d3; idx = gi - 213248; }
    else                  { s = s4; d = d4; idx = gi - 246016; }
    float4 v = ((const float4*)s)[idx];
    u16x4 o = { bfu(v.x), bfu(v.y), bfu(v.z), bfu(v.w) };
    ((u16x4*)d)[idx] = o;
}

// ---------------- K0: memory_context -> bf16 row-major + transposed ----------------
__global__ __launch_bounds__(256) void k_conv(const float* __restrict__ mem,
                                              __hip_bfloat16* __restrict__ memB,
                                              __hip_bfloat16* __restrict__ memT)
{
    __shared__ float Ms[32][129];
    const int t = threadIdx.x;
    const int b = blockIdx.x >> 7;
    const int m0 = (blockIdx.x & 127) << 5;
    const float* src = mem + ((size_t)b*MEMS + m0)*MD;
    for (int idx = t; idx < 32*128; idx += 256) {
        int m = idx >> 7, d = idx & 127;
        float v = src[(size_t)m*MD + d];
        Ms[m][d] = v;
        memB[((size_t)b*MEMS + m0 + m)*MD + d] = __float2bfloat16(v);
    }
    __syncthreads();
    for (int idx = t; idx < 128*32; idx += 256) {
        int d = idx >> 5, m = idx & 31;
        memT[((size_t)b*MD + d)*MEMS + m0 + m] = __float2bfloat16(Ms[m][d]);
    }
}

// ---------------- K1: MMU GEMM (MFMA)  C[16384,644] = regs * Wmmu^T + b ----------------
__global__ __launch_bounds__(256) void k_mmu(const __hip_bfloat16* __restrict__ Ab,
                                             const __hip_bfloat16* __restrict__ Wb,
                                             const float* __restrict__ bias,
                                             float* __restrict__ out,
                                             __hip_bfloat16* __restrict__ qbf)
{
    const int t = threadIdx.x, w = t >> 6, l = t & 63;
    const int lg = l >> 4, ll = l & 15;
    const int m0 = blockIdx.x*64 + w*16;
    const int n0 = blockIdx.y*256;
    const short* A = (const short*)Ab;
    const short* W = (const short*)Wb;
    f32x4 acc[16];
    #pragma unroll
    for (int c = 0; c < 16; c++) acc[c] = (f32x4){0,0,0,0};
    for (int k0 = 0; k0 < RS; k0 += 32) {
        bf16x8 af = *(const bf16x8*)(A + (size_t)(m0+ll)*RS + k0 + lg*8);
        #pragma unroll
        for (int c = 0; c < 16; c++) {
            int n = n0 + c*16 + ll;
            bf16x8 bf = {};
            if (n < MMUO) bf = *(const bf16x8*)(W + (size_t)n*RS + k0 + lg*8);
            acc[c] = __builtin_amdgcn_mfma_f32_16x16x32_bf16(af, bf, acc[c], 0, 0, 0);
        }
    }
    #pragma unroll
    for (int c = 0; c < 16; c++) {
        int o = n0 + c*16 + ll;
        if (o >= MMUO) continue;
        float bv = bias[o];
        #pragma unroll
        for (int r = 0; r < 4; r++) {
            int row = m0 + lg*4 + r;
            float v = acc[c][r] + bv;
            if      (o < MD)        qbf[(size_t)row*MD + o] = __float2bfloat16(v * 0.08838834764831845f);
            else if (o < 2*MD)      out[O_WKEY + (size_t)row*MD + (o -   MD)] = v;
            else if (o < 3*MD)      out[O_WVAL + (size_t)row*MD + (o - 2*MD)] = v;
            else if (o == 3*MD)     out[O_WGATE + row] = sigf(v);
            else if (o < 4*MD + 1)  out[O_SSDK + (size_t)row*MD + (o - (3*MD+1))] = v;
            else if (o < 5*MD + 1)  out[O_SSDV + (size_t)row*MD + (o - (4*MD+1))] = v;
            else                    out[O_SSDG + (size_t)row*3  + (o - (5*MD+1))] = v;
        }
    }
}

// ---------------- K1b: softmax over the 3 ssd_gate logits ----------------
__global__ void k_softmax3(float* __restrict__ out)
{
    int r = blockIdx.x*256 + threadIdx.x;
    if (r >= NROWS) return;
    float* p = out + O_SSDG + (size_t)r*3;
    float a = p[0], b = p[1], c = p[2];
    float m = fmaxf(a, fmaxf(b, c));
    float ea = __expf(a-m), eb = __expf(b-m), ec = __expf(c-m);
    float inv = 1.f/(ea+eb+ec);
    p[0] = ea*inv; p[1] = eb*inv; p[2] = ec*inv;
}

// ---------------- K2: LDS-staged 4-way split-K flash attention, 16 q-rows/wave ----------------
// 1024 blocks x 4 waves; launch_bounds(256,3) caps regs at ~170 -> 3 blocks/CU
// co-resident (LDS 3x37KB=111KB < 160KB). Block: 64 q-rows, keys [kh*1024,+1024).
// K+V tile (32 keys, 16KB) double-buffered via global_load_lds; counted vmcnt(4).
// K swizzle (row&7 on 16 chunks), V swizzle ((row>>1)&3 on 4 chunks).
__global__ __launch_bounds__(256, 3) void k_attn(const __hip_bfloat16* __restrict__ qb,
                                                 const __hip_bfloat16* __restrict__ memB,
                                                 const __hip_bfloat16* __restrict__ memT,
                                                 float* __restrict__ Opart,
                                                 float* __restrict__ MLpart)
{
    __shared__ __hip_bfloat16 Kt[2][32][128];
    __shared__ __hip_bfloat16 Vt[2][128][32];
    __shared__ __hip_bfloat16 Pl[4][16][40];
    const int t = threadIdx.x, w = t >> 6, l = t & 63;
    const int lg = l >> 4, ll = l & 15;
    const int bid = blockIdx.x;
    const int xcd = bid & 7, rest = bid >> 3;      // rest 0..127
    const int b = xcd + ((rest >> 6) << 3);        // 2 batches per XCD
    const int sub = rest & 63;
    const int qblk = sub >> 2, kh = sub & 3;       // 16 q-blocks x 4 key-quarters
    const int qrow0 = (b << 10) + (qblk << 6) + (w << 4);   // wave's 16 q-rows
    const int k_beg = kh << 10;                             // 1024 keys per quarter
    const float THR = 4.0f;

    const short* Q = (const short*)qb;
    bf16x8 qf[4];
    #pragma unroll
    for (int ks = 0; ks < 4; ks++)
        qf[ks] = *(const bf16x8*)(Q + (size_t)(qrow0 + ll)*MD + ks*32 + lg*8);

    f32x4 O[8];
    #pragma unroll
    for (int dt = 0; dt < 8; dt++) O[dt] = (f32x4){0.f,0.f,0.f,0.f};
    float m_run[4], lsum[4];
    #pragma unroll
    for (int r = 0; r < 4; r++) { m_run[r] = -INFINITY; lsum[r] = 0.f; }

    const char* MbB = (const char*)memB + (size_t)b*MEMS*MD*2;
    const char* MtB = (const char*)memT + (size_t)b*MD*MEMS*2;

    auto stage = [&](int buf, int it) {
        const int k0 = k_beg + it*32;
        char* kbase = (char*)(&Kt[buf][0][0]);
        char* vbase = (char*)(&Vt[buf][0][0]);
        #pragma unroll
        for (int j = 0; j < 2; j++) {
            int ci = (w << 7) + (j << 6) + l;        // chunk 0..511 (16B each)
            int krow = ci >> 4, cc = ci & 15;
            int gc = cc ^ (krow & 7);                // pre-swizzled global source
            gload16(MbB + (size_t)(k0 + krow)*256 + gc*16,
                    kbase + (size_t)((w << 7) + (j << 6))*16);
        }
        #pragma unroll
        for (int j = 0; j < 2; j++) {
            int ci = (w << 7) + (j << 6) + l;
            int drow = ci >> 2, cc = ci & 3;
            int gc = cc ^ ((drow >> 1) & 3);         // V swizzle (both-sides involution)
            gload16(MtB + (size_t)drow*(MEMS*2) + (size_t)k0*2 + gc*16,
                    vbase + (size_t)((w << 7) + (j << 6))*16);
        }
    };

    stage(0, 0);
    asm volatile("s_waitcnt vmcnt(0)" ::: "memory");
    asm volatile("s_barrier" ::: "memory");
    int cur = 0;
    const int NIT = 1024/32;   // 32
    const int vsw = ((lg ^ ((ll >> 1) & 3)) << 4);
    for (int it = 0; it < NIT; ++it) {
        if (it + 1 < NIT) {
            stage(cur ^ 1, it + 1);
            asm volatile("s_waitcnt vmcnt(4)" ::: "memory");   // own stage(cur) done; next in flight
        } else {
            asm volatile("s_waitcnt vmcnt(0)" ::: "memory");
        }
        asm volatile("s_barrier" ::: "memory");                // everyone's stage(cur) done
        const char* kbase = (const char*)(&Kt[cur][0][0]);
        const char* vbase = (const char*)(&Vt[cur][0][0]);
        // QK^T: S[16q][32k]
        f32x4 s0 = (f32x4){0,0,0,0}, s1 = (f32x4){0,0,0,0};
        #pragma unroll
        for (int ks = 0; ks < 4; ks++) {
            int c0 = ks*4 + lg;
            int sw = (c0 ^ (ll & 7)) << 4;
            bf16x8 kf0 = *(const bf16x8*)(kbase + (size_t)ll*256 + sw);
            bf16x8 kf1 = *(const bf16x8*)(kbase + (size_t)(16 + ll)*256 + sw);
            s0 = __builtin_amdgcn_mfma_f32_16x16x32_bf16(qf[ks], kf0, s0, 0, 0, 0);
            s1 = __builtin_amdgcn_mfma_f32_16x16x32_bf16(qf[ks], kf1, s1, 0, 0, 0);
        }
        // defer-max (fast path: no cross-lane ops)
        bool need = false;
        #pragma unroll
        for (int r = 0; r < 4; r++) {
            need |= (s0[r] > m_run[r] + THR);
            need |= (s1[r] > m_run[r] + THR);
        }
        if (__any(need)) {
            #pragma unroll
            for (int r = 0; r < 4; r++) {
                float v = fmaxf(s0[r], s1[r]);
                v = fmaxf(v, __shfl_xor(v, 1));
                v = fmaxf(v, __shfl_xor(v, 2));
                v = fmaxf(v, __shfl_xor(v, 4));
                v = fmaxf(v, __shfl_xor(v, 8));
                float mnew = fmaxf(m_run[r], v);
                float alpha = __expf(m_run[r] - mnew);
                m_run[r] = mnew;
                lsum[r] *= alpha;
                #pragma unroll
                for (int dt = 0; dt < 8; dt++) O[dt][r] *= alpha;
            }
        }
        // P = exp(s - m), per-lane l partials
        #pragma unroll
        for (int r = 0; r < 4; r++) {
            float p0 = __expf(s0[r] - m_run[r]);
            float p1 = __expf(s1[r] - m_run[r]);
            Pl[w][lg*4 + r][ll]      = __float2bfloat16(p0);
            Pl[w][lg*4 + r][16 + ll] = __float2bfloat16(p1);
            lsum[r] += p0 + p1;
        }
        __builtin_amdgcn_wave_barrier();
        bf16x8 pa = *(const bf16x8*)(&Pl[w][ll][lg*8]);
        __builtin_amdgcn_wave_barrier();
        #pragma unroll
        for (int dt = 0; dt < 8; dt++) {
            bf16x8 vf = *(const bf16x8*)(vbase + (size_t)(dt*16 + ll)*64 + vsw);
            O[dt] = __builtin_amdgcn_mfma_f32_16x16x32_bf16(pa, vf, O[dt], 0, 0, 0);
        }
        asm volatile("s_barrier" ::: "memory");                // all reads of buf cur done
        cur ^= 1;
    }
    #pragma unroll
    for (int r = 0; r < 4; r++) {
        float s = lsum[r];
        s += __shfl_xor(s, 1);
        s += __shfl_xor(s, 2);
        s += __shfl_xor(s, 4);
        s += __shfl_xor(s, 8);
        lsum[r] = s;
    }
    #pragma unroll
    for (int dt = 0; dt < 8; dt++)
        #pragma unroll
        for (int r = 0; r < 4; r++) {
            int row = qrow0 + lg*4 + r;
            Opart[((size_t)row*4 + kh)*128 + dt*16 + ll] = O[dt][r];
        }
    if (ll == 0) {
        #pragma unroll
        for (int r = 0; r < 4; r++) {
            int row = qrow0 + lg*4 + r;
            MLpart[((size_t)row*4 + kh)*2 + 0] = m_run[r];
            MLpart[((size_t)row*4 + kh)*2 + 1] = lsum[r];
        }
    }
}

// ---------------- K2b: combine the 4 split-K partials -> rd bf16 ----------------
__global__ __launch_bounds__(256) void k_comb(const float* __restrict__ Opart,
                                              const float* __restrict__ MLpart,
                                              __hip_bfloat16* __restrict__ rdb)
{
    const int t = threadIdx.x;
    const int row = blockIdx.x*64 + (t >> 2);
    const int c0 = (t & 3) * 32;
    float m[4], lv[4], a[4];
    float M = -INFINITY;
    #pragma unroll
    for (int i = 0; i < 4; i++) {
        m[i]  = MLpart[((size_t)row*4 + i)*2 + 0];
        lv[i] = MLpart[((size_t)row*4 + i)*2 + 1];
        M = fmaxf(M, m[i]);
    }
    float L = 0.f;
    #pragma unroll
    for (int i = 0; i < 4; i++) { a[i] = __expf(m[i] - M); L += a[i]*lv[i]; }
    float invL = 1.f / L;
    #pragma unroll
    for (int i = 0; i < 4; i++) a[i] *= invL;
    unsigned short* dst = (unsigned short*)rdb + (size_t)row*128 + c0;
    #pragma unroll
    for (int j = 0; j < 8; j++) {
        float4 acc = {0.f,0.f,0.f,0.f};
        #pragma unroll
        for (int i = 0; i < 4; i++) {
            float4 x = ((const float4*)(Opart + ((size_t)row*4 + i)*128 + c0))[j];
            acc.x += a[i]*x.x; acc.y += a[i]*x.y; acc.z += a[i]*x.z; acc.w += a[i]*x.w;
        }
        u16x4 o = { bfu(acc.x), bfu(acc.y), bfu(acc.z), bfu(acc.w) };
        ((u16x4*)dst)[j] = o;
    }
}

// ---------------- K3: fused GRU (MFMA, LDS-staged double-buffered GEMM) ----------------
__global__ __launch_bounds__(256) void k_gru(const __hip_bfloat16* __restrict__ inpb,
                                             const __hip_bfloat16* __restrict__ rdb,
                                             const __hip_bfloat16* __restrict__ regsb,
                                             const float* __restrict__ regs,
                                             const __hip_bfloat16* __restrict__ Wihb,
                                             const float* __restrict__ bih,
                                             const __hip_bfloat16* __restrict__ Whhb,
                                             const float* __restrict__ bhh,
                                             float* __restrict__ newregs,
                                             __hip_bfloat16* __restrict__ nregsb)
{
    __shared__ __hip_bfloat16 At[2][64][32];
    __shared__ __hip_bfloat16 Bt[2][192][32];
    const int t = threadIdx.x, w = t >> 6, l = t & 63;
    const int lg = l >> 4, ll = l & 15;
    const int m0 = blockIdx.x*64;
    const int n0 = blockIdx.y*64;
    const int batch = blockIdx.x >> 4;
    const short* Xi = (const short*)inpb + (size_t)batch*INS;
    const short* Rd = (const short*)rdb;
    const short* Hb = (const short*)regsb;
    const short* Wi = (const short*)Wihb;
    const short* Wh = (const short*)Whhb;

    f32x4 aR[4], aZ[4], aNi[4], aNh[4];
    #pragma unroll
    for (int c = 0; c < 4; c++) {
        aR[c] = (f32x4){0,0,0,0}; aZ[c] = (f32x4){0,0,0,0};
        aNi[c] = (f32x4){0,0,0,0}; aNh[c] = (f32x4){0,0,0,0};
    }

    const int NIT1 = GRUIN/32;              // 20
    const int NIT  = NIT1 + RS/32;          // 28

    auto stage = [&](int buf, int it) {
        char* abase = (char*)(&At[buf][0][0]);
        char* bbase = (char*)(&Bt[buf][0][0]);
        {
            int ci = (w << 6) + l;
            int row = ci >> 2, cc = ci & 3;
            int gc = cc ^ ((row >> 1) & 3);
            const char* src;
            if (it < NIT1) {
                int k0 = it*32;
                if (k0 < INS) src = (const char*)(Xi + k0) + gc*16;
                else          src = (const char*)(Rd + (size_t)(m0+row)*MD + (k0 - INS)) + gc*16;
            } else {
                int k0 = (it - NIT1)*32;
                src = (const char*)(Hb + (size_t)(m0+row)*RS + k0) + gc*16;
            }
            gload16(src, abase + (size_t)((w << 6))*16);
        }
        #pragma unroll
        for (int j = 0; j < 3; j++) {
            int ci = w*192 + (j << 6) + l;
            int row = ci >> 2, cc = ci & 3;
            int gc = cc ^ ((row >> 1) & 3);
            int g = row >> 6, col = row & 63;
            const char* src;
            if (it < NIT1) {
                int k0 = it*32;
                src = (const char*)(Wi + (size_t)(g*RS + n0 + col)*GRUIN + k0) + gc*16;
            } else {
                int k0 = (it - NIT1)*32;
                src = (const char*)(Wh + (size_t)(g*RS + n0 + col)*RS + k0) + gc*16;
            }
            gload16(src, bbase + (size_t)(w*192 + (j << 6))*16);
        }
    };

    stage(0, 0);
    asm volatile("s_waitcnt vmcnt(0)" ::: "memory");
    __syncthreads();
    int cur = 0;
    const int arow = (w << 4) + ll;
    const int aswz = ((lg ^ ((arow >> 1) & 3)) << 4);
    for (int it = 0; it < NIT; ++it) {
        if (it + 1 < NIT) stage(cur ^ 1, it + 1);
        const char* ab = (const char*)(&At[cur][0][0]);
        const char* bb = (const char*)(&Bt[cur][0][0]);
        bf16x8 af = *(const bf16x8*)(ab + arow*64 + aswz);
        if (it < NIT1) {
            #pragma unroll
            for (int c = 0; c < 4; c++) {
                int r0 = c*16 + ll;
                int sw = ((lg ^ ((r0 >> 1) & 3)) << 4);
                bf16x8 bR = *(const bf16x8*)(bb + (size_t)r0*64 + sw);
                bf16x8 bZ = *(const bf16x8*)(bb + (size_t)(r0 + 64)*64 + sw);
                bf16x8 bN = *(const bf16x8*)(bb + (size_t)(r0 + 128)*64 + sw);
                aR[c]  = __builtin_amdgcn_mfma_f32_16x16x32_bf16(af, bR, aR[c],  0, 0, 0);
                aZ[c]  = __builtin_amdgcn_mfma_f32_16x16x32_bf16(af, bZ, aZ[c],  0, 0, 0);
                aNi[c] = __builtin_amdgcn_mfma_f32_16x16x32_bf16(af, bN, aNi[c], 0, 0, 0);
            }
        } else {
            #pragma unroll
            for (int c = 0; c < 4; c++) {
                int r0 = c*16 + ll;
                int sw = ((lg ^ ((r0 >> 1) & 3)) << 4);
                bf16x8 bR = *(const bf16x8*)(bb + (size_t)r0*64 + sw);
                bf16x8 bZ = *(const bf16x8*)(bb + (size_t)(r0 + 64)*64 + sw);
                bf16x8 bN = *(const bf16x8*)(bb + (size_t)(r0 + 128)*64 + sw);
                aR[c]  = __builtin_amdgcn_mfma_f32_16x16x32_bf16(af, bR, aR[c],  0, 0, 0);
                aZ[c]  = __builtin_amdgcn_mfma_f32_16x16x32_bf16(af, bZ, aZ[c],  0, 0, 0);
                aNh[c] = __builtin_amdgcn_mfma_f32_16x16x32_bf16(af, bN, aNh[c], 0, 0, 0);
            }
        }
        asm volatile("s_waitcnt vmcnt(0)" ::: "memory");
        __syncthreads();
        cur ^= 1;
    }
    const int wm0 = m0 + (w << 4);
    #pragma unroll
    for (int c = 0; c < 4; c++) {
        int o = n0 + c*16 + ll;
        float bR = bih[o]        + bhh[o];
        float bZ = bih[o +   RS] + bhh[o +   RS];
        float bNi = bih[o + 2*RS];
        float bNh = bhh[o + 2*RS];
        #pragma unroll
        for (int r = 0; r < 4; r++) {
            int row = wm0 + lg*4 + r;
            float rr = sigf(aR[c][r] + bR);
            float zz = sigf(aZ[c][r] + bZ);
            float nn = tanhf(aNi[c][r] + bNi + rr*(aNh[c][r] + bNh));
            float cv = regs[(size_t)row*RS + o];
            float nv = (1.f - zz)*nn + zz*cv;
            newregs[(size_t)row*RS + o] = nv;
            nregsb[(size_t)row*RS + o] = __float2bfloat16(nv);
        }
    }
}

// ---------------- K4: output GEMM (MFMA) ----------------
__global__ __launch_bounds__(256) void k_out(const __hip_bfloat16* __restrict__ Ab,
                                             const __hip_bfloat16* __restrict__ Wb,
                                             const float* __restrict__ bias,
                                             float* __restrict__ out0)
{
    const int t = threadIdx.x, w = t >> 6, l = t & 63;
    const int lg = l >> 4, ll = l & 15;
    const int m0 = blockIdx.x*64 + w*16;
    const int n0 = blockIdx.y*256;
    const short* A = (const short*)Ab;
    const short* W = (const short*)Wb;
    f32x4 acc[16];
    #pragma unroll
    for (int c = 0; c < 16; c++) acc[c] = (f32x4){0,0,0,0};
    for (int k0 = 0; k0 < RS; k0 += 32) {
        bf16x8 af = *(const bf16x8*)(A + (size_t)(m0+ll)*RS + k0 + lg*8);
        #pragma unroll
        for (int c = 0; c < 16; c++) {
            int n = n0 + c*16 + ll;
            bf16x8 bf = *(const bf16x8*)(W + (size_t)n*RS + k0 + lg*8);
            acc[c] = __builtin_amdgcn_mfma_f32_16x16x32_bf16(af, bf, acc[c], 0, 0, 0);
        }
    }
    #pragma unroll
    for (int c = 0; c < 16; c++) {
        int o = n0 + c*16 + ll;
        float bv = bias[o];
        #pragma unroll
        for (int r = 0; r < 4; r++) {
            int row = m0 + lg*4 + r;
            out0[(size_t)row*INS + o] = acc[c][r] + bv;
        }
    }
}

extern "C" void kernel_launch(void* const* d_in, const int* in_sizes, int n_in,
                              void* d_out, int out_size, void* d_ws, size_t ws_size,
                              hipStream_t stream)
{
    const float* inp  = (const float*)d_in[0];
    const float* regs = (const float*)d_in[1];
    const float* mem  = (const float*)d_in[2];
    const float* Wih  = (const float*)d_in[3];
    const float* bih  = (const float*)d_in[4];
    const float* Whh  = (const float*)d_in[5];
    const float* bhh  = (const float*)d_in[6];
    const float* Wmmu = (const float*)d_in[7];
    const float* bmmu = (const float*)d_in[8];
    const float* Wout = (const float*)d_in[9];
    const float* bout = (const float*)d_in[10];
    float* out = (float*)d_out;

    char* ws = (char*)d_ws;
    __hip_bfloat16* qbf    = (__hip_bfloat16*)(ws);
    __hip_bfloat16* rdb    = (__hip_bfloat16*)(ws + ((size_t)4<<20));
    __hip_bfloat16* memB   = (__hip_bfloat16*)(ws + ((size_t)8<<20));
    __hip_bfloat16* memT   = (__hip_bfloat16*)(ws + ((size_t)24<<20));
    __hip_bfloat16* regsb  = (__hip_bfloat16*)(ws + ((size_t)40<<20));
    __hip_bfloat16* nregsb = (__hip_bfloat16*)(ws + ((size_t)48<<20));
    __hip_bfloat16* Wmmub  = (__hip_bfloat16*)(ws + ((size_t)56<<20));
    __hip_bfloat16* Wihb   = (__hip_bfloat16*)(ws + ((size_t)56<<20) + ( 1<<20));
    __hip_bfloat16* Whhb   = (__hip_bfloat16*)(ws + ((size_t)56<<20) + ( 2<<20));
    __hip_bfloat16* Woutb  = (__hip_bfloat16*)(ws + ((size_t)56<<20) + ( 3<<20));
    __hip_bfloat16* inpb   = (__hip_bfloat16*)(ws + ((size_t)56<<20) + ( 4<<20));
    float*          MLpart = (float*)(ws + ((size_t)61<<20));            // 512 KB
    float*          Opart  = out + O_OUT;   // 33.5 MB, exactly the out0 region

    k_cvt5<<<969, 256, 0, stream>>>(Wmmu, (unsigned short*)Wmmub,
                                    Wih,  (unsigned short*)Wihb,
                                    Whh,  (unsigned short*)Whhb,
                                    Wout, (unsigned short*)Woutb,
                                    inp,  (unsigned short*)inpb);
    k_cvt<<<(4194304/4 + 255)/256, 256, 0, stream>>>(regs, (unsigned short*)regsb, 4194304/4);
    k_conv<<<B_*128, 256, 0, stream>>>(mem, memB, memT);

    dim3 g1(NROWS/64, 3);
    k_mmu<<<g1, 256, 0, stream>>>(regsb, Wmmub, bmmu, out, qbf);
    k_softmax3<<<NROWS/256, 256, 0, stream>>>(out);
    k_attn<<<1024, 256, 0, stream>>>(qbf, memB, memT, Opart, MLpart);
    k_comb<<<NROWS/64, 256, 0, stream>>>(Opart, MLpart, rdb);
    dim3 g3(NROWS/64, 4);
    k_gru<<<g3, 256, 0, stream>>>(inpb, rdb, regsb, regs, Wihb, bih, Whhb, bhh,
                                  out + O_REGS, nregsb);
    dim3 g4(NROWS/64, 2);
    k_out<<<g4, 256, 0, stream>>>(nregsb, Woutb, bout, out);
}

// Round 11
// 248.078 us; speedup vs baseline: 2.1835x; 1.0972x over previous
//
#include <hip/hip_runtime.h>
#include <hip/hip_bf16.h>
#include <math.h>

#define B_      16
#define NPUS    1024
#define MEMS    4096
#define INS     512
#define RS      256
#define MD      128
#define GRUIN   640
#define MMUO    644
#define NROWS   (B_*NPUS)   // 16384

// d_out flat offsets (reference return order)
#define O_OUT   0u
#define O_REGS  8388608u
#define O_WKEY  12582912u
#define O_WVAL  14680064u
#define O_WGATE 16777216u
#define O_SSDK  16793600u
#define O_SSDV  18890752u
#define O_SSDG  20987904u

typedef __attribute__((ext_vector_type(8))) short bf16x8;
typedef __attribute__((ext_vector_type(4))) float f32x4;
typedef __attribute__((ext_vector_type(4))) unsigned short u16x4;

__device__ __forceinline__ float sigf(float x){ return 1.f/(1.f+__expf(-x)); }
__device__ __forceinline__ unsigned short bfu(float x){
    __hip_bfloat16 h = __float2bfloat16(x);
    return __builtin_bit_cast(unsigned short, h);
}
// async global->LDS, 16B per lane; LDS dest is wave-uniform base + lane*16 (m104)
__device__ __forceinline__ void gload16(const void* g, void* s)
{
    __builtin_amdgcn_global_load_lds(
        (const __attribute__((address_space(1))) void*)g,
        (__attribute__((address_space(3))) void*)s, 16, 0, 0);
}

// ---------------- K_cvt: fp32 -> bf16, vectorized x4 ----------------
__global__ __launch_bounds__(256) void k_cvt(const float* __restrict__ src,
                                             unsigned short* __restrict__ dst, int n4)
{
    int i = blockIdx.x*256 + threadIdx.x;
    if (i >= n4) return;
    float4 v = ((const float4*)src)[i];
    u16x4 o = { bfu(v.x), bfu(v.y), bfu(v.z), bfu(v.w) };
    ((u16x4*)dst)[i] = o;
}

// ---------------- K_cvt5: fused 5-tensor fp32->bf16 (block-aligned segments) ----------------
__global__ __launch_bounds__(256) void k_cvt5(const float* __restrict__ s0, unsigned short* __restrict__ d0,
                                              const float* __restrict__ s1, unsigned short* __restrict__ d1,
                                              const float* __restrict__ s2, unsigned short* __restrict__ d2,
                                              const float* __restrict__ s3, unsigned short* __restrict__ d3,
                                              const float* __restrict__ s4, unsigned short* __restrict__ d4)
{
    int gi = blockIdx.x*256 + threadIdx.x;
    const float* s; unsigned short* d; int idx;
    if      (gi < 41216)  { s = s0; d = d0; idx = gi; }
    else if (gi < 164096) { s = s1; d = d1; idx = gi - 41216; }
    else if (gi < 213248) { s = s2; d = d2; idx = gi - 164096; }
    else if (gi < 246016) { s = s3; d = d3; idx = gi - 213248; }
    else                  { s = s4; d = d4; idx = gi - 246016; }
    float4 v = ((const float4*)s)[idx];
    u16x4 o = { bfu(v.x), bfu(v.y), bfu(v.z), bfu(v.w) };
    ((u16x4*)d)[idx] = o;
}

// ---------------- K_gi: gi0[16][768] = inp . Wih[:, :512]^T (fp32, once per batch) ----------------
// Exploits input_vector broadcast: this part of gi is row-independent within a batch.
__global__ __launch_bounds__(256) void k_gi(const float* __restrict__ inp,
                                            const float* __restrict__ Wih,
                                            float* __restrict__ gi0)
{
    __shared__ float xs[INS];
    const int b = blockIdx.x, seg = blockIdx.y;
    const int t = threadIdx.x;
    for (int i = t; i < INS; i += 256) xs[i] = inp[(size_t)b*INS + i];
    __syncthreads();
    const int o = seg*256 + t;                      // 0..767
    const float* wrow = Wih + (size_t)o*GRUIN;      // first 512 entries of row o
    float a0 = 0.f, a1 = 0.f, a2 = 0.f, a3 = 0.f;
    for (int k = 0; k < INS; k += 4) {
        float4 wv = *(const float4*)(wrow + k);
        a0 += xs[k]*wv.x; a1 += xs[k+1]*wv.y; a2 += xs[k+2]*wv.z; a3 += xs[k+3]*wv.w;
    }
    gi0[(size_t)b*768 + o] = (a0 + a1) + (a2 + a3);
}

// ---------------- K0: memory_context -> bf16 row-major + transposed ----------------
__global__ __launch_bounds__(256) void k_conv(const float* __restrict__ mem,
                                              __hip_bfloat16* __restrict__ memB,
                                              __hip_bfloat16* __restrict__ memT)
{
    __shared__ float Ms[32][129];
    const int t = threadIdx.x;
    const int b = blockIdx.x >> 7;
    const int m0 = (blockIdx.x & 127) << 5;
    const float* src = mem + ((size_t)b*MEMS + m0)*MD;
    for (int idx = t; idx < 32*128; idx += 256) {
        int m = idx >> 7, d = idx & 127;
        float v = src[(size_t)m*MD + d];
        Ms[m][d] = v;
        memB[((size_t)b*MEMS + m0 + m)*MD + d] = __float2bfloat16(v);
    }
    __syncthreads();
    for (int idx = t; idx < 128*32; idx += 256) {
        int d = idx >> 5, m = idx & 31;
        memT[((size_t)b*MD + d)*MEMS + m0 + m] = __float2bfloat16(Ms[m][d]);
    }
}

// ---------------- K1: MMU GEMM (MFMA)  C[16384,644] = regs * Wmmu^T + b ----------------
__global__ __launch_bounds__(256) void k_mmu(const __hip_bfloat16* __restrict__ Ab,
                                             const __hip_bfloat16* __restrict__ Wb,
                                             const float* __restrict__ bias,
                                             float* __restrict__ out,
                                             __hip_bfloat16* __restrict__ qbf)
{
    const int t = threadIdx.x, w = t >> 6, l = t & 63;
    const int lg = l >> 4, ll = l & 15;
    const int m0 = blockIdx.x*64 + w*16;
    const int n0 = blockIdx.y*256;
    const short* A = (const short*)Ab;
    const short* W = (const short*)Wb;
    f32x4 acc[16];
    #pragma unroll
    for (int c = 0; c < 16; c++) acc[c] = (f32x4){0,0,0,0};
    for (int k0 = 0; k0 < RS; k0 += 32) {
        bf16x8 af = *(const bf16x8*)(A + (size_t)(m0+ll)*RS + k0 + lg*8);
        #pragma unroll
        for (int c = 0; c < 16; c++) {
            int n = n0 + c*16 + ll;
            bf16x8 bf = {};
            if (n < MMUO) bf = *(const bf16x8*)(W + (size_t)n*RS + k0 + lg*8);
            acc[c] = __builtin_amdgcn_mfma_f32_16x16x32_bf16(af, bf, acc[c], 0, 0, 0);
        }
    }
    #pragma unroll
    for (int c = 0; c < 16; c++) {
        int o = n0 + c*16 + ll;
        if (o >= MMUO) continue;
        float bv = bias[o];
        #pragma unroll
        for (int r = 0; r < 4; r++) {
            int row = m0 + lg*4 + r;
            float v = acc[c][r] + bv;
            if      (o < MD)        qbf[(size_t)row*MD + o] = __float2bfloat16(v * 0.08838834764831845f);
            else if (o < 2*MD)      out[O_WKEY + (size_t)row*MD + (o -   MD)] = v;
            else if (o < 3*MD)      out[O_WVAL + (size_t)row*MD + (o - 2*MD)] = v;
            else if (o == 3*MD)     out[O_WGATE + row] = sigf(v);
            else if (o < 4*MD + 1)  out[O_SSDK + (size_t)row*MD + (o - (3*MD+1))] = v;
            else if (o < 5*MD + 1)  out[O_SSDV + (size_t)row*MD + (o - (4*MD+1))] = v;
            else                    out[O_SSDG + (size_t)row*3  + (o - (5*MD+1))] = v;
        }
    }
}

// ---------------- K1b: softmax over the 3 ssd_gate logits ----------------
__global__ void k_softmax3(float* __restrict__ out)
{
    int r = blockIdx.x*256 + threadIdx.x;
    if (r >= NROWS) return;
    float* p = out + O_SSDG + (size_t)r*3;
    float a = p[0], b = p[1], c = p[2];
    float m = fmaxf(a, fmaxf(b, c));
    float ea = __expf(a-m), eb = __expf(b-m), ec = __expf(c-m);
    float inv = 1.f/(ea+eb+ec);
    p[0] = ea*inv; p[1] = eb*inv; p[2] = ec*inv;
}

// ---------------- K2: LDS-staged 4-way split-K flash attention, 16 q-rows/wave ----------------
__global__ __launch_bounds__(256, 3) void k_attn(const __hip_bfloat16* __restrict__ qb,
                                                 const __hip_bfloat16* __restrict__ memB,
                                                 const __hip_bfloat16* __restrict__ memT,
                                                 float* __restrict__ Opart,
                                                 float* __restrict__ MLpart)
{
    __shared__ __hip_bfloat16 Kt[2][32][128];
    __shared__ __hip_bfloat16 Vt[2][128][32];
    __shared__ __hip_bfloat16 Pl[4][16][40];
    const int t = threadIdx.x, w = t >> 6, l = t & 63;
    const int lg = l >> 4, ll = l & 15;
    const int bid = blockIdx.x;
    const int xcd = bid & 7, rest = bid >> 3;      // rest 0..127
    const int b = xcd + ((rest >> 6) << 3);        // 2 batches per XCD
    const int sub = rest & 63;
    const int qblk = sub >> 2, kh = sub & 3;       // 16 q-blocks x 4 key-quarters
    const int qrow0 = (b << 10) + (qblk << 6) + (w << 4);   // wave's 16 q-rows
    const int k_beg = kh << 10;                             // 1024 keys per quarter
    const float THR = 4.0f;

    const short* Q = (const short*)qb;
    bf16x8 qf[4];
    #pragma unroll
    for (int ks = 0; ks < 4; ks++)
        qf[ks] = *(const bf16x8*)(Q + (size_t)(qrow0 + ll)*MD + ks*32 + lg*8);

    f32x4 O[8];
    #pragma unroll
    for (int dt = 0; dt < 8; dt++) O[dt] = (f32x4){0.f,0.f,0.f,0.f};
    float m_run[4], lsum[4];
    #pragma unroll
    for (int r = 0; r < 4; r++) { m_run[r] = -INFINITY; lsum[r] = 0.f; }

    const char* MbB = (const char*)memB + (size_t)b*MEMS*MD*2;
    const char* MtB = (const char*)memT + (size_t)b*MD*MEMS*2;

    auto stage = [&](int buf, int it) {
        const int k0 = k_beg + it*32;
        char* kbase = (char*)(&Kt[buf][0][0]);
        char* vbase = (char*)(&Vt[buf][0][0]);
        #pragma unroll
        for (int j = 0; j < 2; j++) {
            int ci = (w << 7) + (j << 6) + l;        // chunk 0..511 (16B each)
            int krow = ci >> 4, cc = ci & 15;
            int gc = cc ^ (krow & 7);                // pre-swizzled global source
            gload16(MbB + (size_t)(k0 + krow)*256 + gc*16,
                    kbase + (size_t)((w << 7) + (j << 6))*16);
        }
        #pragma unroll
        for (int j = 0; j < 2; j++) {
            int ci = (w << 7) + (j << 6) + l;
            int drow = ci >> 2, cc = ci & 3;
            int gc = cc ^ ((drow >> 1) & 3);         // V swizzle (both-sides involution)
            gload16(MtB + (size_t)drow*(MEMS*2) + (size_t)k0*2 + gc*16,
                    vbase + (size_t)((w << 7) + (j << 6))*16);
        }
    };

    stage(0, 0);
    asm volatile("s_waitcnt vmcnt(0)" ::: "memory");
    asm volatile("s_barrier" ::: "memory");
    int cur = 0;
    const int NIT = 1024/32;   // 32
    const int vsw = ((lg ^ ((ll >> 1) & 3)) << 4);
    for (int it = 0; it < NIT; ++it) {
        if (it + 1 < NIT) {
            stage(cur ^ 1, it + 1);
            asm volatile("s_waitcnt vmcnt(4)" ::: "memory");   // own stage(cur) done; next in flight
        } else {
            asm volatile("s_waitcnt vmcnt(0)" ::: "memory");
        }
        asm volatile("s_barrier" ::: "memory");                // everyone's stage(cur) done
        const char* kbase = (const char*)(&Kt[cur][0][0]);
        const char* vbase = (const char*)(&Vt[cur][0][0]);
        // QK^T: S[16q][32k]
        f32x4 s0 = (f32x4){0,0,0,0}, s1 = (f32x4){0,0,0,0};
        #pragma unroll
        for (int ks = 0; ks < 4; ks++) {
            int c0 = ks*4 + lg;
            int sw = (c0 ^ (ll & 7)) << 4;
            bf16x8 kf0 = *(const bf16x8*)(kbase + (size_t)ll*256 + sw);
            bf16x8 kf1 = *(const bf16x8*)(kbase + (size_t)(16 + ll)*256 + sw);
            s0 = __builtin_amdgcn_mfma_f32_16x16x32_bf16(qf[ks], kf0, s0, 0, 0, 0);
            s1 = __builtin_amdgcn_mfma_f32_16x16x32_bf16(qf[ks], kf1, s1, 0, 0, 0);
        }
        // defer-max (fast path: no cross-lane ops)
        bool need = false;
        #pragma unroll
        for (int r = 0; r < 4; r++) {
            need |= (s0[r] > m_run[r] + THR);
            need |= (s1[r] > m_run[r] + THR);
        }
        if (__any(need)) {
            #pragma unroll
            for (int r = 0; r < 4; r++) {
                float v = fmaxf(s0[r], s1[r]);
                v = fmaxf(v, __shfl_xor(v, 1));
                v = fmaxf(v, __shfl_xor(v, 2));
                v = fmaxf(v, __shfl_xor(v, 4));
                v = fmaxf(v, __shfl_xor(v, 8));
                float mnew = fmaxf(m_run[r], v);
                float alpha = __expf(m_run[r] - mnew);
                m_run[r] = mnew;
                lsum[r] *= alpha;
                #pragma unroll
                for (int dt = 0; dt < 8; dt++) O[dt][r] *= alpha;
            }
        }
        // P = exp(s - m), per-lane l partials
        #pragma unroll
        for (int r = 0; r < 4; r++) {
            float p0 = __expf(s0[r] - m_run[r]);
            float p1 = __expf(s1[r] - m_run[r]);
            Pl[w][lg*4 + r][ll]      = __float2bfloat16(p0);
            Pl[w][lg*4 + r][16 + ll] = __float2bfloat16(p1);
            lsum[r] += p0 + p1;
        }
        __builtin_amdgcn_wave_barrier();
        bf16x8 pa = *(const bf16x8*)(&Pl[w][ll][lg*8]);
        __builtin_amdgcn_wave_barrier();
        #pragma unroll
        for (int dt = 0; dt < 8; dt++) {
            bf16x8 vf = *(const bf16x8*)(vbase + (size_t)(dt*16 + ll)*64 + vsw);
            O[dt] = __builtin_amdgcn_mfma_f32_16x16x32_bf16(pa, vf, O[dt], 0, 0, 0);
        }
        asm volatile("s_barrier" ::: "memory");                // all reads of buf cur done
        cur ^= 1;
    }
    #pragma unroll
    for (int r = 0; r < 4; r++) {
        float s = lsum[r];
        s += __shfl_xor(s, 1);
        s += __shfl_xor(s, 2);
        s += __shfl_xor(s, 4);
        s += __shfl_xor(s, 8);
        lsum[r] = s;
    }
    #pragma unroll
    for (int dt = 0; dt < 8; dt++)
        #pragma unroll
        for (int r = 0; r < 4; r++) {
            int row = qrow0 + lg*4 + r;
            Opart[((size_t)row*4 + kh)*128 + dt*16 + ll] = O[dt][r];
        }
    if (ll == 0) {
        #pragma unroll
        for (int r = 0; r < 4; r++) {
            int row = qrow0 + lg*4 + r;
            MLpart[((size_t)row*4 + kh)*2 + 0] = m_run[r];
            MLpart[((size_t)row*4 + kh)*2 + 1] = lsum[r];
        }
    }
}

// ---------------- K2b: combine the 4 split-K partials -> rd bf16 ----------------
__global__ __launch_bounds__(256) void k_comb(const float* __restrict__ Opart,
                                              const float* __restrict__ MLpart,
                                              __hip_bfloat16* __restrict__ rdb)
{
    const int t = threadIdx.x;
    const int row = blockIdx.x*64 + (t >> 2);
    const int c0 = (t & 3) * 32;
    float m[4], lv[4], a[4];
    float M = -INFINITY;
    #pragma unroll
    for (int i = 0; i < 4; i++) {
        m[i]  = MLpart[((size_t)row*4 + i)*2 + 0];
        lv[i] = MLpart[((size_t)row*4 + i)*2 + 1];
        M = fmaxf(M, m[i]);
    }
    float L = 0.f;
    #pragma unroll
    for (int i = 0; i < 4; i++) { a[i] = __expf(m[i] - M); L += a[i]*lv[i]; }
    float invL = 1.f / L;
    #pragma unroll
    for (int i = 0; i < 4; i++) a[i] *= invL;
    unsigned short* dst = (unsigned short*)rdb + (size_t)row*128 + c0;
    #pragma unroll
    for (int j = 0; j < 8; j++) {
        float4 acc = {0.f,0.f,0.f,0.f};
        #pragma unroll
        for (int i = 0; i < 4; i++) {
            float4 x = ((const float4*)(Opart + ((size_t)row*4 + i)*128 + c0))[j];
            acc.x += a[i]*x.x; acc.y += a[i]*x.y; acc.z += a[i]*x.z; acc.w += a[i]*x.w;
        }
        u16x4 o = { bfu(acc.x), bfu(acc.y), bfu(acc.z), bfu(acc.w) };
        ((u16x4*)dst)[j] = o;
    }
}

// ---------------- K3: fused GRU (MFMA, LDS-staged, gi0-precomputed) ----------------
// Accumulators init from gi0 (inp part, fp32-exact). K-loop: 4 iters over rd
// (Wih[:,512:640]) then 8 over h (Whh) = 12 staged iters (was 28). Staging
// source pointers precomputed per-thread, advanced +64B/iter (no per-iter calc).
__global__ __launch_bounds__(256) void k_gru(const float* __restrict__ gi0,
                                             const __hip_bfloat16* __restrict__ rdb,
                                             const __hip_bfloat16* __restrict__ regsb,
                                             const float* __restrict__ regs,
                                             const __hip_bfloat16* __restrict__ Wihb,
                                             const float* __restrict__ bih,
                                             const __hip_bfloat16* __restrict__ Whhb,
                                             const float* __restrict__ bhh,
                                             float* __restrict__ newregs,
                                             __hip_bfloat16* __restrict__ nregsb)
{
    __shared__ __hip_bfloat16 At[2][64][32];
    __shared__ __hip_bfloat16 Bt[2][192][32];
    const int t = threadIdx.x, w = t >> 6, l = t & 63;
    const int lg = l >> 4, ll = l & 15;
    const int m0 = blockIdx.x*64;
    const int n0 = blockIdx.y*64;
    const int batch = blockIdx.x >> 4;
    const short* Rd = (const short*)rdb;
    const short* Hb = (const short*)regsb;
    const short* Wi = (const short*)Wihb;
    const short* Wh = (const short*)Whhb;

    // acc init from gi0 (constant across the 4 row-slots of each fragment)
    f32x4 aR[4], aZ[4], aNi[4], aNh[4];
    #pragma unroll
    for (int c = 0; c < 4; c++) {
        int o = n0 + c*16 + ll;
        float gR = gi0[(size_t)batch*768 + o];
        float gZ = gi0[(size_t)batch*768 + 256 + o];
        float gN = gi0[(size_t)batch*768 + 512 + o];
        aR[c]  = (f32x4){gR,gR,gR,gR};
        aZ[c]  = (f32x4){gZ,gZ,gZ,gZ};
        aNi[c] = (f32x4){gN,gN,gN,gN};
        aNh[c] = (f32x4){0,0,0,0};
    }

    // per-thread staging sources, +64B per iteration
    const int aci = (w << 6) + l;
    const int arow_s = aci >> 2, acc_s = aci & 3;
    const int agc = acc_s ^ ((arow_s >> 1) & 3);
    const char* aSrcA = (const char*)(Rd + (size_t)(m0+arow_s)*MD) + agc*16;
    const char* aSrcB = (const char*)(Hb + (size_t)(m0+arow_s)*RS) + agc*16;
    const char* bSrcA0; const char* bSrcA1; const char* bSrcA2;
    const char* bSrcB0; const char* bSrcB1; const char* bSrcB2;
    {
        int ci, row, cc, gc, g, col;
        ci = w*192 + 0*64 + l; row = ci >> 2; cc = ci & 3; gc = cc ^ ((row >> 1) & 3);
        g = row >> 6; col = row & 63;
        bSrcA0 = (const char*)(Wi + (size_t)(g*RS + n0 + col)*GRUIN + INS) + gc*16;
        bSrcB0 = (const char*)(Wh + (size_t)(g*RS + n0 + col)*RS) + gc*16;
        ci = w*192 + 1*64 + l; row = ci >> 2; cc = ci & 3; gc = cc ^ ((row >> 1) & 3);
        g = row >> 6; col = row & 63;
        bSrcA1 = (const char*)(Wi + (size_t)(g*RS + n0 + col)*GRUIN + INS) + gc*16;
        bSrcB1 = (const char*)(Wh + (size_t)(g*RS + n0 + col)*RS) + gc*16;
        ci = w*192 + 2*64 + l; row = ci >> 2; cc = ci & 3; gc = cc ^ ((row >> 1) & 3);
        g = row >> 6; col = row & 63;
        bSrcA2 = (const char*)(Wi + (size_t)(g*RS + n0 + col)*GRUIN + INS) + gc*16;
        bSrcB2 = (const char*)(Wh + (size_t)(g*RS + n0 + col)*RS) + gc*16;
    }

    const int NITA = 4, NIT = 12;   // 4 rd-iters (K=128) + 8 h-iters (K=256)
    auto stage = [&](int buf, int it) {
        char* abase = (char*)(&At[buf][0][0]) + (size_t)(w << 6)*16;
        char* bbase = (char*)(&Bt[buf][0][0]) + (size_t)(w*192)*16;
        const char *as, *b0, *b1, *b2;
        if (it < NITA) {
            int off = it*64;
            as = aSrcA + off; b0 = bSrcA0 + off; b1 = bSrcA1 + off; b2 = bSrcA2 + off;
        } else {
            int off = (it - NITA)*64;
            as = aSrcB + off; b0 = bSrcB0 + off; b1 = bSrcB1 + off; b2 = bSrcB2 + off;
        }
        gload16(as, abase);
        gload16(b0, bbase);
        gload16(b1, bbase + 64*16);
        gload16(b2, bbase + 128*16);
    };

    stage(0, 0);
    asm volatile("s_waitcnt vmcnt(0)" ::: "memory");
    __syncthreads();
    int cur = 0;
    const int arow = (w << 4) + ll;
    const int aswz = ((lg ^ ((arow >> 1) & 3)) << 4);
    for (int it = 0; it < NIT; ++it) {
        if (it + 1 < NIT) stage(cur ^ 1, it + 1);
        const char* ab = (const char*)(&At[cur][0][0]);
        const char* bb = (const char*)(&Bt[cur][0][0]);
        bf16x8 af = *(const bf16x8*)(ab + arow*64 + aswz);
        if (it < NITA) {
            #pragma unroll
            for (int c = 0; c < 4; c++) {
                int r0 = c*16 + ll;
                int sw = ((lg ^ ((r0 >> 1) & 3)) << 4);
                bf16x8 bR = *(const bf16x8*)(bb + (size_t)r0*64 + sw);
                bf16x8 bZ = *(const bf16x8*)(bb + (size_t)(r0 + 64)*64 + sw);
                bf16x8 bN = *(const bf16x8*)(bb + (size_t)(r0 + 128)*64 + sw);
                aR[c]  = __builtin_amdgcn_mfma_f32_16x16x32_bf16(af, bR, aR[c],  0, 0, 0);
                aZ[c]  = __builtin_amdgcn_mfma_f32_16x16x32_bf16(af, bZ, aZ[c],  0, 0, 0);
                aNi[c] = __builtin_amdgcn_mfma_f32_16x16x32_bf16(af, bN, aNi[c], 0, 0, 0);
            }
        } else {
            #pragma unroll
            for (int c = 0; c < 4; c++) {
                int r0 = c*16 + ll;
                int sw = ((lg ^ ((r0 >> 1) & 3)) << 4);
                bf16x8 bR = *(const bf16x8*)(bb + (size_t)r0*64 + sw);
                bf16x8 bZ = *(const bf16x8*)(bb + (size_t)(r0 + 64)*64 + sw);
                bf16x8 bN = *(const bf16x8*)(bb + (size_t)(r0 + 128)*64 + sw);
                aR[c]  = __builtin_amdgcn_mfma_f32_16x16x32_bf16(af, bR, aR[c],  0, 0, 0);
                aZ[c]  = __builtin_amdgcn_mfma_f32_16x16x32_bf16(af, bZ, aZ[c],  0, 0, 0);
                aNh[c] = __builtin_amdgcn_mfma_f32_16x16x32_bf16(af, bN, aNh[c], 0, 0, 0);
            }
        }
        asm volatile("s_waitcnt vmcnt(0)" ::: "memory");
        __syncthreads();
        cur ^= 1;
    }
    const int wm0 = m0 + (w << 4);
    #pragma unroll
    for (int c = 0; c < 4; c++) {
        int o = n0 + c*16 + ll;
        float bR = bih[o]        + bhh[o];
        float bZ = bih[o +   RS] + bhh[o +   RS];
        float bNi = bih[o + 2*RS];
        float bNh = bhh[o + 2*RS];
        #pragma unroll
        for (int r = 0; r < 4; r++) {
            int row = wm0 + lg*4 + r;
            float rr = sigf(aR[c][r] + bR);
            float zz = sigf(aZ[c][r] + bZ);
            float nn = tanhf(aNi[c][r] + bNi + rr*(aNh[c][r] + bNh));
            float cv = regs[(size_t)row*RS + o];
            float nv = (1.f - zz)*nn + zz*cv;
            newregs[(size_t)row*RS + o] = nv;
            nregsb[(size_t)row*RS + o] = __float2bfloat16(nv);
        }
    }
}

// ---------------- K4: output GEMM (MFMA) ----------------
__global__ __launch_bounds__(256) void k_out(const __hip_bfloat16* __restrict__ Ab,
                                             const __hip_bfloat16* __restrict__ Wb,
                                             const float* __restrict__ bias,
                                             float* __restrict__ out0)
{
    const int t = threadIdx.x, w = t >> 6, l = t & 63;
    const int lg = l >> 4, ll = l & 15;
    const int m0 = blockIdx.x*64 + w*16;
    const int n0 = blockIdx.y*256;
    const short* A = (const short*)Ab;
    const short* W = (const short*)Wb;
    f32x4 acc[16];
    #pragma unroll
    for (int c = 0; c < 16; c++) acc[c] = (f32x4){0,0,0,0};
    for (int k0 = 0; k0 < RS; k0 += 32) {
        bf16x8 af = *(const bf16x8*)(A + (size_t)(m0+ll)*RS + k0 + lg*8);
        #pragma unroll
        for (int c = 0; c < 16; c++) {
            int n = n0 + c*16 + ll;
            bf16x8 bf = *(const bf16x8*)(W + (size_t)n*RS + k0 + lg*8);
            acc[c] = __builtin_amdgcn_mfma_f32_16x16x32_bf16(af, bf, acc[c], 0, 0, 0);
        }
    }
    #pragma unroll
    for (int c = 0; c < 16; c++) {
        int o = n0 + c*16 + ll;
        float bv = bias[o];
        #pragma unroll
        for (int r = 0; r < 4; r++) {
            int row = m0 + lg*4 + r;
            out0[(size_t)row*INS + o] = acc[c][r] + bv;
        }
    }
}

extern "C" void kernel_launch(void* const* d_in, const int* in_sizes, int n_in,
                              void* d_out, int out_size, void* d_ws, size_t ws_size,
                              hipStream_t stream)
{
    const float* inp  = (const float*)d_in[0];
    const float* regs = (const float*)d_in[1];
    const float* mem  = (const float*)d_in[2];
    const float* Wih  = (const float*)d_in[3];
    const float* bih  = (const float*)d_in[4];
    const float* Whh  = (const float*)d_in[5];
    const float* bhh  = (const float*)d_in[6];
    const float* Wmmu = (const float*)d_in[7];
    const float* bmmu = (const float*)d_in[8];
    const float* Wout = (const float*)d_in[9];
    const float* bout = (const float*)d_in[10];
    float* out = (float*)d_out;

    char* ws = (char*)d_ws;
    __hip_bfloat16* qbf    = (__hip_bfloat16*)(ws);
    __hip_bfloat16* rdb    = (__hip_bfloat16*)(ws + ((size_t)4<<20));
    __hip_bfloat16* memB   = (__hip_bfloat16*)(ws + ((size_t)8<<20));
    __hip_bfloat16* memT   = (__hip_bfloat16*)(ws + ((size_t)24<<20));
    __hip_bfloat16* regsb  = (__hip_bfloat16*)(ws + ((size_t)40<<20));
    __hip_bfloat16* nregsb = (__hip_bfloat16*)(ws + ((size_t)48<<20));
    __hip_bfloat16* Wmmub  = (__hip_bfloat16*)(ws + ((size_t)56<<20));
    __hip_bfloat16* Wihb   = (__hip_bfloat16*)(ws + ((size_t)56<<20) + ( 1<<20));
    __hip_bfloat16* Whhb   = (__hip_bfloat16*)(ws + ((size_t)56<<20) + ( 2<<20));
    __hip_bfloat16* Woutb  = (__hip_bfloat16*)(ws + ((size_t)56<<20) + ( 3<<20));
    __hip_bfloat16* inpb   = (__hip_bfloat16*)(ws + ((size_t)56<<20) + ( 4<<20));
    float*          MLpart = (float*)(ws + ((size_t)61<<20));            // 512 KB
    float*          gi0    = (float*)(ws + ((size_t)61<<20) + (1<<19));  // 49 KB
    float*          Opart  = out + O_OUT;   // 33.5 MB, exactly the out0 region

    dim3 ggi(B_, 3);
    k_gi<<<ggi, 256, 0, stream>>>(inp, Wih, gi0);
    k_cvt5<<<969, 256, 0, stream>>>(Wmmu, (unsigned short*)Wmmub,
                                    Wih,  (unsigned short*)Wihb,
                                    Whh,  (unsigned short*)Whhb,
                                    Wout, (unsigned short*)Woutb,
                                    inp,  (unsigned short*)inpb);
    k_cvt<<<(4194304/4 + 255)/256, 256, 0, stream>>>(regs, (unsigned short*)regsb, 4194304/4);
    k_conv<<<B_*128, 256, 0, stream>>>(mem, memB, memT);

    dim3 g1(NROWS/64, 3);
    k_mmu<<<g1, 256, 0, stream>>>(regsb, Wmmub, bmmu, out, qbf);
    k_softmax3<<<NROWS/256, 256, 0, stream>>>(out);
    k_attn<<<1024, 256, 0, stream>>>(qbf, memB, memT, Opart, MLpart);
    k_comb<<<NROWS/64, 256, 0, stream>>>(Opart, MLpart, rdb);
    dim3 g3(NROWS/64, 4);
    k_gru<<<g3, 256, 0, stream>>>(gi0, rdb, regsb, regs, Wihb, bih, Whhb, bhh,
                                  out + O_REGS, nregsb);
    dim3 g4(NROWS/64, 2);
    k_out<<<g4, 256, 0, stream>>>(nregsb, Woutb, bout, out);
}

// Round 12
// 185.022 us; speedup vs baseline: 2.9276x; 1.3408x over previous
//
#include <hip/hip_runtime.h>
#include <hip/hip_bf16.h>
#include <math.h>

#define B_      16
#define NPUS    1024
#define MEMS    4096
#define INS     512
#define RS      256
#define MD      128
#define GRUIN   640
#define MMUO    644
#define NROWS   (B_*NPUS)   // 16384

// d_out flat offsets (reference return order)
#define O_OUT   0u
#define O_REGS  8388608u
#define O_WKEY  12582912u
#define O_WVAL  14680064u
#define O_WGATE 16777216u
#define O_SSDK  16793600u
#define O_SSDV  18890752u
#define O_SSDG  20987904u

typedef __attribute__((ext_vector_type(8))) short bf16x8;
typedef __attribute__((ext_vector_type(4))) float f32x4;
typedef __attribute__((ext_vector_type(4))) unsigned short u16x4;

__device__ __forceinline__ float sigf(float x){ return 1.f/(1.f+__expf(-x)); }
__device__ __forceinline__ unsigned short bfu(float x){
    __hip_bfloat16 h = __float2bfloat16(x);
    return __builtin_bit_cast(unsigned short, h);
}
// async global->LDS, 16B per lane; LDS dest is wave-uniform base + lane*16 (m104)
__device__ __forceinline__ void gload16(const void* g, void* s)
{
    __builtin_amdgcn_global_load_lds(
        (const __attribute__((address_space(1))) void*)g,
        (__attribute__((address_space(3))) void*)s, 16, 0, 0);
}

// ---------------- K_cvt: fp32 -> bf16, vectorized x4 ----------------
__global__ __launch_bounds__(256) void k_cvt(const float* __restrict__ src,
                                             unsigned short* __restrict__ dst, int n4)
{
    int i = blockIdx.x*256 + threadIdx.x;
    if (i >= n4) return;
    float4 v = ((const float4*)src)[i];
    u16x4 o = { bfu(v.x), bfu(v.y), bfu(v.z), bfu(v.w) };
    ((u16x4*)dst)[i] = o;
}

// ---------------- K_cvt5: fused 5-tensor fp32->bf16 (block-aligned segments) ----------------
__global__ __launch_bounds__(256) void k_cvt5(const float* __restrict__ s0, unsigned short* __restrict__ d0,
                                              const float* __restrict__ s1, unsigned short* __restrict__ d1,
                                              const float* __restrict__ s2, unsigned short* __restrict__ d2,
                                              const float* __restrict__ s3, unsigned short* __restrict__ d3,
                                              const float* __restrict__ s4, unsigned short* __restrict__ d4)
{
    int gi = blockIdx.x*256 + threadIdx.x;
    const float* s; unsigned short* d; int idx;
    if      (gi < 41216)  { s = s0; d = d0; idx = gi; }
    else if (gi < 164096) { s = s1; d = d1; idx = gi - 41216; }
    else if (gi < 213248) { s = s2; d = d2; idx = gi - 164096; }
    else if (gi < 246016) { s = s3; d = d3; idx = gi - 213248; }
    else                  { s = s4; d = d4; idx = gi - 246016; }
    float4 v = ((const float4*)s)[idx];
    u16x4 o = { bfu(v.x), bfu(v.y), bfu(v.z), bfu(v.w) };
    ((u16x4*)d)[idx] = o;
}

// ---------------- K_gi: gi0[16][768] = inp . Wih[:, :512]^T (fp32, once per batch) ----------------
__global__ __launch_bounds__(256) void k_gi(const float* __restrict__ inp,
                                            const float* __restrict__ Wih,
                                            float* __restrict__ gi0)
{
    __shared__ float xs[INS];
    const int b = blockIdx.x, seg = blockIdx.y;
    const int t = threadIdx.x;
    for (int i = t; i < INS; i += 256) xs[i] = inp[(size_t)b*INS + i];
    __syncthreads();
    const int o = seg*256 + t;                      // 0..767
    const float* wrow = Wih + (size_t)o*GRUIN;
    float a0 = 0.f, a1 = 0.f, a2 = 0.f, a3 = 0.f;
    for (int k = 0; k < INS; k += 4) {
        float4 wv = *(const float4*)(wrow + k);
        a0 += xs[k]*wv.x; a1 += xs[k+1]*wv.y; a2 += xs[k+2]*wv.z; a3 += xs[k+3]*wv.w;
    }
    gi0[(size_t)b*768 + o] = (a0 + a1) + (a2 + a3);
}

// ---------------- K0: memory_context -> bf16 row-major + transposed ----------------
__global__ __launch_bounds__(256) void k_conv(const float* __restrict__ mem,
                                              __hip_bfloat16* __restrict__ memB,
                                              __hip_bfloat16* __restrict__ memT)
{
    __shared__ float Ms[32][129];
    const int t = threadIdx.x;
    const int b = blockIdx.x >> 7;
    const int m0 = (blockIdx.x & 127) << 5;
    const float* src = mem + ((size_t)b*MEMS + m0)*MD;
    for (int idx = t; idx < 32*128; idx += 256) {
        int m = idx >> 7, d = idx & 127;
        float v = src[(size_t)m*MD + d];
        Ms[m][d] = v;
        memB[((size_t)b*MEMS + m0 + m)*MD + d] = __float2bfloat16(v);
    }
    __syncthreads();
    for (int idx = t; idx < 128*32; idx += 256) {
        int d = idx >> 5, m = idx & 31;
        memT[((size_t)b*MD + d)*MEMS + m0 + m] = __float2bfloat16(Ms[m][d]);
    }
}

// ---------------- K1: MMU GEMM (MFMA, LDS-staged double-buffered) ----------------
// Block: 64 rows x 256 cols. Per k-step stage A[64][32] (4KB) + B[256][32] (16KB)
// via global_load_lds; (row>>1)&3 chunk swizzle both sides; 8 k-iters.
// B-tile over-reads rows 644..767 into allocated ws (garbage; writes guarded).
__global__ __launch_bounds__(256) void k_mmu(const __hip_bfloat16* __restrict__ Ab,
                                             const __hip_bfloat16* __restrict__ Wb,
                                             const float* __restrict__ bias,
                                             float* __restrict__ out,
                                             __hip_bfloat16* __restrict__ qbf)
{
    __shared__ __hip_bfloat16 At[2][64][32];
    __shared__ __hip_bfloat16 Bt[2][256][32];
    const int t = threadIdx.x, w = t >> 6, l = t & 63;
    const int lg = l >> 4, ll = l & 15;
    const int m0 = blockIdx.x*64;
    const int n0 = blockIdx.y*256;
    f32x4 acc[16];
    #pragma unroll
    for (int c = 0; c < 16; c++) acc[c] = (f32x4){0,0,0,0};

    // staging sources, +64B per iteration
    const char* aSrc;
    {
        int row = t >> 2, cc = t & 3;
        int gc = cc ^ ((row >> 1) & 3);
        aSrc = (const char*)((const short*)Ab + (size_t)(m0+row)*RS) + gc*16;
    }
    const char* bSrc[4];
    #pragma unroll
    for (int j = 0; j < 4; j++) {
        int ci = j*256 + t;
        int row = ci >> 2, cc = ci & 3;
        int gc = cc ^ ((row >> 1) & 3);
        bSrc[j] = (const char*)((const short*)Wb + (size_t)(n0+row)*RS) + gc*16;
    }

    auto stage = [&](int buf, int it) {
        int off = it*64;
        gload16(aSrc + off, (char*)(&At[buf][0][0]) + (size_t)t*0 /*wave-uniform base*/ + (size_t)( (t>>6) << 6 )*16);
        #pragma unroll
        for (int j = 0; j < 4; j++)
            gload16(bSrc[j] + off, (char*)(&Bt[buf][0][0]) + (size_t)((j*256) & ~63)*16 + (size_t)((t >> 6) << 6)*16);
    };
    // NOTE: LDS dest must be wave-uniform base + lane*16. Express explicitly:
    auto stage2 = [&](int buf, int it) {
        int off = it*64;
        char* abase = (char*)(&At[buf][0][0]) + (size_t)(w << 6)*16;           // wave w: chunks w*64..
        gload16(aSrc + off, abase);
        #pragma unroll
        for (int j = 0; j < 4; j++) {
            char* bbase = (char*)(&Bt[buf][0][0]) + (size_t)(j*256 + (w << 6))*16;
            gload16(bSrc[j] + off, bbase);
        }
    };

    stage2(0, 0);
    asm volatile("s_waitcnt vmcnt(0)" ::: "memory");
    __syncthreads();
    int cur = 0;
    const int arow = (w << 4) + ll;
    const int aswz = ((lg ^ ((arow >> 1) & 3)) << 4);
    for (int it = 0; it < 8; ++it) {
        if (it + 1 < 8) stage2(cur ^ 1, it + 1);
        const char* ab = (const char*)(&At[cur][0][0]);
        const char* bb = (const char*)(&Bt[cur][0][0]);
        bf16x8 af = *(const bf16x8*)(ab + arow*64 + aswz);
        #pragma unroll
        for (int c = 0; c < 16; c++) {
            int r0 = c*16 + ll;
            int sw = ((lg ^ ((r0 >> 1) & 3)) << 4);
            bf16x8 bf = *(const bf16x8*)(bb + (size_t)r0*64 + sw);
            acc[c] = __builtin_amdgcn_mfma_f32_16x16x32_bf16(af, bf, acc[c], 0, 0, 0);
        }
        asm volatile("s_waitcnt vmcnt(0)" ::: "memory");
        __syncthreads();
        cur ^= 1;
    }
    const int wm0 = m0 + (w << 4);
    #pragma unroll
    for (int c = 0; c < 16; c++) {
        int o = n0 + c*16 + ll;
        if (o >= MMUO) continue;
        float bv = bias[o];
        #pragma unroll
        for (int r = 0; r < 4; r++) {
            int row = wm0 + lg*4 + r;
            float v = acc[c][r] + bv;
            if      (o < MD)        qbf[(size_t)row*MD + o] = __float2bfloat16(v * 0.08838834764831845f);
            else if (o < 2*MD)      out[O_WKEY + (size_t)row*MD + (o -   MD)] = v;
            else if (o < 3*MD)      out[O_WVAL + (size_t)row*MD + (o - 2*MD)] = v;
            else if (o == 3*MD)     out[O_WGATE + row] = sigf(v);
            else if (o < 4*MD + 1)  out[O_SSDK + (size_t)row*MD + (o - (3*MD+1))] = v;
            else if (o < 5*MD + 1)  out[O_SSDV + (size_t)row*MD + (o - (4*MD+1))] = v;
            else                    out[O_SSDG + (size_t)row*3  + (o - (5*MD+1))] = v;
        }
    }
}

// ---------------- K1b: softmax over the 3 ssd_gate logits ----------------
__global__ void k_softmax3(float* __restrict__ out)
{
    int r = blockIdx.x*256 + threadIdx.x;
    if (r >= NROWS) return;
    float* p = out + O_SSDG + (size_t)r*3;
    float a = p[0], b = p[1], c = p[2];
    float m = fmaxf(a, fmaxf(b, c));
    float ea = __expf(a-m), eb = __expf(b-m), ec = __expf(c-m);
    float inv = 1.f/(ea+eb+ec);
    p[0] = ea*inv; p[1] = eb*inv; p[2] = ec*inv;
}

// ---------------- K2: LDS-staged 4-way split-K flash attention, 16 q-rows/wave ----------------
__global__ __launch_bounds__(256, 3) void k_attn(const __hip_bfloat16* __restrict__ qb,
                                                 const __hip_bfloat16* __restrict__ memB,
                                                 const __hip_bfloat16* __restrict__ memT,
                                                 float* __restrict__ Opart,
                                                 float* __restrict__ MLpart)
{
    __shared__ __hip_bfloat16 Kt[2][32][128];
    __shared__ __hip_bfloat16 Vt[2][128][32];
    __shared__ __hip_bfloat16 Pl[4][16][40];
    const int t = threadIdx.x, w = t >> 6, l = t & 63;
    const int lg = l >> 4, ll = l & 15;
    const int bid = blockIdx.x;
    const int xcd = bid & 7, rest = bid >> 3;      // rest 0..127
    const int b = xcd + ((rest >> 6) << 3);        // 2 batches per XCD
    const int sub = rest & 63;
    const int qblk = sub >> 2, kh = sub & 3;       // 16 q-blocks x 4 key-quarters
    const int qrow0 = (b << 10) + (qblk << 6) + (w << 4);   // wave's 16 q-rows
    const int k_beg = kh << 10;                             // 1024 keys per quarter
    const float THR = 4.0f;

    const short* Q = (const short*)qb;
    bf16x8 qf[4];
    #pragma unroll
    for (int ks = 0; ks < 4; ks++)
        qf[ks] = *(const bf16x8*)(Q + (size_t)(qrow0 + ll)*MD + ks*32 + lg*8);

    f32x4 O[8];
    #pragma unroll
    for (int dt = 0; dt < 8; dt++) O[dt] = (f32x4){0.f,0.f,0.f,0.f};
    float m_run[4], lsum[4];
    #pragma unroll
    for (int r = 0; r < 4; r++) { m_run[r] = -INFINITY; lsum[r] = 0.f; }

    const char* MbB = (const char*)memB + (size_t)b*MEMS*MD*2;
    const char* MtB = (const char*)memT + (size_t)b*MD*MEMS*2;

    auto stage = [&](int buf, int it) {
        const int k0 = k_beg + it*32;
        char* kbase = (char*)(&Kt[buf][0][0]);
        char* vbase = (char*)(&Vt[buf][0][0]);
        #pragma unroll
        for (int j = 0; j < 2; j++) {
            int ci = (w << 7) + (j << 6) + l;        // chunk 0..511 (16B each)
            int krow = ci >> 4, cc = ci & 15;
            int gc = cc ^ (krow & 7);                // pre-swizzled global source
            gload16(MbB + (size_t)(k0 + krow)*256 + gc*16,
                    kbase + (size_t)((w << 7) + (j << 6))*16);
        }
        #pragma unroll
        for (int j = 0; j < 2; j++) {
            int ci = (w << 7) + (j << 6) + l;
            int drow = ci >> 2, cc = ci & 3;
            int gc = cc ^ ((drow >> 1) & 3);         // V swizzle (both-sides involution)
            gload16(MtB + (size_t)drow*(MEMS*2) + (size_t)k0*2 + gc*16,
                    vbase + (size_t)((w << 7) + (j << 6))*16);
        }
    };

    stage(0, 0);
    asm volatile("s_waitcnt vmcnt(0)" ::: "memory");
    asm volatile("s_barrier" ::: "memory");
    int cur = 0;
    const int NIT = 1024/32;   // 32
    const int vsw = ((lg ^ ((ll >> 1) & 3)) << 4);
    for (int it = 0; it < NIT; ++it) {
        if (it + 1 < NIT) {
            stage(cur ^ 1, it + 1);
            asm volatile("s_waitcnt vmcnt(4)" ::: "memory");   // own stage(cur) done; next in flight
        } else {
            asm volatile("s_waitcnt vmcnt(0)" ::: "memory");
        }
        asm volatile("s_barrier" ::: "memory");                // everyone's stage(cur) done
        const char* kbase = (const char*)(&Kt[cur][0][0]);
        const char* vbase = (const char*)(&Vt[cur][0][0]);
        f32x4 s0 = (f32x4){0,0,0,0}, s1 = (f32x4){0,0,0,0};
        #pragma unroll
        for (int ks = 0; ks < 4; ks++) {
            int c0 = ks*4 + lg;
            int sw = (c0 ^ (ll & 7)) << 4;
            bf16x8 kf0 = *(const bf16x8*)(kbase + (size_t)ll*256 + sw);
            bf16x8 kf1 = *(const bf16x8*)(kbase + (size_t)(16 + ll)*256 + sw);
            s0 = __builtin_amdgcn_mfma_f32_16x16x32_bf16(qf[ks], kf0, s0, 0, 0, 0);
            s1 = __builtin_amdgcn_mfma_f32_16x16x32_bf16(qf[ks], kf1, s1, 0, 0, 0);
        }
        bool need = false;
        #pragma unroll
        for (int r = 0; r < 4; r++) {
            need |= (s0[r] > m_run[r] + THR);
            need |= (s1[r] > m_run[r] + THR);
        }
        if (__any(need)) {
            #pragma unroll
            for (int r = 0; r < 4; r++) {
                float v = fmaxf(s0[r], s1[r]);
                v = fmaxf(v, __shfl_xor(v, 1));
                v = fmaxf(v, __shfl_xor(v, 2));
                v = fmaxf(v, __shfl_xor(v, 4));
                v = fmaxf(v, __shfl_xor(v, 8));
                float mnew = fmaxf(m_run[r], v);
                float alpha = __expf(m_run[r] - mnew);
                m_run[r] = mnew;
                lsum[r] *= alpha;
                #pragma unroll
                for (int dt = 0; dt < 8; dt++) O[dt][r] *= alpha;
            }
        }
        #pragma unroll
        for (int r = 0; r < 4; r++) {
            float p0 = __expf(s0[r] - m_run[r]);
            float p1 = __expf(s1[r] - m_run[r]);
            Pl[w][lg*4 + r][ll]      = __float2bfloat16(p0);
            Pl[w][lg*4 + r][16 + ll] = __float2bfloat16(p1);
            lsum[r] += p0 + p1;
        }
        __builtin_amdgcn_wave_barrier();
        bf16x8 pa = *(const bf16x8*)(&Pl[w][ll][lg*8]);
        __builtin_amdgcn_wave_barrier();
        #pragma unroll
        for (int dt = 0; dt < 8; dt++) {
            bf16x8 vf = *(const bf16x8*)(vbase + (size_t)(dt*16 + ll)*64 + vsw);
            O[dt] = __builtin_amdgcn_mfma_f32_16x16x32_bf16(pa, vf, O[dt], 0, 0, 0);
        }
        asm volatile("s_barrier" ::: "memory");                // all reads of buf cur done
        cur ^= 1;
    }
    #pragma unroll
    for (int r = 0; r < 4; r++) {
        float s = lsum[r];
        s += __shfl_xor(s, 1);
        s += __shfl_xor(s, 2);
        s += __shfl_xor(s, 4);
        s += __shfl_xor(s, 8);
        lsum[r] = s;
    }
    #pragma unroll
    for (int dt = 0; dt < 8; dt++)
        #pragma unroll
        for (int r = 0; r < 4; r++) {
            int row = qrow0 + lg*4 + r;
            Opart[((size_t)row*4 + kh)*128 + dt*16 + ll] = O[dt][r];
        }
    if (ll == 0) {
        #pragma unroll
        for (int r = 0; r < 4; r++) {
            int row = qrow0 + lg*4 + r;
            MLpart[((size_t)row*4 + kh)*2 + 0] = m_run[r];
            MLpart[((size_t)row*4 + kh)*2 + 1] = lsum[r];
        }
    }
}

// ---------------- K2b: combine the 4 split-K partials -> rd bf16 ----------------
__global__ __launch_bounds__(256) void k_comb(const float* __restrict__ Opart,
                                              const float* __restrict__ MLpart,
                                              __hip_bfloat16* __restrict__ rdb)
{
    const int t = threadIdx.x;
    const int row = blockIdx.x*64 + (t >> 2);
    const int c0 = (t & 3) * 32;
    float m[4], lv[4], a[4];
    float M = -INFINITY;
    #pragma unroll
    for (int i = 0; i < 4; i++) {
        m[i]  = MLpart[((size_t)row*4 + i)*2 + 0];
        lv[i] = MLpart[((size_t)row*4 + i)*2 + 1];
        M = fmaxf(M, m[i]);
    }
    float L = 0.f;
    #pragma unroll
    for (int i = 0; i < 4; i++) { a[i] = __expf(m[i] - M); L += a[i]*lv[i]; }
    float invL = 1.f / L;
    #pragma unroll
    for (int i = 0; i < 4; i++) a[i] *= invL;
    unsigned short* dst = (unsigned short*)rdb + (size_t)row*128 + c0;
    #pragma unroll
    for (int j = 0; j < 8; j++) {
        float4 acc = {0.f,0.f,0.f,0.f};
        #pragma unroll
        for (int i = 0; i < 4; i++) {
            float4 x = ((const float4*)(Opart + ((size_t)row*4 + i)*128 + c0))[j];
            acc.x += a[i]*x.x; acc.y += a[i]*x.y; acc.z += a[i]*x.z; acc.w += a[i]*x.w;
        }
        u16x4 o = { bfu(acc.x), bfu(acc.y), bfu(acc.z), bfu(acc.w) };
        ((u16x4*)dst)[j] = o;
    }
}

// ---------------- K3: fused GRU (MFMA, LDS-staged, gi0-precomputed) ----------------
__global__ __launch_bounds__(256) void k_gru(const float* __restrict__ gi0,
                                             const __hip_bfloat16* __restrict__ rdb,
                                             const __hip_bfloat16* __restrict__ regsb,
                                             const float* __restrict__ regs,
                                             const __hip_bfloat16* __restrict__ Wihb,
                                             const float* __restrict__ bih,
                                             const __hip_bfloat16* __restrict__ Whhb,
                                             const float* __restrict__ bhh,
                                             float* __restrict__ newregs,
                                             __hip_bfloat16* __restrict__ nregsb)
{
    __shared__ __hip_bfloat16 At[2][64][32];
    __shared__ __hip_bfloat16 Bt[2][192][32];
    const int t = threadIdx.x, w = t >> 6, l = t & 63;
    const int lg = l >> 4, ll = l & 15;
    const int m0 = blockIdx.x*64;
    const int n0 = blockIdx.y*64;
    const int batch = blockIdx.x >> 4;
    const short* Rd = (const short*)rdb;
    const short* Hb = (const short*)regsb;
    const short* Wi = (const short*)Wihb;
    const short* Wh = (const short*)Whhb;

    f32x4 aR[4], aZ[4], aNi[4], aNh[4];
    #pragma unroll
    for (int c = 0; c < 4; c++) {
        int o = n0 + c*16 + ll;
        float gR = gi0[(size_t)batch*768 + o];
        float gZ = gi0[(size_t)batch*768 + 256 + o];
        float gN = gi0[(size_t)batch*768 + 512 + o];
        aR[c]  = (f32x4){gR,gR,gR,gR};
        aZ[c]  = (f32x4){gZ,gZ,gZ,gZ};
        aNi[c] = (f32x4){gN,gN,gN,gN};
        aNh[c] = (f32x4){0,0,0,0};
    }

    const int aci = (w << 6) + l;
    const int arow_s = aci >> 2, acc_s = aci & 3;
    const int agc = acc_s ^ ((arow_s >> 1) & 3);
    const char* aSrcA = (const char*)(Rd + (size_t)(m0+arow_s)*MD) + agc*16;
    const char* aSrcB = (const char*)(Hb + (size_t)(m0+arow_s)*RS) + agc*16;
    const char* bSrcA0; const char* bSrcA1; const char* bSrcA2;
    const char* bSrcB0; const char* bSrcB1; const char* bSrcB2;
    {
        int ci, row, cc, gc, g, col;
        ci = w*192 + 0*64 + l; row = ci >> 2; cc = ci & 3; gc = cc ^ ((row >> 1) & 3);
        g = row >> 6; col = row & 63;
        bSrcA0 = (const char*)(Wi + (size_t)(g*RS + n0 + col)*GRUIN + INS) + gc*16;
        bSrcB0 = (const char*)(Wh + (size_t)(g*RS + n0 + col)*RS) + gc*16;
        ci = w*192 + 1*64 + l; row = ci >> 2; cc = ci & 3; gc = cc ^ ((row >> 1) & 3);
        g = row >> 6; col = row & 63;
        bSrcA1 = (const char*)(Wi + (size_t)(g*RS + n0 + col)*GRUIN + INS) + gc*16;
        bSrcB1 = (const char*)(Wh + (size_t)(g*RS + n0 + col)*RS) + gc*16;
        ci = w*192 + 2*64 + l; row = ci >> 2; cc = ci & 3; gc = cc ^ ((row >> 1) & 3);
        g = row >> 6; col = row & 63;
        bSrcA2 = (const char*)(Wi + (size_t)(g*RS + n0 + col)*GRUIN + INS) + gc*16;
        bSrcB2 = (const char*)(Wh + (size_t)(g*RS + n0 + col)*RS) + gc*16;
    }

    const int NITA = 4, NIT = 12;
    auto stage = [&](int buf, int it) {
        char* abase = (char*)(&At[buf][0][0]) + (size_t)(w << 6)*16;
        char* bbase = (char*)(&Bt[buf][0][0]) + (size_t)(w*192)*16;
        const char *as, *b0, *b1, *b2;
        if (it < NITA) {
            int off = it*64;
            as = aSrcA + off; b0 = bSrcA0 + off; b1 = bSrcA1 + off; b2 = bSrcA2 + off;
        } else {
            int off = (it - NITA)*64;
            as = aSrcB + off; b0 = bSrcB0 + off; b1 = bSrcB1 + off; b2 = bSrcB2 + off;
        }
        gload16(as, abase);
        gload16(b0, bbase);
        gload16(b1, bbase + 64*16);
        gload16(b2, bbase + 128*16);
    };

    stage(0, 0);
    asm volatile("s_waitcnt vmcnt(0)" ::: "memory");
    __syncthreads();
    int cur = 0;
    const int arow = (w << 4) + ll;
    const int aswz = ((lg ^ ((arow >> 1) & 3)) << 4);
    for (int it = 0; it < NIT; ++it) {
        if (it + 1 < NIT) stage(cur ^ 1, it + 1);
        const char* ab = (const char*)(&At[cur][0][0]);
        const char* bb = (const char*)(&Bt[cur][0][0]);
        bf16x8 af = *(const bf16x8*)(ab + arow*64 + aswz);
        if (it < NITA) {
            #pragma unroll
            for (int c = 0; c < 4; c++) {
                int r0 = c*16 + ll;
                int sw = ((lg ^ ((r0 >> 1) & 3)) << 4);
                bf16x8 bR = *(const bf16x8*)(bb + (size_t)r0*64 + sw);
                bf16x8 bZ = *(const bf16x8*)(bb + (size_t)(r0 + 64)*64 + sw);
                bf16x8 bN = *(const bf16x8*)(bb + (size_t)(r0 + 128)*64 + sw);
                aR[c]  = __builtin_amdgcn_mfma_f32_16x16x32_bf16(af, bR, aR[c],  0, 0, 0);
                aZ[c]  = __builtin_amdgcn_mfma_f32_16x16x32_bf16(af, bZ, aZ[c],  0, 0, 0);
                aNi[c] = __builtin_amdgcn_mfma_f32_16x16x32_bf16(af, bN, aNi[c], 0, 0, 0);
            }
        } else {
            #pragma unroll
            for (int c = 0; c < 4; c++) {
                int r0 = c*16 + ll;
                int sw = ((lg ^ ((r0 >> 1) & 3)) << 4);
                bf16x8 bR = *(const bf16x8*)(bb + (size_t)r0*64 + sw);
                bf16x8 bZ = *(const bf16x8*)(bb + (size_t)(r0 + 64)*64 + sw);
                bf16x8 bN = *(const bf16x8*)(bb + (size_t)(r0 + 128)*64 + sw);
                aR[c]  = __builtin_amdgcn_mfma_f32_16x16x32_bf16(af, bR, aR[c],  0, 0, 0);
                aZ[c]  = __builtin_amdgcn_mfma_f32_16x16x32_bf16(af, bZ, aZ[c],  0, 0, 0);
                aNh[c] = __builtin_amdgcn_mfma_f32_16x16x32_bf16(af, bN, aNh[c], 0, 0, 0);
            }
        }
        asm volatile("s_waitcnt vmcnt(0)" ::: "memory");
        __syncthreads();
        cur ^= 1;
    }
    const int wm0 = m0 + (w << 4);
    #pragma unroll
    for (int c = 0; c < 4; c++) {
        int o = n0 + c*16 + ll;
        float bR = bih[o]        + bhh[o];
        float bZ = bih[o +   RS] + bhh[o +   RS];
        float bNi = bih[o + 2*RS];
        float bNh = bhh[o + 2*RS];
        #pragma unroll
        for (int r = 0; r < 4; r++) {
            int row = wm0 + lg*4 + r;
            float rr = sigf(aR[c][r] + bR);
            float zz = sigf(aZ[c][r] + bZ);
            float nn = tanhf(aNi[c][r] + bNi + rr*(aNh[c][r] + bNh));
            float cv = regs[(size_t)row*RS + o];
            float nv = (1.f - zz)*nn + zz*cv;
            newregs[(size_t)row*RS + o] = nv;
            nregsb[(size_t)row*RS + o] = __float2bfloat16(nv);
        }
    }
}

// ---------------- K4: output GEMM (MFMA, LDS-staged double-buffered) ----------------
// Block: 64 rows x 256 cols; A[64][32] + B[256][32] staged; 8 k-iters.
__global__ __launch_bounds__(256) void k_out(const __hip_bfloat16* __restrict__ Ab,
                                             const __hip_bfloat16* __restrict__ Wb,
                                             const float* __restrict__ bias,
                                             float* __restrict__ out0)
{
    __shared__ __hip_bfloat16 At[2][64][32];
    __shared__ __hip_bfloat16 Bt[2][256][32];
    const int t = threadIdx.x, w = t >> 6, l = t & 63;
    const int lg = l >> 4, ll = l & 15;
    const int m0 = blockIdx.x*64;
    const int n0 = blockIdx.y*256;
    f32x4 acc[16];
    #pragma unroll
    for (int c = 0; c < 16; c++) acc[c] = (f32x4){0,0,0,0};

    const char* aSrc;
    {
        int row = t >> 2, cc = t & 3;
        int gc = cc ^ ((row >> 1) & 3);
        aSrc = (const char*)((const short*)Ab + (size_t)(m0+row)*RS) + gc*16;
    }
    const char* bSrc[4];
    #pragma unroll
    for (int j = 0; j < 4; j++) {
        int ci = j*256 + t;
        int row = ci >> 2, cc = ci & 3;
        int gc = cc ^ ((row >> 1) & 3);
        bSrc[j] = (const char*)((const short*)Wb + (size_t)(n0+row)*RS) + gc*16;
    }

    auto stage = [&](int buf, int it) {
        int off = it*64;
        char* abase = (char*)(&At[buf][0][0]) + (size_t)(w << 6)*16;
        gload16(aSrc + off, abase);
        #pragma unroll
        for (int j = 0; j < 4; j++) {
            char* bbase = (char*)(&Bt[buf][0][0]) + (size_t)(j*256 + (w << 6))*16;
            gload16(bSrc[j] + off, bbase);
        }
    };

    stage(0, 0);
    asm volatile("s_waitcnt vmcnt(0)" ::: "memory");
    __syncthreads();
    int cur = 0;
    const int arow = (w << 4) + ll;
    const int aswz = ((lg ^ ((arow >> 1) & 3)) << 4);
    for (int it = 0; it < 8; ++it) {
        if (it + 1 < 8) stage(cur ^ 1, it + 1);
        const char* ab = (const char*)(&At[cur][0][0]);
        const char* bb = (const char*)(&Bt[cur][0][0]);
        bf16x8 af = *(const bf16x8*)(ab + arow*64 + aswz);
        #pragma unroll
        for (int c = 0; c < 16; c++) {
            int r0 = c*16 + ll;
            int sw = ((lg ^ ((r0 >> 1) & 3)) << 4);
            bf16x8 bf = *(const bf16x8*)(bb + (size_t)r0*64 + sw);
            acc[c] = __builtin_amdgcn_mfma_f32_16x16x32_bf16(af, bf, acc[c], 0, 0, 0);
        }
        asm volatile("s_waitcnt vmcnt(0)" ::: "memory");
        __syncthreads();
        cur ^= 1;
    }
    const int wm0 = m0 + (w << 4);
    #pragma unroll
    for (int c = 0; c < 16; c++) {
        int o = n0 + c*16 + ll;
        float bv = bias[o];
        #pragma unroll
        for (int r = 0; r < 4; r++) {
            int row = wm0 + lg*4 + r;
            out0[(size_t)row*INS + o] = acc[c][r] + bv;
        }
    }
}

extern "C" void kernel_launch(void* const* d_in, const int* in_sizes, int n_in,
                              void* d_out, int out_size, void* d_ws, size_t ws_size,
                              hipStream_t stream)
{
    const float* inp  = (const float*)d_in[0];
    const float* regs = (const float*)d_in[1];
    const float* mem  = (const float*)d_in[2];
    const float* Wih  = (const float*)d_in[3];
    const float* bih  = (const float*)d_in[4];
    const float* Whh  = (const float*)d_in[5];
    const float* bhh  = (const float*)d_in[6];
    const float* Wmmu = (const float*)d_in[7];
    const float* bmmu = (const float*)d_in[8];
    const float* Wout = (const float*)d_in[9];
    const float* bout = (const float*)d_in[10];
    float* out = (float*)d_out;

    char* ws = (char*)d_ws;
    __hip_bfloat16* qbf    = (__hip_bfloat16*)(ws);
    __hip_bfloat16* rdb    = (__hip_bfloat16*)(ws + ((size_t)4<<20));
    __hip_bfloat16* memB   = (__hip_bfloat16*)(ws + ((size_t)8<<20));
    __hip_bfloat16* memT   = (__hip_bfloat16*)(ws + ((size_t)24<<20));
    __hip_bfloat16* regsb  = (__hip_bfloat16*)(ws + ((size_t)40<<20));
    __hip_bfloat16* nregsb = (__hip_bfloat16*)(ws + ((size_t)48<<20));
    __hip_bfloat16* Wmmub  = (__hip_bfloat16*)(ws + ((size_t)56<<20));
    __hip_bfloat16* Wihb   = (__hip_bfloat16*)(ws + ((size_t)56<<20) + ( 1<<20));
    __hip_bfloat16* Whhb   = (__hip_bfloat16*)(ws + ((size_t)56<<20) + ( 2<<20));
    __hip_bfloat16* Woutb  = (__hip_bfloat16*)(ws + ((size_t)56<<20) + ( 3<<20));
    __hip_bfloat16* inpb   = (__hip_bfloat16*)(ws + ((size_t)56<<20) + ( 4<<20));
    float*          MLpart = (float*)(ws + ((size_t)61<<20));            // 512 KB
    float*          gi0    = (float*)(ws + ((size_t)61<<20) + (1<<19));  // 49 KB
    float*          Opart  = out + O_OUT;   // 33.5 MB, exactly the out0 region

    dim3 ggi(B_, 3);
    k_gi<<<ggi, 256, 0, stream>>>(inp, Wih, gi0);
    k_cvt5<<<969, 256, 0, stream>>>(Wmmu, (unsigned short*)Wmmub,
                                    Wih,  (unsigned short*)Wihb,
                                    Whh,  (unsigned short*)Whhb,
                                    Wout, (unsigned short*)Woutb,
                                    inp,  (unsigned short*)inpb);
    k_cvt<<<(4194304/4 + 255)/256, 256, 0, stream>>>(regs, (unsigned short*)regsb, 4194304/4);
    k_conv<<<B_*128, 256, 0, stream>>>(mem, memB, memT);

    dim3 g1(NROWS/64, 3);
    k_mmu<<<g1, 256, 0, stream>>>(regsb, Wmmub, bmmu, out, qbf);
    k_softmax3<<<NROWS/256, 256, 0, stream>>>(out);
    k_attn<<<1024, 256, 0, stream>>>(qbf, memB, memT, Opart, MLpart);
    k_comb<<<NROWS/64, 256, 0, stream>>>(Opart, MLpart, rdb);
    dim3 g3(NROWS/64, 4);
    k_gru<<<g3, 256, 0, stream>>>(gi0, rdb, regsb, regs, Wihb, bih, Whhb, bhh,
                                  out + O_REGS, nregsb);
    dim3 g4(NROWS/64, 2);
    k_out<<<g4, 256, 0, stream>>>(nregsb, Woutb, bout, out);
}

// Round 13
// 172.892 us; speedup vs baseline: 3.1331x; 1.0702x over previous
//
#include <hip/hip_runtime.h>
#include <hip/hip_bf16.h>
#include <math.h>

#define B_      16
#define NPUS    1024
#define MEMS    4096
#define INS     512
#define RS      256
#define MD      128
#define GRUIN   640
#define MMUO    644
#define NROWS   (B_*NPUS)   // 16384

// d_out flat offsets (reference return order)
#define O_OUT   0u
#define O_REGS  8388608u
#define O_WKEY  12582912u
#define O_WVAL  14680064u
#define O_WGATE 16777216u
#define O_SSDK  16793600u
#define O_SSDV  18890752u
#define O_SSDG  20987904u

typedef __attribute__((ext_vector_type(8))) short bf16x8;
typedef __attribute__((ext_vector_type(4))) float f32x4;
typedef __attribute__((ext_vector_type(4))) unsigned short u16x4;

__device__ __forceinline__ float sigf(float x){ return 1.f/(1.f+__expf(-x)); }
__device__ __forceinline__ unsigned short bfu(float x){
    __hip_bfloat16 h = __float2bfloat16(x);
    return __builtin_bit_cast(unsigned short, h);
}
__device__ __forceinline__ float b2f(unsigned short u){
    unsigned v = ((unsigned)u) << 16;
    return __builtin_bit_cast(float, v);
}
// async global->LDS, 16B per lane; LDS dest is wave-uniform base + lane*16 (m104)
__device__ __forceinline__ void gload16(const void* g, void* s)
{
    __builtin_amdgcn_global_load_lds(
        (const __attribute__((address_space(1))) void*)g,
        (__attribute__((address_space(3))) void*)s, 16, 0, 0);
}

// ---------------- K_cvt: fp32 -> bf16, vectorized x4 ----------------
__global__ __launch_bounds__(256) void k_cvt(const float* __restrict__ src,
                                             unsigned short* __restrict__ dst, int n4)
{
    int i = blockIdx.x*256 + threadIdx.x;
    if (i >= n4) return;
    float4 v = ((const float4*)src)[i];
    u16x4 o = { bfu(v.x), bfu(v.y), bfu(v.z), bfu(v.w) };
    ((u16x4*)dst)[i] = o;
}

// ---------------- K_cvt5: fused 5-tensor fp32->bf16 (block-aligned segments) ----------------
__global__ __launch_bounds__(256) void k_cvt5(const float* __restrict__ s0, unsigned short* __restrict__ d0,
                                              const float* __restrict__ s1, unsigned short* __restrict__ d1,
                                              const float* __restrict__ s2, unsigned short* __restrict__ d2,
                                              const float* __restrict__ s3, unsigned short* __restrict__ d3,
                                              const float* __restrict__ s4, unsigned short* __restrict__ d4)
{
    int gi = blockIdx.x*256 + threadIdx.x;
    const float* s; unsigned short* d; int idx;
    if      (gi < 41216)  { s = s0; d = d0; idx = gi; }
    else if (gi < 164096) { s = s1; d = d1; idx = gi - 41216; }
    else if (gi < 213248) { s = s2; d = d2; idx = gi - 164096; }
    else if (gi < 246016) { s = s3; d = d3; idx = gi - 213248; }
    else                  { s = s4; d = d4; idx = gi - 246016; }
    float4 v = ((const float4*)s)[idx];
    u16x4 o = { bfu(v.x), bfu(v.y), bfu(v.z), bfu(v.w) };
    ((u16x4*)d)[idx] = o;
}

// ---------------- K_gi: gi0[16][768] = inp . Wih[:, :512]^T (fp32, once per batch) ----------------
__global__ __launch_bounds__(256) void k_gi(const float* __restrict__ inp,
                                            const float* __restrict__ Wih,
                                            float* __restrict__ gi0)
{
    __shared__ float xs[INS];
    const int b = blockIdx.x, seg = blockIdx.y;
    const int t = threadIdx.x;
    for (int i = t; i < INS; i += 256) xs[i] = inp[(size_t)b*INS + i];
    __syncthreads();
    const int o = seg*256 + t;                      // 0..767
    const float* wrow = Wih + (size_t)o*GRUIN;
    float a0 = 0.f, a1 = 0.f, a2 = 0.f, a3 = 0.f;
    for (int k = 0; k < INS; k += 4) {
        float4 wv = *(const float4*)(wrow + k);
        a0 += xs[k]*wv.x; a1 += xs[k+1]*wv.y; a2 += xs[k+2]*wv.z; a3 += xs[k+3]*wv.w;
    }
    gi0[(size_t)b*768 + o] = (a0 + a1) + (a2 + a3);
}

// ---------------- K0: memory_context -> bf16 row-major + transposed ----------------
__global__ __launch_bounds__(256) void k_conv(const float* __restrict__ mem,
                                              __hip_bfloat16* __restrict__ memB,
                                              __hip_bfloat16* __restrict__ memT)
{
    __shared__ float Ms[32][129];
    const int t = threadIdx.x;
    const int b = blockIdx.x >> 7;
    const int m0 = (blockIdx.x & 127) << 5;
    const float* src = mem + ((size_t)b*MEMS + m0)*MD;
    for (int idx = t; idx < 32*128; idx += 256) {
        int m = idx >> 7, d = idx & 127;
        float v = src[(size_t)m*MD + d];
        Ms[m][d] = v;
        memB[((size_t)b*MEMS + m0 + m)*MD + d] = __float2bfloat16(v);
    }
    __syncthreads();
    for (int idx = t; idx < 128*32; idx += 256) {
        int d = idx >> 5, m = idx & 31;
        memT[((size_t)b*MD + d)*MEMS + m0 + m] = __float2bfloat16(Ms[m][d]);
    }
}

// ---------------- K1: MMU GEMM (MFMA, LDS-staged double-buffered) ----------------
__global__ __launch_bounds__(256) void k_mmu(const __hip_bfloat16* __restrict__ Ab,
                                             const __hip_bfloat16* __restrict__ Wb,
                                             const float* __restrict__ bias,
                                             float* __restrict__ out,
                                             __hip_bfloat16* __restrict__ qbf)
{
    __shared__ __hip_bfloat16 At[2][64][32];
    __shared__ __hip_bfloat16 Bt[2][256][32];
    const int t = threadIdx.x, w = t >> 6, l = t & 63;
    const int lg = l >> 4, ll = l & 15;
    const int m0 = blockIdx.x*64;
    const int n0 = blockIdx.y*256;
    f32x4 acc[16];
    #pragma unroll
    for (int c = 0; c < 16; c++) acc[c] = (f32x4){0,0,0,0};

    const char* aSrc;
    {
        int row = t >> 2, cc = t & 3;
        int gc = cc ^ ((row >> 1) & 3);
        aSrc = (const char*)((const short*)Ab + (size_t)(m0+row)*RS) + gc*16;
    }
    const char* bSrc[4];
    #pragma unroll
    for (int j = 0; j < 4; j++) {
        int ci = j*256 + t;
        int row = ci >> 2, cc = ci & 3;
        int gc = cc ^ ((row >> 1) & 3);
        bSrc[j] = (const char*)((const short*)Wb + (size_t)(n0+row)*RS) + gc*16;
    }

    auto stage2 = [&](int buf, int it) {
        int off = it*64;
        char* abase = (char*)(&At[buf][0][0]) + (size_t)(w << 6)*16;
        gload16(aSrc + off, abase);
        #pragma unroll
        for (int j = 0; j < 4; j++) {
            char* bbase = (char*)(&Bt[buf][0][0]) + (size_t)(j*256 + (w << 6))*16;
            gload16(bSrc[j] + off, bbase);
        }
    };

    stage2(0, 0);
    asm volatile("s_waitcnt vmcnt(0)" ::: "memory");
    __syncthreads();
    int cur = 0;
    const int arow = (w << 4) + ll;
    const int aswz = ((lg ^ ((arow >> 1) & 3)) << 4);
    for (int it = 0; it < 8; ++it) {
        if (it + 1 < 8) stage2(cur ^ 1, it + 1);
        const char* ab = (const char*)(&At[cur][0][0]);
        const char* bb = (const char*)(&Bt[cur][0][0]);
        bf16x8 af = *(const bf16x8*)(ab + arow*64 + aswz);
        #pragma unroll
        for (int c = 0; c < 16; c++) {
            int r0 = c*16 + ll;
            int sw = ((lg ^ ((r0 >> 1) & 3)) << 4);
            bf16x8 bf = *(const bf16x8*)(bb + (size_t)r0*64 + sw);
            acc[c] = __builtin_amdgcn_mfma_f32_16x16x32_bf16(af, bf, acc[c], 0, 0, 0);
        }
        asm volatile("s_waitcnt vmcnt(0)" ::: "memory");
        __syncthreads();
        cur ^= 1;
    }
    const int wm0 = m0 + (w << 4);
    #pragma unroll
    for (int c = 0; c < 16; c++) {
        int o = n0 + c*16 + ll;
        if (o >= MMUO) continue;
        float bv = bias[o];
        #pragma unroll
        for (int r = 0; r < 4; r++) {
            int row = wm0 + lg*4 + r;
            float v = acc[c][r] + bv;
            if      (o < MD)        qbf[(size_t)row*MD + o] = __float2bfloat16(v * 0.08838834764831845f);
            else if (o < 2*MD)      out[O_WKEY + (size_t)row*MD + (o -   MD)] = v;
            else if (o < 3*MD)      out[O_WVAL + (size_t)row*MD + (o - 2*MD)] = v;
            else if (o == 3*MD)     out[O_WGATE + row] = sigf(v);
            else if (o < 4*MD + 1)  out[O_SSDK + (size_t)row*MD + (o - (3*MD+1))] = v;
            else if (o < 5*MD + 1)  out[O_SSDV + (size_t)row*MD + (o - (4*MD+1))] = v;
            else                    out[O_SSDG + (size_t)row*3  + (o - (5*MD+1))] = v;
        }
    }
}

// ---------------- K1b: softmax over the 3 ssd_gate logits ----------------
__global__ void k_softmax3(float* __restrict__ out)
{
    int r = blockIdx.x*256 + threadIdx.x;
    if (r >= NROWS) return;
    float* p = out + O_SSDG + (size_t)r*3;
    float a = p[0], b = p[1], c = p[2];
    float m = fmaxf(a, fmaxf(b, c));
    float ea = __expf(a-m), eb = __expf(b-m), ec = __expf(c-m);
    float inv = 1.f/(ea+eb+ec);
    p[0] = ea*inv; p[1] = eb*inv; p[2] = ec*inv;
}

// ---------------- K2: LDS-staged 4-way split-K flash attention, 16 q-rows/wave ----------------
// launch_bounds(256,4): 4 blocks/CU (LDS 4x37.9KB=151.5KB fits). Opart in bf16.
__global__ __launch_bounds__(256, 4) void k_attn(const __hip_bfloat16* __restrict__ qb,
                                                 const __hip_bfloat16* __restrict__ memB,
                                                 const __hip_bfloat16* __restrict__ memT,
                                                 unsigned short* __restrict__ Opart,
                                                 float* __restrict__ MLpart)
{
    __shared__ __hip_bfloat16 Kt[2][32][128];
    __shared__ __hip_bfloat16 Vt[2][128][32];
    __shared__ __hip_bfloat16 Pl[4][16][40];
    const int t = threadIdx.x, w = t >> 6, l = t & 63;
    const int lg = l >> 4, ll = l & 15;
    const int bid = blockIdx.x;
    const int xcd = bid & 7, rest = bid >> 3;      // rest 0..127
    const int b = xcd + ((rest >> 6) << 3);        // 2 batches per XCD
    const int sub = rest & 63;
    const int qblk = sub >> 2, kh = sub & 3;       // 16 q-blocks x 4 key-quarters
    const int qrow0 = (b << 10) + (qblk << 6) + (w << 4);   // wave's 16 q-rows
    const int k_beg = kh << 10;                             // 1024 keys per quarter
    const float THR = 4.0f;

    const short* Q = (const short*)qb;
    bf16x8 qf[4];
    #pragma unroll
    for (int ks = 0; ks < 4; ks++)
        qf[ks] = *(const bf16x8*)(Q + (size_t)(qrow0 + ll)*MD + ks*32 + lg*8);

    f32x4 O[8];
    #pragma unroll
    for (int dt = 0; dt < 8; dt++) O[dt] = (f32x4){0.f,0.f,0.f,0.f};
    float m_run[4], lsum[4];
    #pragma unroll
    for (int r = 0; r < 4; r++) { m_run[r] = -INFINITY; lsum[r] = 0.f; }

    const char* MbB = (const char*)memB + (size_t)b*MEMS*MD*2;
    const char* MtB = (const char*)memT + (size_t)b*MD*MEMS*2;

    auto stage = [&](int buf, int it) {
        const int k0 = k_beg + it*32;
        char* kbase = (char*)(&Kt[buf][0][0]);
        char* vbase = (char*)(&Vt[buf][0][0]);
        #pragma unroll
        for (int j = 0; j < 2; j++) {
            int ci = (w << 7) + (j << 6) + l;        // chunk 0..511 (16B each)
            int krow = ci >> 4, cc = ci & 15;
            int gc = cc ^ (krow & 7);                // pre-swizzled global source
            gload16(MbB + (size_t)(k0 + krow)*256 + gc*16,
                    kbase + (size_t)((w << 7) + (j << 6))*16);
        }
        #pragma unroll
        for (int j = 0; j < 2; j++) {
            int ci = (w << 7) + (j << 6) + l;
            int drow = ci >> 2, cc = ci & 3;
            int gc = cc ^ ((drow >> 1) & 3);         // V swizzle (both-sides involution)
            gload16(MtB + (size_t)drow*(MEMS*2) + (size_t)k0*2 + gc*16,
                    vbase + (size_t)((w << 7) + (j << 6))*16);
        }
    };

    stage(0, 0);
    asm volatile("s_waitcnt vmcnt(0)" ::: "memory");
    asm volatile("s_barrier" ::: "memory");
    int cur = 0;
    const int NIT = 1024/32;   // 32
    const int vsw = ((lg ^ ((ll >> 1) & 3)) << 4);
    for (int it = 0; it < NIT; ++it) {
        if (it + 1 < NIT) {
            stage(cur ^ 1, it + 1);
            asm volatile("s_waitcnt vmcnt(4)" ::: "memory");   // own stage(cur) done; next in flight
        } else {
            asm volatile("s_waitcnt vmcnt(0)" ::: "memory");
        }
        asm volatile("s_barrier" ::: "memory");                // everyone's stage(cur) done
        const char* kbase = (const char*)(&Kt[cur][0][0]);
        const char* vbase = (const char*)(&Vt[cur][0][0]);
        f32x4 s0 = (f32x4){0,0,0,0}, s1 = (f32x4){0,0,0,0};
        #pragma unroll
        for (int ks = 0; ks < 4; ks++) {
            int c0 = ks*4 + lg;
            int sw = (c0 ^ (ll & 7)) << 4;
            bf16x8 kf0 = *(const bf16x8*)(kbase + (size_t)ll*256 + sw);
            bf16x8 kf1 = *(const bf16x8*)(kbase + (size_t)(16 + ll)*256 + sw);
            s0 = __builtin_amdgcn_mfma_f32_16x16x32_bf16(qf[ks], kf0, s0, 0, 0, 0);
            s1 = __builtin_amdgcn_mfma_f32_16x16x32_bf16(qf[ks], kf1, s1, 0, 0, 0);
        }
        bool need = false;
        #pragma unroll
        for (int r = 0; r < 4; r++) {
            need |= (s0[r] > m_run[r] + THR);
            need |= (s1[r] > m_run[r] + THR);
        }
        if (__any(need)) {
            #pragma unroll
            for (int r = 0; r < 4; r++) {
                float v = fmaxf(s0[r], s1[r]);
                v = fmaxf(v, __shfl_xor(v, 1));
                v = fmaxf(v, __shfl_xor(v, 2));
                v = fmaxf(v, __shfl_xor(v, 4));
                v = fmaxf(v, __shfl_xor(v, 8));
                float mnew = fmaxf(m_run[r], v);
                float alpha = __expf(m_run[r] - mnew);
                m_run[r] = mnew;
                lsum[r] *= alpha;
                #pragma unroll
                for (int dt = 0; dt < 8; dt++) O[dt][r] *= alpha;
            }
        }
        #pragma unroll
        for (int r = 0; r < 4; r++) {
            float p0 = __expf(s0[r] - m_run[r]);
            float p1 = __expf(s1[r] - m_run[r]);
            Pl[w][lg*4 + r][ll]      = __float2bfloat16(p0);
            Pl[w][lg*4 + r][16 + ll] = __float2bfloat16(p1);
            lsum[r] += p0 + p1;
        }
        __builtin_amdgcn_wave_barrier();
        bf16x8 pa = *(const bf16x8*)(&Pl[w][ll][lg*8]);
        __builtin_amdgcn_wave_barrier();
        #pragma unroll
        for (int dt = 0; dt < 8; dt++) {
            bf16x8 vf = *(const bf16x8*)(vbase + (size_t)(dt*16 + ll)*64 + vsw);
            O[dt] = __builtin_amdgcn_mfma_f32_16x16x32_bf16(pa, vf, O[dt], 0, 0, 0);
        }
        asm volatile("s_barrier" ::: "memory");                // all reads of buf cur done
        cur ^= 1;
    }
    #pragma unroll
    for (int r = 0; r < 4; r++) {
        float s = lsum[r];
        s += __shfl_xor(s, 1);
        s += __shfl_xor(s, 2);
        s += __shfl_xor(s, 4);
        s += __shfl_xor(s, 8);
        lsum[r] = s;
    }
    #pragma unroll
    for (int dt = 0; dt < 8; dt++)
        #pragma unroll
        for (int r = 0; r < 4; r++) {
            int row = qrow0 + lg*4 + r;
            Opart[((size_t)row*4 + kh)*128 + dt*16 + ll] = bfu(O[dt][r]);
        }
    if (ll == 0) {
        #pragma unroll
        for (int r = 0; r < 4; r++) {
            int row = qrow0 + lg*4 + r;
            MLpart[((size_t)row*4 + kh)*2 + 0] = m_run[r];
            MLpart[((size_t)row*4 + kh)*2 + 1] = lsum[r];
        }
    }
}

// ---------------- K2b: combine the 4 split-K partials (bf16) -> rd bf16 ----------------
__global__ __launch_bounds__(256) void k_comb(const unsigned short* __restrict__ Opart,
                                              const float* __restrict__ MLpart,
                                              __hip_bfloat16* __restrict__ rdb)
{
    const int t = threadIdx.x;
    const int row = blockIdx.x*64 + (t >> 2);
    const int c0 = (t & 3) * 32;
    float m[4], lv[4], a[4];
    float M = -INFINITY;
    #pragma unroll
    for (int i = 0; i < 4; i++) {
        m[i]  = MLpart[((size_t)row*4 + i)*2 + 0];
        lv[i] = MLpart[((size_t)row*4 + i)*2 + 1];
        M = fmaxf(M, m[i]);
    }
    float L = 0.f;
    #pragma unroll
    for (int i = 0; i < 4; i++) { a[i] = __expf(m[i] - M); L += a[i]*lv[i]; }
    float invL = 1.f / L;
    #pragma unroll
    for (int i = 0; i < 4; i++) a[i] *= invL;
    unsigned short* dst = (unsigned short*)rdb + (size_t)row*128 + c0;
    #pragma unroll
    for (int j = 0; j < 8; j++) {
        float acc0=0.f, acc1=0.f, acc2=0.f, acc3=0.f;
        #pragma unroll
        for (int i = 0; i < 4; i++) {
            u16x4 x = ((const u16x4*)(Opart + ((size_t)row*4 + i)*128 + c0))[j];
            acc0 += a[i]*b2f(x[0]); acc1 += a[i]*b2f(x[1]);
            acc2 += a[i]*b2f(x[2]); acc3 += a[i]*b2f(x[3]);
        }
        u16x4 o = { bfu(acc0), bfu(acc1), bfu(acc2), bfu(acc3) };
        ((u16x4*)dst)[j] = o;
    }
}

// ---------------- K3: fused GRU (MFMA, LDS-staged, gi0-precomputed) ----------------
__global__ __launch_bounds__(256) void k_gru(const float* __restrict__ gi0,
                                             const __hip_bfloat16* __restrict__ rdb,
                                             const __hip_bfloat16* __restrict__ regsb,
                                             const float* __restrict__ regs,
                                             const __hip_bfloat16* __restrict__ Wihb,
                                             const float* __restrict__ bih,
                                             const __hip_bfloat16* __restrict__ Whhb,
                                             const float* __restrict__ bhh,
                                             float* __restrict__ newregs,
                                             __hip_bfloat16* __restrict__ nregsb)
{
    __shared__ __hip_bfloat16 At[2][64][32];
    __shared__ __hip_bfloat16 Bt[2][192][32];
    const int t = threadIdx.x, w = t >> 6, l = t & 63;
    const int lg = l >> 4, ll = l & 15;
    const int m0 = blockIdx.x*64;
    const int n0 = blockIdx.y*64;
    const int batch = blockIdx.x >> 4;
    const short* Rd = (const short*)rdb;
    const short* Hb = (const short*)regsb;
    const short* Wi = (const short*)Wihb;
    const short* Wh = (const short*)Whhb;

    f32x4 aR[4], aZ[4], aNi[4], aNh[4];
    #pragma unroll
    for (int c = 0; c < 4; c++) {
        int o = n0 + c*16 + ll;
        float gR = gi0[(size_t)batch*768 + o];
        float gZ = gi0[(size_t)batch*768 + 256 + o];
        float gN = gi0[(size_t)batch*768 + 512 + o];
        aR[c]  = (f32x4){gR,gR,gR,gR};
        aZ[c]  = (f32x4){gZ,gZ,gZ,gZ};
        aNi[c] = (f32x4){gN,gN,gN,gN};
        aNh[c] = (f32x4){0,0,0,0};
    }

    const int aci = (w << 6) + l;
    const int arow_s = aci >> 2, acc_s = aci & 3;
    const int agc = acc_s ^ ((arow_s >> 1) & 3);
    const char* aSrcA = (const char*)(Rd + (size_t)(m0+arow_s)*MD) + agc*16;
    const char* aSrcB = (const char*)(Hb + (size_t)(m0+arow_s)*RS) + agc*16;
    const char* bSrcA0; const char* bSrcA1; const char* bSrcA2;
    const char* bSrcB0; const char* bSrcB1; const char* bSrcB2;
    {
        int ci, row, cc, gc, g, col;
        ci = w*192 + 0*64 + l; row = ci >> 2; cc = ci & 3; gc = cc ^ ((row >> 1) & 3);
        g = row >> 6; col = row & 63;
        bSrcA0 = (const char*)(Wi + (size_t)(g*RS + n0 + col)*GRUIN + INS) + gc*16;
        bSrcB0 = (const char*)(Wh + (size_t)(g*RS + n0 + col)*RS) + gc*16;
        ci = w*192 + 1*64 + l; row = ci >> 2; cc = ci & 3; gc = cc ^ ((row >> 1) & 3);
        g = row >> 6; col = row & 63;
        bSrcA1 = (const char*)(Wi + (size_t)(g*RS + n0 + col)*GRUIN + INS) + gc*16;
        bSrcB1 = (const char*)(Wh + (size_t)(g*RS + n0 + col)*RS) + gc*16;
        ci = w*192 + 2*64 + l; row = ci >> 2; cc = ci & 3; gc = cc ^ ((row >> 1) & 3);
        g = row >> 6; col = row & 63;
        bSrcA2 = (const char*)(Wi + (size_t)(g*RS + n0 + col)*GRUIN + INS) + gc*16;
        bSrcB2 = (const char*)(Wh + (size_t)(g*RS + n0 + col)*RS) + gc*16;
    }

    const int NITA = 4, NIT = 12;
    auto stage = [&](int buf, int it) {
        char* abase = (char*)(&At[buf][0][0]) + (size_t)(w << 6)*16;
        char* bbase = (char*)(&Bt[buf][0][0]) + (size_t)(w*192)*16;
        const char *as, *b0, *b1, *b2;
        if (it < NITA) {
            int off = it*64;
            as = aSrcA + off; b0 = bSrcA0 + off; b1 = bSrcA1 + off; b2 = bSrcA2 + off;
        } else {
            int off = (it - NITA)*64;
            as = aSrcB + off; b0 = bSrcB0 + off; b1 = bSrcB1 + off; b2 = bSrcB2 + off;
        }
        gload16(as, abase);
        gload16(b0, bbase);
        gload16(b1, bbase + 64*16);
        gload16(b2, bbase + 128*16);
    };

    stage(0, 0);
    asm volatile("s_waitcnt vmcnt(0)" ::: "memory");
    __syncthreads();
    int cur = 0;
    const int arow = (w << 4) + ll;
    const int aswz = ((lg ^ ((arow >> 1) & 3)) << 4);
    for (int it = 0; it < NIT; ++it) {
        if (it + 1 < NIT) stage(cur ^ 1, it + 1);
        const char* ab = (const char*)(&At[cur][0][0]);
        const char* bb = (const char*)(&Bt[cur][0][0]);
        bf16x8 af = *(const bf16x8*)(ab + arow*64 + aswz);
        if (it < NITA) {
            #pragma unroll
            for (int c = 0; c < 4; c++) {
                int r0 = c*16 + ll;
                int sw = ((lg ^ ((r0 >> 1) & 3)) << 4);
                bf16x8 bR = *(const bf16x8*)(bb + (size_t)r0*64 + sw);
                bf16x8 bZ = *(const bf16x8*)(bb + (size_t)(r0 + 64)*64 + sw);
                bf16x8 bN = *(const bf16x8*)(bb + (size_t)(r0 + 128)*64 + sw);
                aR[c]  = __builtin_amdgcn_mfma_f32_16x16x32_bf16(af, bR, aR[c],  0, 0, 0);
                aZ[c]  = __builtin_amdgcn_mfma_f32_16x16x32_bf16(af, bZ, aZ[c],  0, 0, 0);
                aNi[c] = __builtin_amdgcn_mfma_f32_16x16x32_bf16(af, bN, aNi[c], 0, 0, 0);
            }
        } else {
            #pragma unroll
            for (int c = 0; c < 4; c++) {
                int r0 = c*16 + ll;
                int sw = ((lg ^ ((r0 >> 1) & 3)) << 4);
                bf16x8 bR = *(const bf16x8*)(bb + (size_t)r0*64 + sw);
                bf16x8 bZ = *(const bf16x8*)(bb + (size_t)(r0 + 64)*64 + sw);
                bf16x8 bN = *(const bf16x8*)(bb + (size_t)(r0 + 128)*64 + sw);
                aR[c]  = __builtin_amdgcn_mfma_f32_16x16x32_bf16(af, bR, aR[c],  0, 0, 0);
                aZ[c]  = __builtin_amdgcn_mfma_f32_16x16x32_bf16(af, bZ, aZ[c],  0, 0, 0);
                aNh[c] = __builtin_amdgcn_mfma_f32_16x16x32_bf16(af, bN, aNh[c], 0, 0, 0);
            }
        }
        asm volatile("s_waitcnt vmcnt(0)" ::: "memory");
        __syncthreads();
        cur ^= 1;
    }
    const int wm0 = m0 + (w << 4);
    #pragma unroll
    for (int c = 0; c < 4; c++) {
        int o = n0 + c*16 + ll;
        float bR = bih[o]        + bhh[o];
        float bZ = bih[o +   RS] + bhh[o +   RS];
        float bNi = bih[o + 2*RS];
        float bNh = bhh[o + 2*RS];
        #pragma unroll
        for (int r = 0; r < 4; r++) {
            int row = wm0 + lg*4 + r;
            float rr = sigf(aR[c][r] + bR);
            float zz = sigf(aZ[c][r] + bZ);
            float nn = tanhf(aNi[c][r] + bNi + rr*(aNh[c][r] + bNh));
            float cv = regs[(size_t)row*RS + o];
            float nv = (1.f - zz)*nn + zz*cv;
            newregs[(size_t)row*RS + o] = nv;
            nregsb[(size_t)row*RS + o] = __float2bfloat16(nv);
        }
    }
}

// ---------------- K4: output GEMM (MFMA, LDS-staged double-buffered) ----------------
__global__ __launch_bounds__(256) void k_out(const __hip_bfloat16* __restrict__ Ab,
                                             const __hip_bfloat16* __restrict__ Wb,
                                             const float* __restrict__ bias,
                                             float* __restrict__ out0)
{
    __shared__ __hip_bfloat16 At[2][64][32];
    __shared__ __hip_bfloat16 Bt[2][256][32];
    const int t = threadIdx.x, w = t >> 6, l = t & 63;
    const int lg = l >> 4, ll = l & 15;
    const int m0 = blockIdx.x*64;
    const int n0 = blockIdx.y*256;
    f32x4 acc[16];
    #pragma unroll
    for (int c = 0; c < 16; c++) acc[c] = (f32x4){0,0,0,0};

    const char* aSrc;
    {
        int row = t >> 2, cc = t & 3;
        int gc = cc ^ ((row >> 1) & 3);
        aSrc = (const char*)((const short*)Ab + (size_t)(m0+row)*RS) + gc*16;
    }
    const char* bSrc[4];
    #pragma unroll
    for (int j = 0; j < 4; j++) {
        int ci = j*256 + t;
        int row = ci >> 2, cc = ci & 3;
        int gc = cc ^ ((row >> 1) & 3);
        bSrc[j] = (const char*)((const short*)Wb + (size_t)(n0+row)*RS) + gc*16;
    }

    auto stage = [&](int buf, int it) {
        int off = it*64;
        char* abase = (char*)(&At[buf][0][0]) + (size_t)(w << 6)*16;
        gload16(aSrc + off, abase);
        #pragma unroll
        for (int j = 0; j < 4; j++) {
            char* bbase = (char*)(&Bt[buf][0][0]) + (size_t)(j*256 + (w << 6))*16;
            gload16(bSrc[j] + off, bbase);
        }
    };

    stage(0, 0);
    asm volatile("s_waitcnt vmcnt(0)" ::: "memory");
    __syncthreads();
    int cur = 0;
    const int arow = (w << 4) + ll;
    const int aswz = ((lg ^ ((arow >> 1) & 3)) << 4);
    for (int it = 0; it < 8; ++it) {
        if (it + 1 < 8) stage(cur ^ 1, it + 1);
        const char* ab = (const char*)(&At[cur][0][0]);
        const char* bb = (const char*)(&Bt[cur][0][0]);
        bf16x8 af = *(const bf16x8*)(ab + arow*64 + aswz);
        #pragma unroll
        for (int c = 0; c < 16; c++) {
            int r0 = c*16 + ll;
            int sw = ((lg ^ ((r0 >> 1) & 3)) << 4);
            bf16x8 bf = *(const bf16x8*)(bb + (size_t)r0*64 + sw);
            acc[c] = __builtin_amdgcn_mfma_f32_16x16x32_bf16(af, bf, acc[c], 0, 0, 0);
        }
        asm volatile("s_waitcnt vmcnt(0)" ::: "memory");
        __syncthreads();
        cur ^= 1;
    }
    const int wm0 = m0 + (w << 4);
    #pragma unroll
    for (int c = 0; c < 16; c++) {
        int o = n0 + c*16 + ll;
        float bv = bias[o];
        #pragma unroll
        for (int r = 0; r < 4; r++) {
            int row = wm0 + lg*4 + r;
            out0[(size_t)row*INS + o] = acc[c][r] + bv;
        }
    }
}

extern "C" void kernel_launch(void* const* d_in, const int* in_sizes, int n_in,
                              void* d_out, int out_size, void* d_ws, size_t ws_size,
                              hipStream_t stream)
{
    const float* inp  = (const float*)d_in[0];
    const float* regs = (const float*)d_in[1];
    const float* mem  = (const float*)d_in[2];
    const float* Wih  = (const float*)d_in[3];
    const float* bih  = (const float*)d_in[4];
    const float* Whh  = (const float*)d_in[5];
    const float* bhh  = (const float*)d_in[6];
    const float* Wmmu = (const float*)d_in[7];
    const float* bmmu = (const float*)d_in[8];
    const float* Wout = (const float*)d_in[9];
    const float* bout = (const float*)d_in[10];
    float* out = (float*)d_out;

    char* ws = (char*)d_ws;
    __hip_bfloat16* qbf    = (__hip_bfloat16*)(ws);
    __hip_bfloat16* rdb    = (__hip_bfloat16*)(ws + ((size_t)4<<20));
    __hip_bfloat16* memB   = (__hip_bfloat16*)(ws + ((size_t)8<<20));
    __hip_bfloat16* memT   = (__hip_bfloat16*)(ws + ((size_t)24<<20));
    __hip_bfloat16* regsb  = (__hip_bfloat16*)(ws + ((size_t)40<<20));
    __hip_bfloat16* nregsb = (__hip_bfloat16*)(ws + ((size_t)48<<20));
    __hip_bfloat16* Wmmub  = (__hip_bfloat16*)(ws + ((size_t)56<<20));
    __hip_bfloat16* Wihb   = (__hip_bfloat16*)(ws + ((size_t)56<<20) + ( 1<<20));
    __hip_bfloat16* Whhb   = (__hip_bfloat16*)(ws + ((size_t)56<<20) + ( 2<<20));
    __hip_bfloat16* Woutb  = (__hip_bfloat16*)(ws + ((size_t)56<<20) + ( 3<<20));
    __hip_bfloat16* inpb   = (__hip_bfloat16*)(ws + ((size_t)56<<20) + ( 4<<20));
    float*          MLpart = (float*)(ws + ((size_t)61<<20));            // 512 KB
    float*          gi0    = (float*)(ws + ((size_t)61<<20) + (1<<19));  // 49 KB
    unsigned short* Opart  = (unsigned short*)(out + O_OUT);  // 16.7 MB bf16 in out0 region

    dim3 ggi(B_, 3);
    k_gi<<<ggi, 256, 0, stream>>>(inp, Wih, gi0);
    k_cvt5<<<969, 256, 0, stream>>>(Wmmu, (unsigned short*)Wmmub,
                                    Wih,  (unsigned short*)Wihb,
                                    Whh,  (unsigned short*)Whhb,
                                    Wout, (unsigned short*)Woutb,
                                    inp,  (unsigned short*)inpb);
    k_cvt<<<(4194304/4 + 255)/256, 256, 0, stream>>>(regs, (unsigned short*)regsb, 4194304/4);
    k_conv<<<B_*128, 256, 0, stream>>>(mem, memB, memT);

    dim3 g1(NROWS/64, 3);
    k_mmu<<<g1, 256, 0, stream>>>(regsb, Wmmub, bmmu, out, qbf);
    k_softmax3<<<NROWS/256, 256, 0, stream>>>(out);
    k_attn<<<1024, 256, 0, stream>>>(qbf, memB, memT, Opart, MLpart);
    k_comb<<<NROWS/64, 256, 0, stream>>>(Opart, MLpart, rdb);
    dim3 g3(NROWS/64, 4);
    k_gru<<<g3, 256, 0, stream>>>(gi0, rdb, regsb, regs, Wihb, bih, Whhb, bhh,
                                  out + O_REGS, nregsb);
    dim3 g4(NROWS/64, 2);
    k_out<<<g4, 256, 0, stream>>>(nregsb, Woutb, bout, out);
}

// Round 14
// 157.974 us; speedup vs baseline: 3.4289x; 1.0944x over previous
//
#include <hip/hip_runtime.h>
#include <hip/hip_bf16.h>
#include <math.h>

#define B_      16
#define NPUS    1024
#define MEMS    4096
#define INS     512
#define RS      256
#define MD      128
#define GRUIN   640
#define MMUO    644
#define NROWS   (B_*NPUS)   // 16384

// d_out flat offsets (reference return order)
#define O_OUT   0u
#define O_REGS  8388608u
#define O_WKEY  12582912u
#define O_WVAL  14680064u
#define O_WGATE 16777216u
#define O_SSDK  16793600u
#define O_SSDV  18890752u
#define O_SSDG  20987904u

typedef __attribute__((ext_vector_type(8))) short bf16x8;
typedef __attribute__((ext_vector_type(4))) float f32x4;
typedef __attribute__((ext_vector_type(4))) unsigned short u16x4;

__device__ __forceinline__ float sigf(float x){ return 1.f/(1.f+__expf(-x)); }
__device__ __forceinline__ unsigned short bfu(float x){
    __hip_bfloat16 h = __float2bfloat16(x);
    return __builtin_bit_cast(unsigned short, h);
}
__device__ __forceinline__ float b2f(unsigned short u){
    unsigned v = ((unsigned)u) << 16;
    return __builtin_bit_cast(float, v);
}
// async global->LDS, 16B per lane; LDS dest is wave-uniform base + lane*16 (m104)
__device__ __forceinline__ void gload16(const void* g, void* s)
{
    __builtin_amdgcn_global_load_lds(
        (const __attribute__((address_space(1))) void*)g,
        (__attribute__((address_space(3))) void*)s, 16, 0, 0);
}

// ---------------- K_cvt: fp32 -> bf16, vectorized x4 ----------------
__global__ __launch_bounds__(256) void k_cvt(const float* __restrict__ src,
                                             unsigned short* __restrict__ dst, int n4)
{
    int i = blockIdx.x*256 + threadIdx.x;
    if (i >= n4) return;
    float4 v = ((const float4*)src)[i];
    u16x4 o = { bfu(v.x), bfu(v.y), bfu(v.z), bfu(v.w) };
    ((u16x4*)dst)[i] = o;
}

// ---------------- K_cvt5: fused 5-tensor fp32->bf16 (block-aligned segments) ----------------
__global__ __launch_bounds__(256) void k_cvt5(const float* __restrict__ s0, unsigned short* __restrict__ d0,
                                              const float* __restrict__ s1, unsigned short* __restrict__ d1,
                                              const float* __restrict__ s2, unsigned short* __restrict__ d2,
                                              const float* __restrict__ s3, unsigned short* __restrict__ d3,
                                              const float* __restrict__ s4, unsigned short* __restrict__ d4)
{
    int gi = blockIdx.x*256 + threadIdx.x;
    const float* s; unsigned short* d; int idx;
    if      (gi < 41216)  { s = s0; d = d0; idx = gi; }
    else if (gi < 164096) { s = s1; d = d1; idx = gi - 41216; }
    else if (gi < 213248) { s = s2; d = d2; idx = gi - 164096; }
    else if (gi < 246016) { s = s3; d = d3; idx = gi - 213248; }
    else                  { s = s4; d = d4; idx = gi - 246016; }
    float4 v = ((const float4*)s)[idx];
    u16x4 o = { bfu(v.x), bfu(v.y), bfu(v.z), bfu(v.w) };
    ((u16x4*)d)[idx] = o;
}

// ---------------- K_gi: gi0[16][768] = inp . Wih[:, :512]^T (fp32, once per batch) ----------------
__global__ __launch_bounds__(256) void k_gi(const float* __restrict__ inp,
                                            const float* __restrict__ Wih,
                                            float* __restrict__ gi0)
{
    __shared__ float xs[INS];
    const int b = blockIdx.x, seg = blockIdx.y;
    const int t = threadIdx.x;
    for (int i = t; i < INS; i += 256) xs[i] = inp[(size_t)b*INS + i];
    __syncthreads();
    const int o = seg*256 + t;                      // 0..767
    const float* wrow = Wih + (size_t)o*GRUIN;
    float a0 = 0.f, a1 = 0.f, a2 = 0.f, a3 = 0.f;
    for (int k = 0; k < INS; k += 4) {
        float4 wv = *(const float4*)(wrow + k);
        a0 += xs[k]*wv.x; a1 += xs[k+1]*wv.y; a2 += xs[k+2]*wv.z; a3 += xs[k+3]*wv.w;
    }
    gi0[(size_t)b*768 + o] = (a0 + a1) + (a2 + a3);
}

// ---------------- K0: memory_context -> bf16 row-major + transposed ----------------
__global__ __launch_bounds__(256) void k_conv(const float* __restrict__ mem,
                                              __hip_bfloat16* __restrict__ memB,
                                              __hip_bfloat16* __restrict__ memT)
{
    __shared__ float Ms[32][129];
    const int t = threadIdx.x;
    const int b = blockIdx.x >> 7;
    const int m0 = (blockIdx.x & 127) << 5;
    const float* src = mem + ((size_t)b*MEMS + m0)*MD;
    for (int idx = t; idx < 32*128; idx += 256) {
        int m = idx >> 7, d = idx & 127;
        float v = src[(size_t)m*MD + d];
        Ms[m][d] = v;
        memB[((size_t)b*MEMS + m0 + m)*MD + d] = __float2bfloat16(v);
    }
    __syncthreads();
    for (int idx = t; idx < 128*32; idx += 256) {
        int d = idx >> 5, m = idx & 31;
        memT[((size_t)b*MD + d)*MEMS + m0 + m] = __float2bfloat16(Ms[m][d]);
    }
}

// ---------------- K1: MMU GEMM (MFMA, LDS-staged, 128-col tiles, fused ssd softmax) ----------------
// Block: 64 rows x 128 cols. A[64][32] + B[128][32] double-buffered (24.6KB LDS).
// Grid (256, 6); tile y=5 covers o 640-767 (only 640-643 valid; logits softmaxed in-wave).
__global__ __launch_bounds__(256, 4) void k_mmu(const __hip_bfloat16* __restrict__ Ab,
                                                const __hip_bfloat16* __restrict__ Wb,
                                                const float* __restrict__ bias,
                                                float* __restrict__ out,
                                                __hip_bfloat16* __restrict__ qbf)
{
    __shared__ __hip_bfloat16 At[2][64][32];
    __shared__ __hip_bfloat16 Bt[2][128][32];
    const int t = threadIdx.x, w = t >> 6, l = t & 63;
    const int lg = l >> 4, ll = l & 15;
    const int m0 = blockIdx.x*64;
    const int n0 = blockIdx.y*128;
    f32x4 acc[8];
    #pragma unroll
    for (int c = 0; c < 8; c++) acc[c] = (f32x4){0,0,0,0};

    const char* aSrc;
    {
        int row = t >> 2, cc = t & 3;
        int gc = cc ^ ((row >> 1) & 3);
        aSrc = (const char*)((const short*)Ab + (size_t)(m0+row)*RS) + gc*16;
    }
    const char* bSrc[2];
    #pragma unroll
    for (int j = 0; j < 2; j++) {
        int ci = w*128 + j*64 + l;
        int row = ci >> 2, cc = ci & 3;
        int gc = cc ^ ((row >> 1) & 3);
        bSrc[j] = (const char*)((const short*)Wb + (size_t)(n0+row)*RS) + gc*16;
    }

    auto stage = [&](int buf, int it) {
        int off = it*64;
        char* abase = (char*)(&At[buf][0][0]) + (size_t)(w << 6)*16;
        gload16(aSrc + off, abase);
        #pragma unroll
        for (int j = 0; j < 2; j++) {
            char* bbase = (char*)(&Bt[buf][0][0]) + (size_t)(w*128 + j*64)*16;
            gload16(bSrc[j] + off, bbase);
        }
    };

    stage(0, 0);
    asm volatile("s_waitcnt vmcnt(0)" ::: "memory");
    __syncthreads();
    int cur = 0;
    const int arow = (w << 4) + ll;
    const int aswz = ((lg ^ ((arow >> 1) & 3)) << 4);
    for (int it = 0; it < 8; ++it) {
        if (it + 1 < 8) stage(cur ^ 1, it + 1);
        const char* ab = (const char*)(&At[cur][0][0]);
        const char* bb = (const char*)(&Bt[cur][0][0]);
        bf16x8 af = *(const bf16x8*)(ab + arow*64 + aswz);
        #pragma unroll
        for (int c = 0; c < 8; c++) {
            int r0 = c*16 + ll;
            int sw = ((lg ^ ((r0 >> 1) & 3)) << 4);
            bf16x8 bf = *(const bf16x8*)(bb + (size_t)r0*64 + sw);
            acc[c] = __builtin_amdgcn_mfma_f32_16x16x32_bf16(af, bf, acc[c], 0, 0, 0);
        }
        asm volatile("s_waitcnt vmcnt(0)" ::: "memory");
        __syncthreads();
        cur ^= 1;
    }
    const int wm0 = m0 + (w << 4);
    #pragma unroll
    for (int c = 0; c < 8; c++) {
        int o = n0 + c*16 + ll;
        if (o > 640) continue;      // logits (641-643) handled below; >643 invalid
        float bv = bias[o];
        #pragma unroll
        for (int r = 0; r < 4; r++) {
            int row = wm0 + lg*4 + r;
            float v = acc[c][r] + bv;
            if      (o < MD)        qbf[(size_t)row*MD + o] = __float2bfloat16(v * 0.08838834764831845f);
            else if (o < 2*MD)      out[O_WKEY + (size_t)row*MD + (o -   MD)] = v;
            else if (o < 3*MD)      out[O_WVAL + (size_t)row*MD + (o - 2*MD)] = v;
            else if (o == 3*MD)     out[O_WGATE + row] = sigf(v);
            else if (o < 4*MD + 1)  out[O_SSDK + (size_t)row*MD + (o - (3*MD+1))] = v;
            else                    out[O_SSDV + (size_t)row*MD + (o - (4*MD+1))] = v;
        }
    }
    if (n0 == 640) {
        // fused ssd_gate softmax: lanes ll=1,2,3 of c=0 hold the 3 logits per row
        #pragma unroll
        for (int r = 0; r < 4; r++) {
            int o = n0 + ll;
            float vr = acc[0][r] + ((o < MMUO) ? bias[o] : 0.f);
            float va = __shfl(vr, lg*16 + 1);
            float vb = __shfl(vr, lg*16 + 2);
            float vc = __shfl(vr, lg*16 + 3);
            float mm = fmaxf(va, fmaxf(vb, vc));
            float ea = __expf(va-mm), eb = __expf(vb-mm), ec = __expf(vc-mm);
            float inv = 1.f/(ea+eb+ec);
            int row = wm0 + lg*4 + r;
            if (ll == 1) out[O_SSDG + (size_t)row*3 + 0] = ea*inv;
            if (ll == 2) out[O_SSDG + (size_t)row*3 + 1] = eb*inv;
            if (ll == 3) out[O_SSDG + (size_t)row*3 + 2] = ec*inv;
        }
    }
}

// ---------------- K2: LDS-staged 4-way split-K flash attention, 16 q-rows/wave ----------------
__global__ __launch_bounds__(256, 4) void k_attn(const __hip_bfloat16* __restrict__ qb,
                                                 const __hip_bfloat16* __restrict__ memB,
                                                 const __hip_bfloat16* __restrict__ memT,
                                                 unsigned short* __restrict__ Opart,
                                                 float* __restrict__ MLpart)
{
    __shared__ __hip_bfloat16 Kt[2][32][128];
    __shared__ __hip_bfloat16 Vt[2][128][32];
    __shared__ __hip_bfloat16 Pl[4][16][40];
    const int t = threadIdx.x, w = t >> 6, l = t & 63;
    const int lg = l >> 4, ll = l & 15;
    const int bid = blockIdx.x;
    const int xcd = bid & 7, rest = bid >> 3;      // rest 0..127
    const int b = xcd + ((rest >> 6) << 3);        // 2 batches per XCD
    const int sub = rest & 63;
    const int qblk = sub >> 2, kh = sub & 3;       // 16 q-blocks x 4 key-quarters
    const int qrow0 = (b << 10) + (qblk << 6) + (w << 4);   // wave's 16 q-rows
    const int k_beg = kh << 10;                             // 1024 keys per quarter
    const float THR = 4.0f;

    const short* Q = (const short*)qb;
    bf16x8 qf[4];
    #pragma unroll
    for (int ks = 0; ks < 4; ks++)
        qf[ks] = *(const bf16x8*)(Q + (size_t)(qrow0 + ll)*MD + ks*32 + lg*8);

    f32x4 O[8];
    #pragma unroll
    for (int dt = 0; dt < 8; dt++) O[dt] = (f32x4){0.f,0.f,0.f,0.f};
    float m_run[4], lsum[4];
    #pragma unroll
    for (int r = 0; r < 4; r++) { m_run[r] = -INFINITY; lsum[r] = 0.f; }

    const char* MbB = (const char*)memB + (size_t)b*MEMS*MD*2;
    const char* MtB = (const char*)memT + (size_t)b*MD*MEMS*2;

    auto stage = [&](int buf, int it) {
        const int k0 = k_beg + it*32;
        char* kbase = (char*)(&Kt[buf][0][0]);
        char* vbase = (char*)(&Vt[buf][0][0]);
        #pragma unroll
        for (int j = 0; j < 2; j++) {
            int ci = (w << 7) + (j << 6) + l;        // chunk 0..511 (16B each)
            int krow = ci >> 4, cc = ci & 15;
            int gc = cc ^ (krow & 7);                // pre-swizzled global source
            gload16(MbB + (size_t)(k0 + krow)*256 + gc*16,
                    kbase + (size_t)((w << 7) + (j << 6))*16);
        }
        #pragma unroll
        for (int j = 0; j < 2; j++) {
            int ci = (w << 7) + (j << 6) + l;
            int drow = ci >> 2, cc = ci & 3;
            int gc = cc ^ ((drow >> 1) & 3);         // V swizzle (both-sides involution)
            gload16(MtB + (size_t)drow*(MEMS*2) + (size_t)k0*2 + gc*16,
                    vbase + (size_t)((w << 7) + (j << 6))*16);
        }
    };

    stage(0, 0);
    asm volatile("s_waitcnt vmcnt(0)" ::: "memory");
    asm volatile("s_barrier" ::: "memory");
    int cur = 0;
    const int NIT = 1024/32;   // 32
    const int vsw = ((lg ^ ((ll >> 1) & 3)) << 4);
    for (int it = 0; it < NIT; ++it) {
        if (it + 1 < NIT) {
            stage(cur ^ 1, it + 1);
            asm volatile("s_waitcnt vmcnt(4)" ::: "memory");   // own stage(cur) done; next in flight
        } else {
            asm volatile("s_waitcnt vmcnt(0)" ::: "memory");
        }
        asm volatile("s_barrier" ::: "memory");                // everyone's stage(cur) done
        const char* kbase = (const char*)(&Kt[cur][0][0]);
        const char* vbase = (const char*)(&Vt[cur][0][0]);
        f32x4 s0 = (f32x4){0,0,0,0}, s1 = (f32x4){0,0,0,0};
        #pragma unroll
        for (int ks = 0; ks < 4; ks++) {
            int c0 = ks*4 + lg;
            int sw = (c0 ^ (ll & 7)) << 4;
            bf16x8 kf0 = *(const bf16x8*)(kbase + (size_t)ll*256 + sw);
            bf16x8 kf1 = *(const bf16x8*)(kbase + (size_t)(16 + ll)*256 + sw);
            s0 = __builtin_amdgcn_mfma_f32_16x16x32_bf16(qf[ks], kf0, s0, 0, 0, 0);
            s1 = __builtin_amdgcn_mfma_f32_16x16x32_bf16(qf[ks], kf1, s1, 0, 0, 0);
        }
        bool need = false;
        #pragma unroll
        for (int r = 0; r < 4; r++) {
            need |= (s0[r] > m_run[r] + THR);
            need |= (s1[r] > m_run[r] + THR);
        }
        if (__any(need)) {
            #pragma unroll
            for (int r = 0; r < 4; r++) {
                float v = fmaxf(s0[r], s1[r]);
                v = fmaxf(v, __shfl_xor(v, 1));
                v = fmaxf(v, __shfl_xor(v, 2));
                v = fmaxf(v, __shfl_xor(v, 4));
                v = fmaxf(v, __shfl_xor(v, 8));
                float mnew = fmaxf(m_run[r], v);
                float alpha = __expf(m_run[r] - mnew);
                m_run[r] = mnew;
                lsum[r] *= alpha;
                #pragma unroll
                for (int dt = 0; dt < 8; dt++) O[dt][r] *= alpha;
            }
        }
        #pragma unroll
        for (int r = 0; r < 4; r++) {
            float p0 = __expf(s0[r] - m_run[r]);
            float p1 = __expf(s1[r] - m_run[r]);
            Pl[w][lg*4 + r][ll]      = __float2bfloat16(p0);
            Pl[w][lg*4 + r][16 + ll] = __float2bfloat16(p1);
            lsum[r] += p0 + p1;
        }
        __builtin_amdgcn_wave_barrier();
        bf16x8 pa = *(const bf16x8*)(&Pl[w][ll][lg*8]);
        __builtin_amdgcn_wave_barrier();
        #pragma unroll
        for (int dt = 0; dt < 8; dt++) {
            bf16x8 vf = *(const bf16x8*)(vbase + (size_t)(dt*16 + ll)*64 + vsw);
            O[dt] = __builtin_amdgcn_mfma_f32_16x16x32_bf16(pa, vf, O[dt], 0, 0, 0);
        }
        asm volatile("s_barrier" ::: "memory");                // all reads of buf cur done
        cur ^= 1;
    }
    #pragma unroll
    for (int r = 0; r < 4; r++) {
        float s = lsum[r];
        s += __shfl_xor(s, 1);
        s += __shfl_xor(s, 2);
        s += __shfl_xor(s, 4);
        s += __shfl_xor(s, 8);
        lsum[r] = s;
    }
    #pragma unroll
    for (int dt = 0; dt < 8; dt++)
        #pragma unroll
        for (int r = 0; r < 4; r++) {
            int row = qrow0 + lg*4 + r;
            Opart[((size_t)row*4 + kh)*128 + dt*16 + ll] = bfu(O[dt][r]);
        }
    if (ll == 0) {
        #pragma unroll
        for (int r = 0; r < 4; r++) {
            int row = qrow0 + lg*4 + r;
            MLpart[((size_t)row*4 + kh)*2 + 0] = m_run[r];
            MLpart[((size_t)row*4 + kh)*2 + 1] = lsum[r];
        }
    }
}

// ---------------- K2b: combine the 4 split-K partials (bf16) -> rd bf16 ----------------
__global__ __launch_bounds__(256) void k_comb(const unsigned short* __restrict__ Opart,
                                              const float* __restrict__ MLpart,
                                              __hip_bfloat16* __restrict__ rdb)
{
    const int t = threadIdx.x;
    const int row = blockIdx.x*64 + (t >> 2);
    const int c0 = (t & 3) * 32;
    float m[4], lv[4], a[4];
    float M = -INFINITY;
    #pragma unroll
    for (int i = 0; i < 4; i++) {
        m[i]  = MLpart[((size_t)row*4 + i)*2 + 0];
        lv[i] = MLpart[((size_t)row*4 + i)*2 + 1];
        M = fmaxf(M, m[i]);
    }
    float L = 0.f;
    #pragma unroll
    for (int i = 0; i < 4; i++) { a[i] = __expf(m[i] - M); L += a[i]*lv[i]; }
    float invL = 1.f / L;
    #pragma unroll
    for (int i = 0; i < 4; i++) a[i] *= invL;
    unsigned short* dst = (unsigned short*)rdb + (size_t)row*128 + c0;
    #pragma unroll
    for (int j = 0; j < 8; j++) {
        float acc0=0.f, acc1=0.f, acc2=0.f, acc3=0.f;
        #pragma unroll
        for (int i = 0; i < 4; i++) {
            u16x4 x = ((const u16x4*)(Opart + ((size_t)row*4 + i)*128 + c0))[j];
            acc0 += a[i]*b2f(x[0]); acc1 += a[i]*b2f(x[1]);
            acc2 += a[i]*b2f(x[2]); acc3 += a[i]*b2f(x[3]);
        }
        u16x4 o = { bfu(acc0), bfu(acc1), bfu(acc2), bfu(acc3) };
        ((u16x4*)dst)[j] = o;
    }
}

// ---------------- K3: fused GRU (MFMA, LDS-staged, gi0-precomputed) ----------------
__global__ __launch_bounds__(256, 4) void k_gru(const float* __restrict__ gi0,
                                                const __hip_bfloat16* __restrict__ rdb,
                                                const __hip_bfloat16* __restrict__ regsb,
                                                const float* __restrict__ regs,
                                                const __hip_bfloat16* __restrict__ Wihb,
                                                const float* __restrict__ bih,
                                                const __hip_bfloat16* __restrict__ Whhb,
                                                const float* __restrict__ bhh,
                                                float* __restrict__ newregs,
                                                __hip_bfloat16* __restrict__ nregsb)
{
    __shared__ __hip_bfloat16 At[2][64][32];
    __shared__ __hip_bfloat16 Bt[2][192][32];
    const int t = threadIdx.x, w = t >> 6, l = t & 63;
    const int lg = l >> 4, ll = l & 15;
    const int m0 = blockIdx.x*64;
    const int n0 = blockIdx.y*64;
    const int batch = blockIdx.x >> 4;
    const short* Rd = (const short*)rdb;
    const short* Hb = (const short*)regsb;
    const short* Wi = (const short*)Wihb;
    const short* Wh = (const short*)Whhb;

    f32x4 aR[4], aZ[4], aNi[4], aNh[4];
    #pragma unroll
    for (int c = 0; c < 4; c++) {
        int o = n0 + c*16 + ll;
        float gR = gi0[(size_t)batch*768 + o];
        float gZ = gi0[(size_t)batch*768 + 256 + o];
        float gN = gi0[(size_t)batch*768 + 512 + o];
        aR[c]  = (f32x4){gR,gR,gR,gR};
        aZ[c]  = (f32x4){gZ,gZ,gZ,gZ};
        aNi[c] = (f32x4){gN,gN,gN,gN};
        aNh[c] = (f32x4){0,0,0,0};
    }

    const int aci = (w << 6) + l;
    const int arow_s = aci >> 2, acc_s = aci & 3;
    const int agc = acc_s ^ ((arow_s >> 1) & 3);
    const char* aSrcA = (const char*)(Rd + (size_t)(m0+arow_s)*MD) + agc*16;
    const char* aSrcB = (const char*)(Hb + (size_t)(m0+arow_s)*RS) + agc*16;
    const char* bSrcA0; const char* bSrcA1; const char* bSrcA2;
    const char* bSrcB0; const char* bSrcB1; const char* bSrcB2;
    {
        int ci, row, cc, gc, g, col;
        ci = w*192 + 0*64 + l; row = ci >> 2; cc = ci & 3; gc = cc ^ ((row >> 1) & 3);
        g = row >> 6; col = row & 63;
        bSrcA0 = (const char*)(Wi + (size_t)(g*RS + n0 + col)*GRUIN + INS) + gc*16;
        bSrcB0 = (const char*)(Wh + (size_t)(g*RS + n0 + col)*RS) + gc*16;
        ci = w*192 + 1*64 + l; row = ci >> 2; cc = ci & 3; gc = cc ^ ((row >> 1) & 3);
        g = row >> 6; col = row & 63;
        bSrcA1 = (const char*)(Wi + (size_t)(g*RS + n0 + col)*GRUIN + INS) + gc*16;
        bSrcB1 = (const char*)(Wh + (size_t)(g*RS + n0 + col)*RS) + gc*16;
        ci = w*192 + 2*64 + l; row = ci >> 2; cc = ci & 3; gc = cc ^ ((row >> 1) & 3);
        g = row >> 6; col = row & 63;
        bSrcA2 = (const char*)(Wi + (size_t)(g*RS + n0 + col)*GRUIN + INS) + gc*16;
        bSrcB2 = (const char*)(Wh + (size_t)(g*RS + n0 + col)*RS) + gc*16;
    }

    const int NITA = 4, NIT = 12;
    auto stage = [&](int buf, int it) {
        char* abase = (char*)(&At[buf][0][0]) + (size_t)(w << 6)*16;
        char* bbase = (char*)(&Bt[buf][0][0]) + (size_t)(w*192)*16;
        const char *as, *b0, *b1, *b2;
        if (it < NITA) {
            int off = it*64;
            as = aSrcA + off; b0 = bSrcA0 + off; b1 = bSrcA1 + off; b2 = bSrcA2 + off;
        } else {
            int off = (it - NITA)*64;
            as = aSrcB + off; b0 = bSrcB0 + off; b1 = bSrcB1 + off; b2 = bSrcB2 + off;
        }
        gload16(as, abase);
        gload16(b0, bbase);
        gload16(b1, bbase + 64*16);
        gload16(b2, bbase + 128*16);
    };

    stage(0, 0);
    asm volatile("s_waitcnt vmcnt(0)" ::: "memory");
    __syncthreads();
    int cur = 0;
    const int arow = (w << 4) + ll;
    const int aswz = ((lg ^ ((arow >> 1) & 3)) << 4);
    for (int it = 0; it < NIT; ++it) {
        if (it + 1 < NIT) stage(cur ^ 1, it + 1);
        const char* ab = (const char*)(&At[cur][0][0]);
        const char* bb = (const char*)(&Bt[cur][0][0]);
        bf16x8 af = *(const bf16x8*)(ab + arow*64 + aswz);
        if (it < NITA) {
            #pragma unroll
            for (int c = 0; c < 4; c++) {
                int r0 = c*16 + ll;
                int sw = ((lg ^ ((r0 >> 1) & 3)) << 4);
                bf16x8 bR = *(const bf16x8*)(bb + (size_t)r0*64 + sw);
                bf16x8 bZ = *(const bf16x8*)(bb + (size_t)(r0 + 64)*64 + sw);
                bf16x8 bN = *(const bf16x8*)(bb + (size_t)(r0 + 128)*64 + sw);
                aR[c]  = __builtin_amdgcn_mfma_f32_16x16x32_bf16(af, bR, aR[c],  0, 0, 0);
                aZ[c]  = __builtin_amdgcn_mfma_f32_16x16x32_bf16(af, bZ, aZ[c],  0, 0, 0);
                aNi[c] = __builtin_amdgcn_mfma_f32_16x16x32_bf16(af, bN, aNi[c], 0, 0, 0);
            }
        } else {
            #pragma unroll
            for (int c = 0; c < 4; c++) {
                int r0 = c*16 + ll;
                int sw = ((lg ^ ((r0 >> 1) & 3)) << 4);
                bf16x8 bR = *(const bf16x8*)(bb + (size_t)r0*64 + sw);
                bf16x8 bZ = *(const bf16x8*)(bb + (size_t)(r0 + 64)*64 + sw);
                bf16x8 bN = *(const bf16x8*)(bb + (size_t)(r0 + 128)*64 + sw);
                aR[c]  = __builtin_amdgcn_mfma_f32_16x16x32_bf16(af, bR, aR[c],  0, 0, 0);
                aZ[c]  = __builtin_amdgcn_mfma_f32_16x16x32_bf16(af, bZ, aZ[c],  0, 0, 0);
                aNh[c] = __builtin_amdgcn_mfma_f32_16x16x32_bf16(af, bN, aNh[c], 0, 0, 0);
            }
        }
        asm volatile("s_waitcnt vmcnt(0)" ::: "memory");
        __syncthreads();
        cur ^= 1;
    }
    const int wm0 = m0 + (w << 4);
    #pragma unroll
    for (int c = 0; c < 4; c++) {
        int o = n0 + c*16 + ll;
        float bR = bih[o]        + bhh[o];
        float bZ = bih[o +   RS] + bhh[o +   RS];
        float bNi = bih[o + 2*RS];
        float bNh = bhh[o + 2*RS];
        #pragma unroll
        for (int r = 0; r < 4; r++) {
            int row = wm0 + lg*4 + r;
            float rr = sigf(aR[c][r] + bR);
            float zz = sigf(aZ[c][r] + bZ);
            float nn = tanhf(aNi[c][r] + bNi + rr*(aNh[c][r] + bNh));
            float cv = regs[(size_t)row*RS + o];
            float nv = (1.f - zz)*nn + zz*cv;
            newregs[(size_t)row*RS + o] = nv;
            nregsb[(size_t)row*RS + o] = __float2bfloat16(nv);
        }
    }
}

// ---------------- K4: output GEMM (MFMA, LDS-staged, 128-col tiles) ----------------
// Block: 64 rows x 128 cols; grid (256, 4); LDS 24.6KB double-buffered.
__global__ __launch_bounds__(256, 4) void k_out(const __hip_bfloat16* __restrict__ Ab,
                                                const __hip_bfloat16* __restrict__ Wb,
                                                const float* __restrict__ bias,
                                                float* __restrict__ out0)
{
    __shared__ __hip_bfloat16 At[2][64][32];
    __shared__ __hip_bfloat16 Bt[2][128][32];
    const int t = threadIdx.x, w = t >> 6, l = t & 63;
    const int lg = l >> 4, ll = l & 15;
    const int m0 = blockIdx.x*64;
    const int n0 = blockIdx.y*128;
    f32x4 acc[8];
    #pragma unroll
    for (int c = 0; c < 8; c++) acc[c] = (f32x4){0,0,0,0};

    const char* aSrc;
    {
        int row = t >> 2, cc = t & 3;
        int gc = cc ^ ((row >> 1) & 3);
        aSrc = (const char*)((const short*)Ab + (size_t)(m0+row)*RS) + gc*16;
    }
    const char* bSrc[2];
    #pragma unroll
    for (int j = 0; j < 2; j++) {
        int ci = w*128 + j*64 + l;
        int row = ci >> 2, cc = ci & 3;
        int gc = cc ^ ((row >> 1) & 3);
        bSrc[j] = (const char*)((const short*)Wb + (size_t)(n0+row)*RS) + gc*16;
    }

    auto stage = [&](int buf, int it) {
        int off = it*64;
        char* abase = (char*)(&At[buf][0][0]) + (size_t)(w << 6)*16;
        gload16(aSrc + off, abase);
        #pragma unroll
        for (int j = 0; j < 2; j++) {
            char* bbase = (char*)(&Bt[buf][0][0]) + (size_t)(w*128 + j*64)*16;
            gload16(bSrc[j] + off, bbase);
        }
    };

    stage(0, 0);
    asm volatile("s_waitcnt vmcnt(0)" ::: "memory");
    __syncthreads();
    int cur = 0;
    const int arow = (w << 4) + ll;
    const int aswz = ((lg ^ ((arow >> 1) & 3)) << 4);
    for (int it = 0; it < 8; ++it) {
        if (it + 1 < 8) stage(cur ^ 1, it + 1);
        const char* ab = (const char*)(&At[cur][0][0]);
        const char* bb = (const char*)(&Bt[cur][0][0]);
        bf16x8 af = *(const bf16x8*)(ab + arow*64 + aswz);
        #pragma unroll
        for (int c = 0; c < 8; c++) {
            int r0 = c*16 + ll;
            int sw = ((lg ^ ((r0 >> 1) & 3)) << 4);
            bf16x8 bf = *(const bf16x8*)(bb + (size_t)r0*64 + sw);
            acc[c] = __builtin_amdgcn_mfma_f32_16x16x32_bf16(af, bf, acc[c], 0, 0, 0);
        }
        asm volatile("s_waitcnt vmcnt(0)" ::: "memory");
        __syncthreads();
        cur ^= 1;
    }
    const int wm0 = m0 + (w << 4);
    #pragma unroll
    for (int c = 0; c < 8; c++) {
        int o = n0 + c*16 + ll;
        float bv = bias[o];
        #pragma unroll
        for (int r = 0; r < 4; r++) {
            int row = wm0 + lg*4 + r;
            out0[(size_t)row*INS + o] = acc[c][r] + bv;
        }
    }
}

extern "C" void kernel_launch(void* const* d_in, const int* in_sizes, int n_in,
                              void* d_out, int out_size, void* d_ws, size_t ws_size,
                              hipStream_t stream)
{
    const float* inp  = (const float*)d_in[0];
    const float* regs = (const float*)d_in[1];
    const float* mem  = (const float*)d_in[2];
    const float* Wih  = (const float*)d_in[3];
    const float* bih  = (const float*)d_in[4];
    const float* Whh  = (const float*)d_in[5];
    const float* bhh  = (const float*)d_in[6];
    const float* Wmmu = (const float*)d_in[7];
    const float* bmmu = (const float*)d_in[8];
    const float* Wout = (const float*)d_in[9];
    const float* bout = (const float*)d_in[10];
    float* out = (float*)d_out;

    char* ws = (char*)d_ws;
    __hip_bfloat16* qbf    = (__hip_bfloat16*)(ws);
    __hip_bfloat16* rdb    = (__hip_bfloat16*)(ws + ((size_t)4<<20));
    __hip_bfloat16* memB   = (__hip_bfloat16*)(ws + ((size_t)8<<20));
    __hip_bfloat16* memT   = (__hip_bfloat16*)(ws + ((size_t)24<<20));
    __hip_bfloat16* regsb  = (__hip_bfloat16*)(ws + ((size_t)40<<20));
    __hip_bfloat16* nregsb = (__hip_bfloat16*)(ws + ((size_t)48<<20));
    __hip_bfloat16* Wmmub  = (__hip_bfloat16*)(ws + ((size_t)56<<20));
    __hip_bfloat16* Wihb   = (__hip_bfloat16*)(ws + ((size_t)56<<20) + ( 1<<20));
    __hip_bfloat16* Whhb   = (__hip_bfloat16*)(ws + ((size_t)56<<20) + ( 2<<20));
    __hip_bfloat16* Woutb  = (__hip_bfloat16*)(ws + ((size_t)56<<20) + ( 3<<20));
    __hip_bfloat16* inpb   = (__hip_bfloat16*)(ws + ((size_t)56<<20) + ( 4<<20));
    float*          MLpart = (float*)(ws + ((size_t)61<<20));            // 512 KB
    float*          gi0    = (float*)(ws + ((size_t)61<<20) + (1<<19));  // 49 KB
    unsigned short* Opart  = (unsigned short*)(out + O_OUT);  // 16.7 MB bf16 in out0 region

    dim3 ggi(B_, 3);
    k_gi<<<ggi, 256, 0, stream>>>(inp, Wih, gi0);
    k_cvt5<<<969, 256, 0, stream>>>(Wmmu, (unsigned short*)Wmmub,
                                    Wih,  (unsigned short*)Wihb,
                                    Whh,  (unsigned short*)Whhb,
                                    Wout, (unsigned short*)Woutb,
                                    inp,  (unsigned short*)inpb);
    k_cvt<<<(4194304/4 + 255)/256, 256, 0, stream>>>(regs, (unsigned short*)regsb, 4194304/4);
    k_conv<<<B_*128, 256, 0, stream>>>(mem, memB, memT);

    dim3 g1(NROWS/64, 6);
    k_mmu<<<g1, 256, 0, stream>>>(regsb, Wmmub, bmmu, out, qbf);
    k_attn<<<1024, 256, 0, stream>>>(qbf, memB, memT, Opart, MLpart);
    k_comb<<<NROWS/64, 256, 0, stream>>>(Opart, MLpart, rdb);
    dim3 g3(NROWS/64, 4);
    k_gru<<<g3, 256, 0, stream>>>(gi0, rdb, regsb, regs, Wihb, bih, Whhb, bhh,
                                  out + O_REGS, nregsb);
    dim3 g4(NROWS/64, 4);
    k_out<<<g4, 256, 0, stream>>>(nregsb, Woutb, bout, out);
}

// Round 15
// 155.445 us; speedup vs baseline: 3.4847x; 1.0163x over previous
//
#include <hip/hip_runtime.h>
#include <hip/hip_bf16.h>
#include <math.h>

#define B_      16
#define NPUS    1024
#define MEMS    4096
#define INS     512
#define RS      256
#define MD      128
#define GRUIN   640
#define MMUO    644
#define NROWS   (B_*NPUS)   // 16384

// d_out flat offsets (reference return order)
#define O_OUT   0u
#define O_REGS  8388608u
#define O_WKEY  12582912u
#define O_WVAL  14680064u
#define O_WGATE 16777216u
#define O_SSDK  16793600u
#define O_SSDV  18890752u
#define O_SSDG  20987904u

typedef __attribute__((ext_vector_type(8))) short bf16x8;
typedef __attribute__((ext_vector_type(4))) float f32x4;
typedef __attribute__((ext_vector_type(4))) unsigned short u16x4;

__device__ __forceinline__ float sigf(float x){ return 1.f/(1.f+__expf(-x)); }
__device__ __forceinline__ unsigned short bfu(float x){
    __hip_bfloat16 h = __float2bfloat16(x);
    return __builtin_bit_cast(unsigned short, h);
}
__device__ __forceinline__ float b2f(unsigned short u){
    unsigned v = ((unsigned)u) << 16;
    return __builtin_bit_cast(float, v);
}
// async global->LDS, 16B per lane; LDS dest is wave-uniform base + lane*16 (m104)
__device__ __forceinline__ void gload16(const void* g, void* s)
{
    __builtin_amdgcn_global_load_lds(
        (const __attribute__((address_space(1))) void*)g,
        (__attribute__((address_space(3))) void*)s, 16, 0, 0);
}

// ---------------- K_cvt: fp32 -> bf16, vectorized x4 ----------------
__global__ __launch_bounds__(256) void k_cvt(const float* __restrict__ src,
                                             unsigned short* __restrict__ dst, int n4)
{
    int i = blockIdx.x*256 + threadIdx.x;
    if (i >= n4) return;
    float4 v = ((const float4*)src)[i];
    u16x4 o = { bfu(v.x), bfu(v.y), bfu(v.z), bfu(v.w) };
    ((u16x4*)dst)[i] = o;
}

// ---------------- K_cvt5g: fused 5-tensor fp32->bf16 + gi0 GEMM (blocks >= 969) ----------------
// quads: Wmmu 41216 | Wih 122880 | Whh 49152 | Wout 32768 | inp 2048 = 969 blocks;
// blocks 969..1016: gi0[b][768] = inp[b] . Wih[:, :512]^T (fp32)
__global__ __launch_bounds__(256) void k_cvt5g(const float* __restrict__ s0, unsigned short* __restrict__ d0,
                                               const float* __restrict__ s1, unsigned short* __restrict__ d1,
                                               const float* __restrict__ s2, unsigned short* __restrict__ d2,
                                               const float* __restrict__ s3, unsigned short* __restrict__ d3,
                                               const float* __restrict__ s4, unsigned short* __restrict__ d4,
                                               float* __restrict__ gi0)
{
    __shared__ float xs[INS];
    if (blockIdx.x >= 969) {
        const int gb = blockIdx.x - 969;
        const int b = gb / 3, seg = gb % 3;
        const int t = threadIdx.x;
        for (int i = t; i < INS; i += 256) xs[i] = s4[(size_t)b*INS + i];
        __syncthreads();
        const int o = seg*256 + t;
        const float* wrow = s1 + (size_t)o*GRUIN;
        float a0 = 0.f, a1 = 0.f, a2 = 0.f, a3 = 0.f;
        for (int k = 0; k < INS; k += 4) {
            float4 wv = *(const float4*)(wrow + k);
            a0 += xs[k]*wv.x; a1 += xs[k+1]*wv.y; a2 += xs[k+2]*wv.z; a3 += xs[k+3]*wv.w;
        }
        gi0[(size_t)b*768 + o] = (a0 + a1) + (a2 + a3);
        return;
    }
    int gi = blockIdx.x*256 + threadIdx.x;
    const float* s; unsigned short* d; int idx;
    if      (gi < 41216)  { s = s0; d = d0; idx = gi; }
    else if (gi < 164096) { s = s1; d = d1; idx = gi - 41216; }
    else if (gi < 213248) { s = s2; d = d2; idx = gi - 164096; }
    else if (gi < 246016) { s = s3; d = d3; idx = gi - 213248; }
    else                  { s = s4; d = d4; idx = gi - 246016; }
    float4 v = ((const float4*)s)[idx];
    u16x4 o = { bfu(v.x), bfu(v.y), bfu(v.z), bfu(v.w) };
    ((u16x4*)d)[idx] = o;
}

// ---------------- K0: memory_context -> bf16 row-major + transposed ----------------
__global__ __launch_bounds__(256) void k_conv(const float* __restrict__ mem,
                                              __hip_bfloat16* __restrict__ memB,
                                              __hip_bfloat16* __restrict__ memT)
{
    __shared__ float Ms[32][129];
    const int t = threadIdx.x;
    const int b = blockIdx.x >> 7;
    const int m0 = (blockIdx.x & 127) << 5;
    const float* src = mem + ((size_t)b*MEMS + m0)*MD;
    for (int idx = t; idx < 32*128; idx += 256) {
        int m = idx >> 7, d = idx & 127;
        float v = src[(size_t)m*MD + d];
        Ms[m][d] = v;
        memB[((size_t)b*MEMS + m0 + m)*MD + d] = __float2bfloat16(v);
    }
    __syncthreads();
    for (int idx = t; idx < 128*32; idx += 256) {
        int d = idx >> 5, m = idx & 31;
        memT[((size_t)b*MD + d)*MEMS + m0 + m] = __float2bfloat16(Ms[m][d]);
    }
}

// ---------------- K1: MMU GEMM (MFMA, LDS-staged, 128-col tiles, fused ssd softmax) ----------------
__global__ __launch_bounds__(256, 4) void k_mmu(const __hip_bfloat16* __restrict__ Ab,
                                                const __hip_bfloat16* __restrict__ Wb,
                                                const float* __restrict__ bias,
                                                float* __restrict__ out,
                                                __hip_bfloat16* __restrict__ qbf)
{
    __shared__ __hip_bfloat16 At[2][64][32];
    __shared__ __hip_bfloat16 Bt[2][128][32];
    const int t = threadIdx.x, w = t >> 6, l = t & 63;
    const int lg = l >> 4, ll = l & 15;
    const int m0 = blockIdx.x*64;
    const int n0 = blockIdx.y*128;
    f32x4 acc[8];
    #pragma unroll
    for (int c = 0; c < 8; c++) acc[c] = (f32x4){0,0,0,0};

    const char* aSrc;
    {
        int row = t >> 2, cc = t & 3;
        int gc = cc ^ ((row >> 1) & 3);
        aSrc = (const char*)((const short*)Ab + (size_t)(m0+row)*RS) + gc*16;
    }
    const char* bSrc[2];
    #pragma unroll
    for (int j = 0; j < 2; j++) {
        int ci = w*128 + j*64 + l;
        int row = ci >> 2, cc = ci & 3;
        int gc = cc ^ ((row >> 1) & 3);
        bSrc[j] = (const char*)((const short*)Wb + (size_t)(n0+row)*RS) + gc*16;
    }

    auto stage = [&](int buf, int it) {
        int off = it*64;
        char* abase = (char*)(&At[buf][0][0]) + (size_t)(w << 6)*16;
        gload16(aSrc + off, abase);
        #pragma unroll
        for (int j = 0; j < 2; j++) {
            char* bbase = (char*)(&Bt[buf][0][0]) + (size_t)(w*128 + j*64)*16;
            gload16(bSrc[j] + off, bbase);
        }
    };

    stage(0, 0);
    asm volatile("s_waitcnt vmcnt(0)" ::: "memory");
    __syncthreads();
    int cur = 0;
    const int arow = (w << 4) + ll;
    const int aswz = ((lg ^ ((arow >> 1) & 3)) << 4);
    for (int it = 0; it < 8; ++it) {
        if (it + 1 < 8) stage(cur ^ 1, it + 1);
        const char* ab = (const char*)(&At[cur][0][0]);
        const char* bb = (const char*)(&Bt[cur][0][0]);
        bf16x8 af = *(const bf16x8*)(ab + arow*64 + aswz);
        #pragma unroll
        for (int c = 0; c < 8; c++) {
            int r0 = c*16 + ll;
            int sw = ((lg ^ ((r0 >> 1) & 3)) << 4);
            bf16x8 bf = *(const bf16x8*)(bb + (size_t)r0*64 + sw);
            acc[c] = __builtin_amdgcn_mfma_f32_16x16x32_bf16(af, bf, acc[c], 0, 0, 0);
        }
        asm volatile("s_waitcnt vmcnt(0)" ::: "memory");
        __syncthreads();
        cur ^= 1;
    }
    const int wm0 = m0 + (w << 4);
    #pragma unroll
    for (int c = 0; c < 8; c++) {
        int o = n0 + c*16 + ll;
        if (o > 640) continue;
        float bv = bias[o];
        #pragma unroll
        for (int r = 0; r < 4; r++) {
            int row = wm0 + lg*4 + r;
            float v = acc[c][r] + bv;
            if      (o < MD)        qbf[(size_t)row*MD + o] = __float2bfloat16(v * 0.08838834764831845f);
            else if (o < 2*MD)      out[O_WKEY + (size_t)row*MD + (o -   MD)] = v;
            else if (o < 3*MD)      out[O_WVAL + (size_t)row*MD + (o - 2*MD)] = v;
            else if (o == 3*MD)     out[O_WGATE + row] = sigf(v);
            else if (o < 4*MD + 1)  out[O_SSDK + (size_t)row*MD + (o - (3*MD+1))] = v;
            else                    out[O_SSDV + (size_t)row*MD + (o - (4*MD+1))] = v;
        }
    }
    if (n0 == 640) {
        #pragma unroll
        for (int r = 0; r < 4; r++) {
            int o = n0 + ll;
            float vr = acc[0][r] + ((o < MMUO) ? bias[o] : 0.f);
            float va = __shfl(vr, lg*16 + 1);
            float vb = __shfl(vr, lg*16 + 2);
            float vc = __shfl(vr, lg*16 + 3);
            float mm = fmaxf(va, fmaxf(vb, vc));
            float ea = __expf(va-mm), eb = __expf(vb-mm), ec = __expf(vc-mm);
            float inv = 1.f/(ea+eb+ec);
            int row = wm0 + lg*4 + r;
            if (ll == 1) out[O_SSDG + (size_t)row*3 + 0] = ea*inv;
            if (ll == 2) out[O_SSDG + (size_t)row*3 + 1] = eb*inv;
            if (ll == 3) out[O_SSDG + (size_t)row*3 + 2] = ec*inv;
        }
    }
}

// ---------------- K2: LDS-staged 4-way split-K flash attention, 32 q-rows/wave ----------------
// 512 blocks x 4 waves, launch_bounds(256,2) -> 2 blocks/CU. Block: 128 q-rows,
// keys [kh*1024,+1024). K/V tile LDS reads amortized over 2x q-rows (LDS-bound fix).
__global__ __launch_bounds__(256, 2) void k_attn(const __hip_bfloat16* __restrict__ qb,
                                                 const __hip_bfloat16* __restrict__ memB,
                                                 const __hip_bfloat16* __restrict__ memT,
                                                 unsigned short* __restrict__ Opart,
                                                 float* __restrict__ MLpart)
{
    __shared__ __hip_bfloat16 Kt[2][32][128];
    __shared__ __hip_bfloat16 Vt[2][128][32];
    __shared__ __hip_bfloat16 Pl[4][16][40];
    const int t = threadIdx.x, w = t >> 6, l = t & 63;
    const int lg = l >> 4, ll = l & 15;
    const int bid = blockIdx.x;
    const int xcd = bid & 7, rest = bid >> 3;      // rest 0..63
    const int b = xcd + ((rest >> 5) << 3);        // 2 batches per XCD
    const int sub = rest & 31;
    const int qblk = sub >> 2, kh = sub & 3;       // 8 q-groups x 4 key-quarters
    const int qrow0 = (b << 10) + (qblk << 7) + (w << 5);   // wave's 32 q-rows
    const int k_beg = kh << 10;                             // 1024 keys per quarter
    const float THR = 4.0f;

    const short* Q = (const short*)qb;
    bf16x8 qf[2][4];
    #pragma unroll
    for (int qs = 0; qs < 2; qs++)
        #pragma unroll
        for (int ks = 0; ks < 4; ks++)
            qf[qs][ks] = *(const bf16x8*)(Q + (size_t)(qrow0 + qs*16 + ll)*MD + ks*32 + lg*8);

    f32x4 O[2][8];
    #pragma unroll
    for (int qs = 0; qs < 2; qs++)
        #pragma unroll
        for (int dt = 0; dt < 8; dt++) O[qs][dt] = (f32x4){0.f,0.f,0.f,0.f};
    float m_run[2][4], lsum[2][4];
    #pragma unroll
    for (int qs = 0; qs < 2; qs++)
        #pragma unroll
        for (int r = 0; r < 4; r++) { m_run[qs][r] = -INFINITY; lsum[qs][r] = 0.f; }

    const char* MbB = (const char*)memB + (size_t)b*MEMS*MD*2;
    const char* MtB = (const char*)memT + (size_t)b*MD*MEMS*2;

    auto stage = [&](int buf, int it) {
        const int k0 = k_beg + it*32;
        char* kbase = (char*)(&Kt[buf][0][0]);
        char* vbase = (char*)(&Vt[buf][0][0]);
        #pragma unroll
        for (int j = 0; j < 2; j++) {
            int ci = (w << 7) + (j << 6) + l;        // chunk 0..511 (16B each)
            int krow = ci >> 4, cc = ci & 15;
            int gc = cc ^ (krow & 7);                // pre-swizzled global source
            gload16(MbB + (size_t)(k0 + krow)*256 + gc*16,
                    kbase + (size_t)((w << 7) + (j << 6))*16);
        }
        #pragma unroll
        for (int j = 0; j < 2; j++) {
            int ci = (w << 7) + (j << 6) + l;
            int drow = ci >> 2, cc = ci & 3;
            int gc = cc ^ ((drow >> 1) & 3);         // V swizzle (both-sides involution)
            gload16(MtB + (size_t)drow*(MEMS*2) + (size_t)k0*2 + gc*16,
                    vbase + (size_t)((w << 7) + (j << 6))*16);
        }
    };

    stage(0, 0);
    asm volatile("s_waitcnt vmcnt(0)" ::: "memory");
    asm volatile("s_barrier" ::: "memory");
    int cur = 0;
    const int NIT = 1024/32;   // 32
    const int vsw = ((lg ^ ((ll >> 1) & 3)) << 4);
    for (int it = 0; it < NIT; ++it) {
        if (it + 1 < NIT) {
            stage(cur ^ 1, it + 1);
            asm volatile("s_waitcnt vmcnt(4)" ::: "memory");
        } else {
            asm volatile("s_waitcnt vmcnt(0)" ::: "memory");
        }
        asm volatile("s_barrier" ::: "memory");
        const char* kbase = (const char*)(&Kt[cur][0][0]);
        const char* vbase = (const char*)(&Vt[cur][0][0]);
        // V fragments once per iter, reused for both q-halves
        bf16x8 vf[8];
        #pragma unroll
        for (int dt = 0; dt < 8; dt++)
            vf[dt] = *(const bf16x8*)(vbase + (size_t)(dt*16 + ll)*64 + vsw);
        // QK^T for both q-halves from one K-frag read
        f32x4 s[2][2];
        s[0][0]=(f32x4){0,0,0,0}; s[0][1]=(f32x4){0,0,0,0};
        s[1][0]=(f32x4){0,0,0,0}; s[1][1]=(f32x4){0,0,0,0};
        #pragma unroll
        for (int ks = 0; ks < 4; ks++) {
            int c0 = ks*4 + lg;
            int sw = (c0 ^ (ll & 7)) << 4;
            bf16x8 kf0 = *(const bf16x8*)(kbase + (size_t)ll*256 + sw);
            bf16x8 kf1 = *(const bf16x8*)(kbase + (size_t)(16 + ll)*256 + sw);
            s[0][0] = __builtin_amdgcn_mfma_f32_16x16x32_bf16(qf[0][ks], kf0, s[0][0], 0, 0, 0);
            s[1][0] = __builtin_amdgcn_mfma_f32_16x16x32_bf16(qf[1][ks], kf0, s[1][0], 0, 0, 0);
            s[0][1] = __builtin_amdgcn_mfma_f32_16x16x32_bf16(qf[0][ks], kf1, s[0][1], 0, 0, 0);
            s[1][1] = __builtin_amdgcn_mfma_f32_16x16x32_bf16(qf[1][ks], kf1, s[1][1], 0, 0, 0);
        }
        // defer-max (fast path: no cross-lane ops)
        bool need = false;
        #pragma unroll
        for (int qs = 0; qs < 2; qs++)
            #pragma unroll
            for (int r = 0; r < 4; r++) {
                need |= (s[qs][0][r] > m_run[qs][r] + THR);
                need |= (s[qs][1][r] > m_run[qs][r] + THR);
            }
        if (__any(need)) {
            #pragma unroll
            for (int qs = 0; qs < 2; qs++)
                #pragma unroll
                for (int r = 0; r < 4; r++) {
                    float v = fmaxf(s[qs][0][r], s[qs][1][r]);
                    v = fmaxf(v, __shfl_xor(v, 1));
                    v = fmaxf(v, __shfl_xor(v, 2));
                    v = fmaxf(v, __shfl_xor(v, 4));
                    v = fmaxf(v, __shfl_xor(v, 8));
                    float mnew = fmaxf(m_run[qs][r], v);
                    float alpha = __expf(m_run[qs][r] - mnew);
                    m_run[qs][r] = mnew;
                    lsum[qs][r] *= alpha;
                    #pragma unroll
                    for (int dt = 0; dt < 8; dt++) O[qs][dt][r] *= alpha;
                }
        }
        // P + PV per q-half (Pl reused qs=0 then qs=1; wave-internal ordering)
        #pragma unroll
        for (int qs = 0; qs < 2; qs++) {
            #pragma unroll
            for (int r = 0; r < 4; r++) {
                float p0 = __expf(s[qs][0][r] - m_run[qs][r]);
                float p1 = __expf(s[qs][1][r] - m_run[qs][r]);
                Pl[w][lg*4 + r][ll]      = __float2bfloat16(p0);
                Pl[w][lg*4 + r][16 + ll] = __float2bfloat16(p1);
                lsum[qs][r] += p0 + p1;
            }
            __builtin_amdgcn_wave_barrier();
            bf16x8 pa = *(const bf16x8*)(&Pl[w][ll][lg*8]);
            __builtin_amdgcn_wave_barrier();
            #pragma unroll
            for (int dt = 0; dt < 8; dt++)
                O[qs][dt] = __builtin_amdgcn_mfma_f32_16x16x32_bf16(pa, vf[dt], O[qs][dt], 0, 0, 0);
        }
        asm volatile("s_barrier" ::: "memory");
        cur ^= 1;
    }
    #pragma unroll
    for (int qs = 0; qs < 2; qs++)
        #pragma unroll
        for (int r = 0; r < 4; r++) {
            float s2 = lsum[qs][r];
            s2 += __shfl_xor(s2, 1);
            s2 += __shfl_xor(s2, 2);
            s2 += __shfl_xor(s2, 4);
            s2 += __shfl_xor(s2, 8);
            lsum[qs][r] = s2;
        }
    #pragma unroll
    for (int qs = 0; qs < 2; qs++)
        #pragma unroll
        for (int dt = 0; dt < 8; dt++)
            #pragma unroll
            for (int r = 0; r < 4; r++) {
                int row = qrow0 + qs*16 + lg*4 + r;
                Opart[((size_t)row*4 + kh)*128 + dt*16 + ll] = bfu(O[qs][dt][r]);
            }
    if (ll == 0) {
        #pragma unroll
        for (int qs = 0; qs < 2; qs++)
            #pragma unroll
            for (int r = 0; r < 4; r++) {
                int row = qrow0 + qs*16 + lg*4 + r;
                MLpart[((size_t)row*4 + kh)*2 + 0] = m_run[qs][r];
                MLpart[((size_t)row*4 + kh)*2 + 1] = lsum[qs][r];
            }
    }
}

// ---------------- K2b: combine the 4 split-K partials (bf16) -> rd bf16 ----------------
__global__ __launch_bounds__(256) void k_comb(const unsigned short* __restrict__ Opart,
                                              const float* __restrict__ MLpart,
                                              __hip_bfloat16* __restrict__ rdb)
{
    const int t = threadIdx.x;
    const int row = blockIdx.x*64 + (t >> 2);
    const int c0 = (t & 3) * 32;
    float m[4], lv[4], a[4];
    float M = -INFINITY;
    #pragma unroll
    for (int i = 0; i < 4; i++) {
        m[i]  = MLpart[((size_t)row*4 + i)*2 + 0];
        lv[i] = MLpart[((size_t)row*4 + i)*2 + 1];
        M = fmaxf(M, m[i]);
    }
    float L = 0.f;
    #pragma unroll
    for (int i = 0; i < 4; i++) { a[i] = __expf(m[i] - M); L += a[i]*lv[i]; }
    float invL = 1.f / L;
    #pragma unroll
    for (int i = 0; i < 4; i++) a[i] *= invL;
    unsigned short* dst = (unsigned short*)rdb + (size_t)row*128 + c0;
    #pragma unroll
    for (int j = 0; j < 8; j++) {
        float acc0=0.f, acc1=0.f, acc2=0.f, acc3=0.f;
        #pragma unroll
        for (int i = 0; i < 4; i++) {
            u16x4 x = ((const u16x4*)(Opart + ((size_t)row*4 + i)*128 + c0))[j];
            acc0 += a[i]*b2f(x[0]); acc1 += a[i]*b2f(x[1]);
            acc2 += a[i]*b2f(x[2]); acc3 += a[i]*b2f(x[3]);
        }
        u16x4 o = { bfu(acc0), bfu(acc1), bfu(acc2), bfu(acc3) };
        ((u16x4*)dst)[j] = o;
    }
}

// ---------------- K3: fused GRU (MFMA, LDS-staged, gi0-precomputed) ----------------
__global__ __launch_bounds__(256, 4) void k_gru(const float* __restrict__ gi0,
                                                const __hip_bfloat16* __restrict__ rdb,
                                                const __hip_bfloat16* __restrict__ regsb,
                                                const float* __restrict__ regs,
                                                const __hip_bfloat16* __restrict__ Wihb,
                                                const float* __restrict__ bih,
                                                const __hip_bfloat16* __restrict__ Whhb,
                                                const float* __restrict__ bhh,
                                                float* __restrict__ newregs,
                                                __hip_bfloat16* __restrict__ nregsb)
{
    __shared__ __hip_bfloat16 At[2][64][32];
    __shared__ __hip_bfloat16 Bt[2][192][32];
    const int t = threadIdx.x, w = t >> 6, l = t & 63;
    const int lg = l >> 4, ll = l & 15;
    const int m0 = blockIdx.x*64;
    const int n0 = blockIdx.y*64;
    const int batch = blockIdx.x >> 4;
    const short* Rd = (const short*)rdb;
    const short* Hb = (const short*)regsb;
    const short* Wi = (const short*)Wihb;
    const short* Wh = (const short*)Whhb;

    f32x4 aR[4], aZ[4], aNi[4], aNh[4];
    #pragma unroll
    for (int c = 0; c < 4; c++) {
        int o = n0 + c*16 + ll;
        float gR = gi0[(size_t)batch*768 + o];
        float gZ = gi0[(size_t)batch*768 + 256 + o];
        float gN = gi0[(size_t)batch*768 + 512 + o];
        aR[c]  = (f32x4){gR,gR,gR,gR};
        aZ[c]  = (f32x4){gZ,gZ,gZ,gZ};
        aNi[c] = (f32x4){gN,gN,gN,gN};
        aNh[c] = (f32x4){0,0,0,0};
    }

    const int aci = (w << 6) + l;
    const int arow_s = aci >> 2, acc_s = aci & 3;
    const int agc = acc_s ^ ((arow_s >> 1) & 3);
    const char* aSrcA = (const char*)(Rd + (size_t)(m0+arow_s)*MD) + agc*16;
    const char* aSrcB = (const char*)(Hb + (size_t)(m0+arow_s)*RS) + agc*16;
    const char* bSrcA0; const char* bSrcA1; const char* bSrcA2;
    const char* bSrcB0; const char* bSrcB1; const char* bSrcB2;
    {
        int ci, row, cc, gc, g, col;
        ci = w*192 + 0*64 + l; row = ci >> 2; cc = ci & 3; gc = cc ^ ((row >> 1) & 3);
        g = row >> 6; col = row & 63;
        bSrcA0 = (const char*)(Wi + (size_t)(g*RS + n0 + col)*GRUIN + INS) + gc*16;
        bSrcB0 = (const char*)(Wh + (size_t)(g*RS + n0 + col)*RS) + gc*16;
        ci = w*192 + 1*64 + l; row = ci >> 2; cc = ci & 3; gc = cc ^ ((row >> 1) & 3);
        g = row >> 6; col = row & 63;
        bSrcA1 = (const char*)(Wi + (size_t)(g*RS + n0 + col)*GRUIN + INS) + gc*16;
        bSrcB1 = (const char*)(Wh + (size_t)(g*RS + n0 + col)*RS) + gc*16;
        ci = w*192 + 2*64 + l; row = ci >> 2; cc = ci & 3; gc = cc ^ ((row >> 1) & 3);
        g = row >> 6; col = row & 63;
        bSrcA2 = (const char*)(Wi + (size_t)(g*RS + n0 + col)*GRUIN + INS) + gc*16;
        bSrcB2 = (const char*)(Wh + (size_t)(g*RS + n0 + col)*RS) + gc*16;
    }

    const int NITA = 4, NIT = 12;
    auto stage = [&](int buf, int it) {
        char* abase = (char*)(&At[buf][0][0]) + (size_t)(w << 6)*16;
        char* bbase = (char*)(&Bt[buf][0][0]) + (size_t)(w*192)*16;
        const char *as, *b0, *b1, *b2;
        if (it < NITA) {
            int off = it*64;
            as = aSrcA + off; b0 = bSrcA0 + off; b1 = bSrcA1 + off; b2 = bSrcA2 + off;
        } else {
            int off = (it - NITA)*64;
            as = aSrcB + off; b0 = bSrcB0 + off; b1 = bSrcB1 + off; b2 = bSrcB2 + off;
        }
        gload16(as, abase);
        gload16(b0, bbase);
        gload16(b1, bbase + 64*16);
        gload16(b2, bbase + 128*16);
    };

    stage(0, 0);
    asm volatile("s_waitcnt vmcnt(0)" ::: "memory");
    __syncthreads();
    int cur = 0;
    const int arow = (w << 4) + ll;
    const int aswz = ((lg ^ ((arow >> 1) & 3)) << 4);
    for (int it = 0; it < NIT; ++it) {
        if (it + 1 < NIT) stage(cur ^ 1, it + 1);
        const char* ab = (const char*)(&At[cur][0][0]);
        const char* bb = (const char*)(&Bt[cur][0][0]);
        bf16x8 af = *(const bf16x8*)(ab + arow*64 + aswz);
        if (it < NITA) {
            #pragma unroll
            for (int c = 0; c < 4; c++) {
                int r0 = c*16 + ll;
                int sw = ((lg ^ ((r0 >> 1) & 3)) << 4);
                bf16x8 bR = *(const bf16x8*)(bb + (size_t)r0*64 + sw);
                bf16x8 bZ = *(const bf16x8*)(bb + (size_t)(r0 + 64)*64 + sw);
                bf16x8 bN = *(const bf16x8*)(bb + (size_t)(r0 + 128)*64 + sw);
                aR[c]  = __builtin_amdgcn_mfma_f32_16x16x32_bf16(af, bR, aR[c],  0, 0, 0);
                aZ[c]  = __builtin_amdgcn_mfma_f32_16x16x32_bf16(af, bZ, aZ[c],  0, 0, 0);
                aNi[c] = __builtin_amdgcn_mfma_f32_16x16x32_bf16(af, bN, aNi[c], 0, 0, 0);
            }
        } else {
            #pragma unroll
            for (int c = 0; c < 4; c++) {
                int r0 = c*16 + ll;
                int sw = ((lg ^ ((r0 >> 1) & 3)) << 4);
                bf16x8 bR = *(const bf16x8*)(bb + (size_t)r0*64 + sw);
                bf16x8 bZ = *(const bf16x8*)(bb + (size_t)(r0 + 64)*64 + sw);
                bf16x8 bN = *(const bf16x8*)(bb + (size_t)(r0 + 128)*64 + sw);
                aR[c]  = __builtin_amdgcn_mfma_f32_16x16x32_bf16(af, bR, aR[c],  0, 0, 0);
                aZ[c]  = __builtin_amdgcn_mfma_f32_16x16x32_bf16(af, bZ, aZ[c],  0, 0, 0);
                aNh[c] = __builtin_amdgcn_mfma_f32_16x16x32_bf16(af, bN, aNh[c], 0, 0, 0);
            }
        }
        asm volatile("s_waitcnt vmcnt(0)" ::: "memory");
        __syncthreads();
        cur ^= 1;
    }
    const int wm0 = m0 + (w << 4);
    #pragma unroll
    for (int c = 0; c < 4; c++) {
        int o = n0 + c*16 + ll;
        float bR = bih[o]        + bhh[o];
        float bZ = bih[o +   RS] + bhh[o +   RS];
        float bNi = bih[o + 2*RS];
        float bNh = bhh[o + 2*RS];
        #pragma unroll
        for (int r = 0; r < 4; r++) {
            int row = wm0 + lg*4 + r;
            float rr = sigf(aR[c][r] + bR);
            float zz = sigf(aZ[c][r] + bZ);
            float nn = tanhf(aNi[c][r] + bNi + rr*(aNh[c][r] + bNh));
            float cv = regs[(size_t)row*RS + o];
            float nv = (1.f - zz)*nn + zz*cv;
            newregs[(size_t)row*RS + o] = nv;
            nregsb[(size_t)row*RS + o] = __float2bfloat16(nv);
        }
    }
}

// ---------------- K4: output GEMM (MFMA, LDS-staged, 128-col tiles) ----------------
__global__ __launch_bounds__(256, 4) void k_out(const __hip_bfloat16* __restrict__ Ab,
                                                const __hip_bfloat16* __restrict__ Wb,
                                                const float* __restrict__ bias,
                                                float* __restrict__ out0)
{
    __shared__ __hip_bfloat16 At[2][64][32];
    __shared__ __hip_bfloat16 Bt[2][128][32];
    const int t = threadIdx.x, w = t >> 6, l = t & 63;
    const int lg = l >> 4, ll = l & 15;
    const int m0 = blockIdx.x*64;
    const int n0 = blockIdx.y*128;
    f32x4 acc[8];
    #pragma unroll
    for (int c = 0; c < 8; c++) acc[c] = (f32x4){0,0,0,0};

    const char* aSrc;
    {
        int row = t >> 2, cc = t & 3;
        int gc = cc ^ ((row >> 1) & 3);
        aSrc = (const char*)((const short*)Ab + (size_t)(m0+row)*RS) + gc*16;
    }
    const char* bSrc[2];
    #pragma unroll
    for (int j = 0; j < 2; j++) {
        int ci = w*128 + j*64 + l;
        int row = ci >> 2, cc = ci & 3;
        int gc = cc ^ ((row >> 1) & 3);
        bSrc[j] = (const char*)((const short*)Wb + (size_t)(n0+row)*RS) + gc*16;
    }

    auto stage = [&](int buf, int it) {
        int off = it*64;
        char* abase = (char*)(&At[buf][0][0]) + (size_t)(w << 6)*16;
        gload16(aSrc + off, abase);
        #pragma unroll
        for (int j = 0; j < 2; j++) {
            char* bbase = (char*)(&Bt[buf][0][0]) + (size_t)(w*128 + j*64)*16;
            gload16(bSrc[j] + off, bbase);
        }
    };

    stage(0, 0);
    asm volatile("s_waitcnt vmcnt(0)" ::: "memory");
    __syncthreads();
    int cur = 0;
    const int arow = (w << 4) + ll;
    const int aswz = ((lg ^ ((arow >> 1) & 3)) << 4);
    for (int it = 0; it < 8; ++it) {
        if (it + 1 < 8) stage(cur ^ 1, it + 1);
        const char* ab = (const char*)(&At[cur][0][0]);
        const char* bb = (const char*)(&Bt[cur][0][0]);
        bf16x8 af = *(const bf16x8*)(ab + arow*64 + aswz);
        #pragma unroll
        for (int c = 0; c < 8; c++) {
            int r0 = c*16 + ll;
            int sw = ((lg ^ ((r0 >> 1) & 3)) << 4);
            bf16x8 bf = *(const bf16x8*)(bb + (size_t)r0*64 + sw);
            acc[c] = __builtin_amdgcn_mfma_f32_16x16x32_bf16(af, bf, acc[c], 0, 0, 0);
        }
        asm volatile("s_waitcnt vmcnt(0)" ::: "memory");
        __syncthreads();
        cur ^= 1;
    }
    const int wm0 = m0 + (w << 4);
    #pragma unroll
    for (int c = 0; c < 8; c++) {
        int o = n0 + c*16 + ll;
        float bv = bias[o];
        #pragma unroll
        for (int r = 0; r < 4; r++) {
            int row = wm0 + lg*4 + r;
            out0[(size_t)row*INS + o] = acc[c][r] + bv;
        }
    }
}

extern "C" void kernel_launch(void* const* d_in, const int* in_sizes, int n_in,
                              void* d_out, int out_size, void* d_ws, size_t ws_size,
                              hipStream_t stream)
{
    const float* inp  = (const float*)d_in[0];
    const float* regs = (const float*)d_in[1];
    const float* mem  = (const float*)d_in[2];
    const float* Wih  = (const float*)d_in[3];
    const float* bih  = (const float*)d_in[4];
    const float* Whh  = (const float*)d_in[5];
    const float* bhh  = (const float*)d_in[6];
    const float* Wmmu = (const float*)d_in[7];
    const float* bmmu = (const float*)d_in[8];
    const float* Wout = (const float*)d_in[9];
    const float* bout = (const float*)d_in[10];
    float* out = (float*)d_out;

    char* ws = (char*)d_ws;
    __hip_bfloat16* qbf    = (__hip_bfloat16*)(ws);
    __hip_bfloat16* rdb    = (__hip_bfloat16*)(ws + ((size_t)4<<20));
    __hip_bfloat16* memB   = (__hip_bfloat16*)(ws + ((size_t)8<<20));
    __hip_bfloat16* memT   = (__hip_bfloat16*)(ws + ((size_t)24<<20));
    __hip_bfloat16* regsb  = (__hip_bfloat16*)(ws + ((size_t)40<<20));
    __hip_bfloat16* nregsb = (__hip_bfloat16*)(ws + ((size_t)48<<20));
    __hip_bfloat16* Wmmub  = (__hip_bfloat16*)(ws + ((size_t)56<<20));
    __hip_bfloat16* Wihb   = (__hip_bfloat16*)(ws + ((size_t)56<<20) + ( 1<<20));
    __hip_bfloat16* Whhb   = (__hip_bfloat16*)(ws + ((size_t)56<<20) + ( 2<<20));
    __hip_bfloat16* Woutb  = (__hip_bfloat16*)(ws + ((size_t)56<<20) + ( 3<<20));
    __hip_bfloat16* inpb   = (__hip_bfloat16*)(ws + ((size_t)56<<20) + ( 4<<20));
    float*          MLpart = (float*)(ws + ((size_t)61<<20));            // 512 KB
    float*          gi0    = (float*)(ws + ((size_t)61<<20) + (1<<19));  // 49 KB
    unsigned short* Opart  = (unsigned short*)(out + O_OUT);  // 16.7 MB bf16 in out0 region

    k_cvt5g<<<1017, 256, 0, stream>>>(Wmmu, (unsigned short*)Wmmub,
                                      Wih,  (unsigned short*)Wihb,
                                      Whh,  (unsigned short*)Whhb,
                                      Wout, (unsigned short*)Woutb,
                                      inp,  (unsigned short*)inpb, gi0);
    k_cvt<<<(4194304/4 + 255)/256, 256, 0, stream>>>(regs, (unsigned short*)regsb, 4194304/4);
    k_conv<<<B_*128, 256, 0, stream>>>(mem, memB, memT);

    dim3 g1(NROWS/64, 6);
    k_mmu<<<g1, 256, 0, stream>>>(regsb, Wmmub, bmmu, out, qbf);
    k_attn<<<512, 256, 0, stream>>>(qbf, memB, memT, Opart, MLpart);
    k_comb<<<NROWS/64, 256, 0, stream>>>(Opart, MLpart, rdb);
    dim3 g3(NROWS/64, 4);
    k_gru<<<g3, 256, 0, stream>>>(gi0, rdb, regsb, regs, Wihb, bih, Whhb, bhh,
                                  out + O_REGS, nregsb);
    dim3 g4(NROWS/64, 4);
    k_out<<<g4, 256, 0, stream>>>(nregsb, Woutb, bout, out);
}